// Round 11
// baseline (560.848 us; speedup 1.0000x reference)
//
#include <hip/hip_runtime.h>
#include <hip/hip_bf16.h>
#include <cstddef>

typedef unsigned short u16;
typedef __attribute__((ext_vector_type(8))) short bf16x8;
typedef __attribute__((ext_vector_type(4))) float f32x4;

#define C2 0.18033688011112042f   // 0.125 * log2(e)

__device__ __forceinline__ u16 f2b(float f) {
    unsigned u = __builtin_bit_cast(unsigned, f);
    unsigned r = (u + 0x7FFF + ((u >> 16) & 1)) >> 16;
    return (u16)r;
}

__device__ __forceinline__ float exp2a(float x) {
    float r; asm("v_exp_f32 %0, %1" : "=v"(r) : "v"(x)); return r;
}

__device__ __forceinline__ unsigned cvtpk(float lo, float hi) {
    unsigned r; asm("v_cvt_pk_bf16_f32 %0, %1, %2" : "=v"(r) : "v"(lo), "v"(hi));
    return r;
}

__device__ __forceinline__ void gload_lds16(const void* g, void* l) {
    __builtin_amdgcn_global_load_lds(
        (const __attribute__((address_space(1))) unsigned int*)g,
        (__attribute__((address_space(3))) unsigned int*)l, 16, 0, 0);
}

#define VDRAIN() asm volatile("s_waitcnt vmcnt(0)" ::: "memory")
#define SBAR() do { __builtin_amdgcn_sched_barrier(0); __builtin_amdgcn_s_barrier(); } while (0)

// ---------------- elementwise fp32 -> bf16 ----------------
__global__ __launch_bounds__(256) void cvt_bf16(const float* __restrict__ in,
                                                u16* __restrict__ out, int n4)
{
    int i = blockIdx.x * 256 + threadIdx.x;
    if (i >= n4) return;
    float4 v = ((const float4*)in)[i];
    union { u16 s[4]; uint2 u; } pk;
    pk.s[0] = f2b(v.x); pk.s[1] = f2b(v.y); pk.s[2] = f2b(v.z); pk.s[3] = f2b(v.w);
    ((uint2*)out)[i] = pk.u;
}

// ---------------- kv_input concat (bf16) ----------------
__global__ __launch_bounds__(256) void concat_bf16(
    const float* __restrict__ x, const float* __restrict__ mem,
    const float* __restrict__ cmem, u16* __restrict__ out)
{
    int rowg = blockIdx.x;               // 0..9215
    int b = rowg / 2304, rr = rowg % 2304;
    const float* src = (rr < 256)  ? cmem + ((size_t)b * 256 + rr) * 1024
                     : (rr < 1280) ? mem  + ((size_t)b * 1024 + (rr - 256)) * 1024
                                   : x    + ((size_t)b * 1024 + (rr - 1280)) * 1024;
    float4 v = ((const float4*)src)[threadIdx.x];
    union { u16 s[4]; uint2 u; } pk;
    pk.s[0] = f2b(v.x); pk.s[1] = f2b(v.y); pk.s[2] = f2b(v.z); pk.s[3] = f2b(v.w);
    ((uint2*)(out + (size_t)rowg * 1024))[threadIdx.x] = pk.u;
}

// ---------------- transpose fp32 [K][N] -> bf16 [N][K] ----------------
__global__ __launch_bounds__(256) void transpose_bf16(
    const float* __restrict__ in, u16* __restrict__ out, int K, int N)
{
    __shared__ float t[32][33];
    int k0 = blockIdx.y * 32, n0 = blockIdx.x * 32;
    int tx = threadIdx.x & 31, ty = threadIdx.x >> 5;
    #pragma unroll
    for (int p = 0; p < 4; ++p)
        t[ty + 8 * p][tx] = in[(size_t)(k0 + ty + 8 * p) * N + n0 + tx];
    __syncthreads();
    #pragma unroll
    for (int p = 0; p < 4; ++p)
        out[(size_t)(n0 + ty + 8 * p) * K + k0 + tx] = f2b(t[tx][ty + 8 * p]);
}

// ---------------- conv_w[o,i,r] -> W2t[o][r*1024+i] bf16 ----------------
__global__ __launch_bounds__(256) void w2t_bf16(const float* __restrict__ cw,
                                                u16* __restrict__ out)
{
    size_t idx = (size_t)blockIdx.x * 256 + threadIdx.x;  // 1024*4096
    int o = (int)(idx >> 12), k = (int)(idx & 4095);
    out[idx] = f2b(cw[(size_t)o * 4096 + (k & 1023) * 4 + (k >> 10)]);
}

// ---------------- V half of [rows][2048] -> Vt[(bh*64+d)][rows] ----------------
__global__ __launch_bounds__(256) void transpose_v(
    const u16* __restrict__ src, int R, u16* __restrict__ dst)
{
    __shared__ u16 t[64 * 65];
    int bh = blockIdx.y, b = bh >> 4, h = bh & 15;
    int j0 = blockIdx.x * 64;
    int tid = threadIdx.x;
    #pragma unroll
    for (int p = 0; p < 2; ++p) {
        int idx = tid + p * 256;
        int j = idx >> 3, c = idx & 7;
        uint4 v = *(const uint4*)(src + ((size_t)(b * R + j0 + j)) * 2048 + 1024 + h * 64 + c * 8);
        const u16* vv = (const u16*)&v;
        #pragma unroll
        for (int u2 = 0; u2 < 8; ++u2) t[j * 65 + c * 8 + u2] = vv[u2];
    }
    __syncthreads();
    #pragma unroll
    for (int p = 0; p < 2; ++p) {
        int idx = tid + p * 256;
        int jc = idx & 7, d = idx >> 3;
        union { u16 s[8]; uint4 u; } pk;
        #pragma unroll
        for (int u2 = 0; u2 < 8; ++u2) pk.s[u2] = t[(jc * 8 + u2) * 65 + d];
        *(uint4*)(dst + ((size_t)(bh * 64 + d)) * (size_t)R + j0 + jc * 8) = pk.u;
    }
}

// ---------------- bf16 MFMA GEMM: C[M,N] = (A' @ Bt^T + bias) ----------------
// Linear grid with XCD-bijective decode: xcd=id&7 owns a contiguous band of
// row-blocks (ny must be divisible by 8). nx = 1<<nxshift column-blocks.
// A row remap: arow = row + (row>>ashift)*apad  (apad=0 -> plain).
__global__ __launch_bounds__(256) void gemm_bf16(
    const u16* __restrict__ A, const u16* __restrict__ Bt,
    const float* __restrict__ bias, float* __restrict__ Cf,
    u16* __restrict__ Cb, int M, int N, int K, float cscale,
    int apad, int ashift, int nxshift)
{
    __shared__ u16 Al[128 * 32];
    __shared__ u16 Bl[128 * 32];
    const int tid = threadIdx.x, w = tid >> 6, lane = tid & 63;
    const int lr = lane & 15, lg = lane >> 4;
    const int id = blockIdx.x;
    const int xcd = id & 7, s = id >> 3;
    const int bx = s & ((1 << nxshift) - 1);
    const int by = ((int)(gridDim.x >> 3) >> nxshift) * xcd + (s >> nxshift);
    const int bm0 = by * 128, bn0 = bx * 128;
    const int wr = (w >> 1) * 64, wc = (w & 1) * 64;

    f32x4 acc[4][4];
    const f32x4 z = {0.f, 0.f, 0.f, 0.f};
    #pragma unroll
    for (int mb = 0; mb < 4; ++mb)
        #pragma unroll
        for (int nb = 0; nb < 4; ++nb) acc[mb][nb] = z;

    for (int k0 = 0; k0 < K; k0 += 32) {
        __syncthreads();
        #pragma unroll
        for (int q = 0; q < 2; ++q) {
            int chunk = w * 2 + q;
            int row = bm0 + chunk * 16 + (lane >> 2);
            int arow = row + ((row >> ashift) * apad);
            int sg = (lane & 3) * 8;
            gload_lds16(A + (size_t)arow * K + k0 + sg, &Al[chunk * 512]);
            gload_lds16(Bt + (size_t)(bn0 + chunk * 16 + (lane >> 2)) * K + k0 + sg, &Bl[chunk * 512]);
        }
        __syncthreads();
        bf16x8 af[4], bf[4];
        #pragma unroll
        for (int mb = 0; mb < 4; ++mb)
            af[mb] = *(const bf16x8*)&Al[(wr + mb * 16 + lr) * 32 + lg * 8];
        #pragma unroll
        for (int nb = 0; nb < 4; ++nb)
            bf[nb] = *(const bf16x8*)&Bl[(wc + nb * 16 + lr) * 32 + lg * 8];
        #pragma unroll
        for (int mb = 0; mb < 4; ++mb)
            #pragma unroll
            for (int nb = 0; nb < 4; ++nb)
                acc[mb][nb] = __builtin_amdgcn_mfma_f32_16x16x32_bf16(
                    af[mb], bf[nb], acc[mb][nb], 0, 0, 0);
    }

    #pragma unroll
    for (int mb = 0; mb < 4; ++mb)
        #pragma unroll
        for (int nb = 0; nb < 4; ++nb)
            #pragma unroll
            for (int jr = 0; jr < 4; ++jr) {
                int row = bm0 + wr + mb * 16 + lg * 4 + jr;
                int col = bn0 + wc + nb * 16 + lr;
                float v = acc[mb][nb][jr] + (bias ? bias[col] : 0.f);
                if (Cf) Cf[(size_t)row * N + col] = v;
                if (Cb) Cb[(size_t)row * N + col] = f2b(v * cscale);
            }
}

// ---------------- fused main attention + aux phase-0 (no max tracking) ----------------
// 512 blocks; each handles TWO i-tiles of one (b,h): i0=ip*64 and 960-ip*64,
// so every block runs exactly 57 tile-iterations (perfect balance), and all
// blocks of one bh stay on one XCD (id&7 == bh&7).
__global__ __launch_bounds__(256) void attn_main_fused(
    const u16* __restrict__ qb,    // (4,1024,1024) bf16, pre-scaled by C2
    const u16* __restrict__ kvb,   // (4,2304,2048) bf16 k|v
    const u16* __restrict__ vt,    // (64bh*64d, 2304) bf16  V^T
    const u16* __restrict__ peb,   // (16,2304,64) bf16
    u16* __restrict__ outb,        // (4,1024,1024) bf16
    float* __restrict__ auxo)      // (64bh,1024,64) fp32 aux phase-0 out
{
    __shared__ u16 kbuf[64 * 64];      // 8 KB
    __shared__ u16 vbuf[64 * 64];      // 8 KB  [d][j-chunks] swizzled
    __shared__ u16 pering[128 * 64];   // 16 KB ring
    __shared__ u16 pls[4][1024];       // 8 KB, XOR-swizzled P

    const int tid = threadIdx.x;
    const int w = tid >> 6, lane = tid & 63;
    const int lr = lane & 15, lg = lane >> 4;
    const int rl = lane >> 3, cch = lane & 7;
    const int id = blockIdx.x;           // 0..511
    const int xcd = id & 7;
    const int slot = id >> 3;            // 0..63
    const int bh = xcd + 8 * (slot >> 3);
    const int ip = slot & 7;             // 0..7
    const int b = bh >> 4, h = bh & 15;

    // per-thread constant pls indices
    const int lrh = lr >> 3, lrm = lr & 7;
    int pwidx[4], pridx[2];
    #pragma unroll
    for (int nb = 0; nb < 4; ++nb)
        pwidx[nb] = (((nb * 2 + lrh) ^ (lg * 2)) * 8) + lrm;
    #pragma unroll
    for (int ks = 0; ks < 2; ++ks)
        pridx[ks] = lr * 64 + (((ks * 4 + lg) ^ ((lr >> 2) * 2)) * 8);

    const f32x4 z = {0.f, 0.f, 0.f, 0.f};

    for (int unit = 0; unit < 2; ++unit) {
        const int i0 = unit ? (960 - ip * 64) : (ip * 64);
        const int iw = i0 + 16 * w;
        const int jb0 = 960 - i0;

        bf16x8 qf[2];
        #pragma unroll
        for (int ks = 0; ks < 2; ++ks)
            qf[ks] = *(const bf16x8*)(qb + ((size_t)(b * 1024 + iw + lr)) * 1024
                                      + h * 64 + ks * 32 + lg * 8);

        f32x4 od[4], od2[4];
        float lloc[4], ll2[4];
        #pragma unroll
        for (int nb = 0; nb < 4; ++nb) { od[nb] = z; od2[nb] = z; }
        #pragma unroll
        for (int jr = 0; jr < 4; ++jr) { lloc[jr] = 0.f; ll2[jr] = 0.f; }

        // ---- prologue: K(0), V(0), full 128-row PE band ----
        #pragma unroll
        for (int q = 0; q < 2; ++q) {
            int row = 16 * w + 8 * q + rl;
            gload_lds16(kvb + ((size_t)(b * 2304 + row)) * 2048 + h * 64 + ((cch ^ rl) * 8),
                        &kbuf[(16 * w + 8 * q) * 64]);
            gload_lds16(vt + ((size_t)(bh * 64 + row)) * 2304 + ((cch ^ rl) * 8),
                        &vbuf[(16 * w + 8 * q) * 64]);
        }
        #pragma unroll
        for (int q = 0; q < 4; ++q) {
            int rr = 32 * w + 8 * q;
            int a = jb0 + rr + rl;
            int srow = a > 2303 ? 2303 : a;
            gload_lds16(peb + ((size_t)(h * 2304 + srow)) * 64 + ((cch ^ rl) * 8),
                        &pering[((jb0 + rr) & 127) * 64]);
        }
        VDRAIN();
        __syncthreads();

        const int nt = ((i0 + 1343) >> 6) + 1;
        for (int t = 0; t < nt; ++t) {
            const int j0 = t * 64;
            const int jb = jb0 + j0;
            const bool more = (t + 1 < nt);

            // ---- QK & QP MFMA (read kbuf, pering) ----
            f32x4 qk[4], qp[5];
            #pragma unroll
            for (int nb = 0; nb < 4; ++nb) qk[nb] = z;
            #pragma unroll
            for (int f = 0; f < 5; ++f) qp[f] = z;
            __builtin_amdgcn_s_setprio(1);
            #pragma unroll
            for (int ks = 0; ks < 2; ++ks) {
                #pragma unroll
                for (int nb = 0; nb < 4; ++nb) {
                    int row = nb * 16 + lr;
                    bf16x8 kb = *(const bf16x8*)&kbuf[row * 64 + (((4 * ks + lg) ^ (row & 7)) * 8)];
                    qk[nb] = __builtin_amdgcn_mfma_f32_16x16x32_bf16(qf[ks], kb, qk[nb], 0, 0, 0);
                }
                #pragma unroll
                for (int f = 0; f < 5; ++f) {
                    int rel = 48 - 16 * w + f * 16 + lr;
                    int slotp = (jb + rel) & 127;
                    bf16x8 pb = *(const bf16x8*)&pering[slotp * 64 + (((4 * ks + lg) ^ (slotp & 7)) * 8)];
                    qp[f] = __builtin_amdgcn_mfma_f32_16x16x32_bf16(qf[ks], pb, qp[f], 0, 0, 0);
                }
            }
            __builtin_amdgcn_s_setprio(0);

            VDRAIN();   // retire own V(t) loads (issued after barrier C of t-1)
            SBAR();     // B: publishes V(t); certifies kbuf/pering reads of tile t

            if (more) { // stage K(t+1) and PE(t+1)
                const int j0n = j0 + 64;
                #pragma unroll
                for (int q = 0; q < 2; ++q) {
                    int row = 16 * w + 8 * q + rl;
                    gload_lds16(kvb + ((size_t)(b * 2304 + j0n + row)) * 2048 + h * 64 + ((cch ^ rl) * 8),
                                &kbuf[(16 * w + 8 * q) * 64]);
                }
                const int A0 = jb + 128;
                #pragma unroll
                for (int q = 0; q < 2; ++q) {
                    int rr = A0 + 16 * w + 8 * q;
                    int a = rr + rl;
                    int srow = a > 2303 ? 2303 : a;
                    gload_lds16(peb + ((size_t)(h * 2304 + srow)) * 64 + ((cch ^ rl) * 8),
                                &pering[(rr & 127) * 64]);
                }
            }

            // ---- main: mask + softmax (m == 0), shuffle qp gather ----
            const bool nomask = (j0 + 63 <= iw + 1280);
            #pragma unroll
            for (int jr = 0; jr < 4; ++jr) {
                const int r = lg * 4 + jr;
                const int ia = iw + r;
                const int src = (lane & 48) | ((lr + 15 - r) & 15);
                float rot0 = __shfl(qp[0][jr], src);
                float rot1 = __shfl(qp[1][jr], src);
                float rot2 = __shfl(qp[2][jr], src);
                float rot3 = __shfl(qp[3][jr], src);
                float rot4 = __shfl(qp[4][jr], src);
                const bool hi = (lr > r);
                float s0 = qk[0][jr] + (hi ? rot1 : rot0);
                float s1 = qk[1][jr] + (hi ? rot2 : rot1);
                float s2 = qk[2][jr] + (hi ? rot3 : rot2);
                float s3 = qk[3][jr] + (hi ? rot4 : rot3);
                if (!nomask) {
                    s0 = (j0 + lr      <= ia + 1280) ? s0 : -1e30f;
                    s1 = (j0 + lr + 16 <= ia + 1280) ? s1 : -1e30f;
                    s2 = (j0 + lr + 32 <= ia + 1280) ? s2 : -1e30f;
                    s3 = (j0 + lr + 48 <= ia + 1280) ? s3 : -1e30f;
                }
                float p0 = exp2a(s0), p1 = exp2a(s1);
                float p2 = exp2a(s2), p3 = exp2a(s3);
                unsigned pkA = cvtpk(p0, p1), pkB = cvtpk(p2, p3);
                u16* pw = &pls[w][r * 64];
                pw[pwidx[0]] = (u16)pkA; pw[pwidx[1]] = (u16)(pkA >> 16);
                pw[pwidx[2]] = (u16)pkB; pw[pwidx[3]] = (u16)(pkB >> 16);
                lloc[jr] += (p0 + p1) + (p2 + p3);
            }

            // ---- main PV MFMA ----
            __builtin_amdgcn_s_setprio(1);
            #pragma unroll
            for (int ks = 0; ks < 2; ++ks) {
                bf16x8 pa = *(const bf16x8*)&pls[w][pridx[ks]];
                #pragma unroll
                for (int nb = 0; nb < 4; ++nb) {
                    int d = nb * 16 + lr;
                    bf16x8 vb = *(const bf16x8*)&vbuf[d * 64 + (((4 * ks + lg) ^ (d & 7)) * 8)];
                    od[nb] = __builtin_amdgcn_mfma_f32_16x16x32_bf16(pa, vb, od[nb], 0, 0, 0);
                }
            }
            __builtin_amdgcn_s_setprio(0);

            // ---- aux phase-0: kv rows 256..1279 == tiles 4..19 ----
            if (t >= 4 && t <= 19) {
                #pragma unroll
                for (int jr = 0; jr < 4; ++jr) {
                    const int r = lg * 4 + jr;
                    float p0 = exp2a(qk[0][jr]), p1 = exp2a(qk[1][jr]);
                    float p2 = exp2a(qk[2][jr]), p3 = exp2a(qk[3][jr]);
                    unsigned pkA = cvtpk(p0, p1), pkB = cvtpk(p2, p3);
                    u16* pw = &pls[w][r * 64];
                    pw[pwidx[0]] = (u16)pkA; pw[pwidx[1]] = (u16)(pkA >> 16);
                    pw[pwidx[2]] = (u16)pkB; pw[pwidx[3]] = (u16)(pkB >> 16);
                    ll2[jr] += (p0 + p1) + (p2 + p3);
                }
                __builtin_amdgcn_s_setprio(1);
                #pragma unroll
                for (int ks = 0; ks < 2; ++ks) {
                    bf16x8 pa = *(const bf16x8*)&pls[w][pridx[ks]];
                    #pragma unroll
                    for (int nb = 0; nb < 4; ++nb) {
                        int d = nb * 16 + lr;
                        bf16x8 vb = *(const bf16x8*)&vbuf[d * 64 + (((4 * ks + lg) ^ (d & 7)) * 8)];
                        od2[nb] = __builtin_amdgcn_mfma_f32_16x16x32_bf16(pa, vb, od2[nb], 0, 0, 0);
                    }
                }
                __builtin_amdgcn_s_setprio(0);
            }

            VDRAIN();   // retire own K(t+1)/PE(t+1) loads
            SBAR();     // C: publishes kbuf=K(t+1), pering; certifies vbuf/pls reads

            if (more) { // stage V(t+1)
                const int j0n = j0 + 64;
                #pragma unroll
                for (int q = 0; q < 2; ++q) {
                    int row = 16 * w + 8 * q + rl;
                    gload_lds16(vt + ((size_t)(bh * 64 + row)) * 2304 + j0n + ((cch ^ rl) * 8),
                                &vbuf[(16 * w + 8 * q) * 64]);
                }
            }
        }

        // ---- main epilogue ----
        #pragma unroll
        for (int jr = 0; jr < 4; ++jr) {
            float l = lloc[jr];
            #pragma unroll
            for (int mk = 1; mk < 16; mk <<= 1) l += __shfl_xor(l, mk);
            float inv = 1.f / l;
            int ia = iw + lg * 4 + jr;
            #pragma unroll
            for (int nb = 0; nb < 4; ++nb)
                outb[((size_t)(b * 1024 + ia)) * 1024 + h * 64 + nb * 16 + lr] =
                    f2b(od[nb][jr] * inv);
        }
        // ---- aux phase-0 epilogue ----
        #pragma unroll
        for (int jr = 0; jr < 4; ++jr) {
            float l = ll2[jr];
            #pragma unroll
            for (int mk = 1; mk < 16; mk <<= 1) l += __shfl_xor(l, mk);
            float inv = 1.f / l;
            int ig = i0 + 16 * w + lg * 4 + jr;
            #pragma unroll
            for (int nb = 0; nb < 4; ++nb)
                auxo[((size_t)(bh * 1024 + ig)) * 64 + nb * 16 + lr] = od2[nb][jr] * inv;
        }
        // last C-barrier of the loop certified all LDS reads of this unit;
        // next unit's prologue staging is safe to issue.
    }
}

// ---------------- aux phase-1 (compressed KV) + squared diff ----------------
__global__ __launch_bounds__(256) void attn_aux_diff(
    const u16* __restrict__ qb, const u16* __restrict__ ckcv,
    const u16* __restrict__ cvt, const float* __restrict__ auxo,
    float* __restrict__ acc)
{
    __shared__ u16 kbuf[64 * 64];
    __shared__ u16 vbuf[64 * 64];
    __shared__ u16 pls[4][1024];
    __shared__ float red[4];

    const int tid = threadIdx.x;
    const int w = tid >> 6, lane = tid & 63;
    const int lr = lane & 15, lg = lane >> 4;
    const int rl = lane >> 3, cch = lane & 7;
    const int id = blockIdx.x;
    const int slot = id >> 3;
    const int bh = (id & 7) + ((slot >> 4) << 3);
    const int b = bh >> 4, h = bh & 15;
    const int i0 = (slot & 15) * 64;
    const int iw = i0 + 16 * w;

    const int lrh = lr >> 3, lrm = lr & 7;
    int pwidx[4], pridx[2];
    #pragma unroll
    for (int nb = 0; nb < 4; ++nb)
        pwidx[nb] = (((nb * 2 + lrh) ^ (lg * 2)) * 8) + lrm;
    #pragma unroll
    for (int ks = 0; ks < 2; ++ks)
        pridx[ks] = lr * 64 + (((ks * 4 + lg) ^ ((lr >> 2) * 2)) * 8);

    const u16* kbase = ckcv + ((size_t)(b * 256)) * 2048 + h * 64;
    const u16* vbase = cvt + ((size_t)(bh * 64)) * 256;

    bf16x8 qf[2];
    #pragma unroll
    for (int ks = 0; ks < 2; ++ks)
        qf[ks] = *(const bf16x8*)(qb + ((size_t)(b * 1024 + iw + lr)) * 1024
                                  + h * 64 + ks * 32 + lg * 8);

    const f32x4 z = {0.f, 0.f, 0.f, 0.f};
    f32x4 od[4];
    float lloc[4];
    #pragma unroll
    for (int nb = 0; nb < 4; ++nb) od[nb] = z;
    #pragma unroll
    for (int jr = 0; jr < 4; ++jr) lloc[jr] = 0.f;

    for (int t = 0; t < 4; ++t) {
        const int j0 = t * 64;
        __syncthreads();
        #pragma unroll
        for (int q = 0; q < 2; ++q) {
            int row = 16 * w + 8 * q + rl;
            gload_lds16(kbase + (size_t)(j0 + row) * 2048 + ((cch ^ rl) * 8),
                        &kbuf[(16 * w + 8 * q) * 64]);
            gload_lds16(vbase + (size_t)row * 256 + j0 + ((cch ^ rl) * 8),
                        &vbuf[(16 * w + 8 * q) * 64]);
        }
        __syncthreads();

        f32x4 qk[4];
        #pragma unroll
        for (int nb = 0; nb < 4; ++nb) qk[nb] = z;
        #pragma unroll
        for (int ks = 0; ks < 2; ++ks)
            #pragma unroll
            for (int nb = 0; nb < 4; ++nb) {
                int row = nb * 16 + lr;
                bf16x8 kb = *(const bf16x8*)&kbuf[row * 64 + (((4 * ks + lg) ^ (row & 7)) * 8)];
                qk[nb] = __builtin_amdgcn_mfma_f32_16x16x32_bf16(qf[ks], kb, qk[nb], 0, 0, 0);
            }

        #pragma unroll
        for (int jr = 0; jr < 4; ++jr) {
            const int r = lg * 4 + jr;
            float p0 = exp2a(qk[0][jr]), p1 = exp2a(qk[1][jr]);
            float p2 = exp2a(qk[2][jr]), p3 = exp2a(qk[3][jr]);
            unsigned pkA = cvtpk(p0, p1), pkB = cvtpk(p2, p3);
            u16* pw = &pls[w][r * 64];
            pw[pwidx[0]] = (u16)pkA; pw[pwidx[1]] = (u16)(pkA >> 16);
            pw[pwidx[2]] = (u16)pkB; pw[pwidx[3]] = (u16)(pkB >> 16);
            lloc[jr] += (p0 + p1) + (p2 + p3);
        }

        #pragma unroll
        for (int ks = 0; ks < 2; ++ks) {
            bf16x8 pa = *(const bf16x8*)&pls[w][pridx[ks]];
            #pragma unroll
            for (int nb = 0; nb < 4; ++nb) {
                int d = nb * 16 + lr;
                bf16x8 vb = *(const bf16x8*)&vbuf[d * 64 + (((4 * ks + lg) ^ (d & 7)) * 8)];
                od[nb] = __builtin_amdgcn_mfma_f32_16x16x32_bf16(pa, vb, od[nb], 0, 0, 0);
            }
        }
    }

    float local = 0.f;
    #pragma unroll
    for (int jr = 0; jr < 4; ++jr) {
        float l = lloc[jr];
        #pragma unroll
        for (int mk = 1; mk < 16; mk <<= 1) l += __shfl_xor(l, mk);
        float inv = 1.f / l;
        int ig = i0 + 16 * w + lg * 4 + jr;
        #pragma unroll
        for (int nb = 0; nb < 4; ++nb) {
            float o2 = od[nb][jr] * inv;
            float o1 = auxo[((size_t)(bh * 1024 + ig)) * 64 + nb * 16 + lr];
            float d = o1 - o2;
            local += d * d;
        }
    }
    #pragma unroll
    for (int mk = 1; mk < 64; mk <<= 1) local += __shfl_xor(local, mk);
    if (lane == 0) red[w] = local;
    __syncthreads();
    if (tid == 0) atomicAdd(acc, red[0] + red[1] + red[2] + red[3]);
}

__global__ void finish_aux(const float* __restrict__ acc, float* __restrict__ out)
{
    out[0] = acc[0] * (1.0f / 4194304.0f);
}

// ---------------- launch ----------------
extern "C" void kernel_launch(void* const* d_in, const int* in_sizes, int n_in,
                              void* d_out, int out_size, void* d_ws, size_t ws_size,
                              hipStream_t stream)
{
    const float* x     = (const float*)d_in[0];
    const float* mem   = (const float*)d_in[1];
    const float* cmem  = (const float*)d_in[2];
    const float* pos   = (const float*)d_in[3];
    const float* Wq    = (const float*)d_in[5];
    const float* Wkv   = (const float*)d_in[6];
    const float* Wout  = (const float*)d_in[7];
    const float* bout  = (const float*)d_in[8];
    const float* convw = (const float*)d_in[9];
    const float* convb = (const float*)d_in[10];

    float* out      = (float*)d_out;
    float* logits   = out;
    float* new_mem  = out + 4194304;
    float* new_cmem = out + 8388608;
    float* aux_out  = out + 9437184;

    char* p = (char*)d_ws;
    u16* kvb   = (u16*)p; p += (size_t)9216 * 2048 * 2;
    u16* qb    = (u16*)p; p += (size_t)4096 * 1024 * 2;
    u16* kvin  = (u16*)p; p += (size_t)9216 * 1024 * 2;   // becomes vt AFTER all kvin readers done
    u16* wkvt  = (u16*)p; p += (size_t)2048 * 1024 * 2;
    u16* wqt   = (u16*)p; p += (size_t)1024 * 1024 * 2;
    u16* woutt = (u16*)p; p += (size_t)1024 * 1024 * 2;
    u16* w2t   = (u16*)p; p += (size_t)1024 * 4096 * 2;   // becomes cvt AFTER compress GEMM
    u16* peb   = (u16*)p; p += (size_t)16 * 2304 * 64 * 2;
    u16* xb    = (u16*)p; p += (size_t)4096 * 1024 * 2;   // auxo overlay region
    u16* memb  = (u16*)p; p += (size_t)4096 * 1024 * 2;
    u16* cmpb  = (u16*)p; p += (size_t)1024 * 1024 * 2;
    u16* ckcvb = (u16*)p; p += (size_t)1024 * 2048 * 2;
    u16* aob   = (u16*)p; p += (size_t)4096 * 1024 * 2;
    float* acc = (float*)p;
    u16* vt   = kvin;          // 4096 x 2304 u16, exact fit
    u16* cvt  = w2t;           // 4096 x 256 u16, fits
    float* auxo = (float*)xb;  // 4,194,304 f32 == xb+memb region exactly
    (void)memb;

    hipMemcpyAsync(new_mem, x, (size_t)4194304 * sizeof(float),
                   hipMemcpyDeviceToDevice, stream);

    cvt_bf16<<<2304, 256, 0, stream>>>(pos, peb, 589824);
    concat_bf16<<<9216, 256, 0, stream>>>(x, mem, cmem, kvin);
    transpose_bf16<<<dim3(64, 32), 256, 0, stream>>>(Wkv, wkvt, 1024, 2048);
    transpose_bf16<<<dim3(32, 32), 256, 0, stream>>>(Wq, wqt, 1024, 1024);
    transpose_bf16<<<dim3(32, 32), 256, 0, stream>>>(Wout, woutt, 1024, 1024);
    w2t_bf16<<<16384, 256, 0, stream>>>(convw, w2t);

    // ---- all kvin readers FIRST (kvin is clobbered by transpose_v below) ----
    // kv GEMM: ny=72, nx=16
    gemm_bf16<<<1152, 256, 0, stream>>>(kvin, wkvt, nullptr, nullptr, kvb, 9216, 2048, 1024, 1.f, 0, 10, 4);
    // Q = x @ Wq; A = kvin rows 1280.. per 2304-row batch; ny=32, nx=8
    gemm_bf16<<<256, 256, 0, stream>>>(kvin + (size_t)1280 * 1024, wqt, nullptr, nullptr, qb,
                                       4096, 1024, 1024, C2, 1280, 10, 3);
    // compressed = mem @ W2 + convb; A = kvin rows 256.. (256-row batches, K=4096); ny=8, nx=8
    gemm_bf16<<<64, 256, 0, stream>>>(kvin + (size_t)256 * 1024, w2t, convb, new_cmem, cmpb,
                                      1024, 1024, 4096, 1.f, 320, 8, 3);
    // ckcv: ny=8, nx=16
    gemm_bf16<<<128, 256, 0, stream>>>(cmpb, wkvt, nullptr, nullptr, ckcvb, 1024, 2048, 1024, 1.f, 0, 10, 4);

    // ---- now kvin and w2t are dead: overlay with vt / cvt ----
    transpose_v<<<dim3(36, 64), 256, 0, stream>>>(kvb, 2304, vt);
    transpose_v<<<dim3(4, 64), 256, 0, stream>>>(ckcvb, 256, cvt);

    attn_main_fused<<<512, 256, 0, stream>>>(qb, kvb, vt, peb, aob, auxo);
    // out GEMM: ny=32, nx=8
    gemm_bf16<<<256, 256, 0, stream>>>(aob, woutt, bout, logits, nullptr, 4096, 1024, 1024, 1.f, 0, 10, 3);

    hipMemsetAsync(acc, 0, sizeof(float), stream);
    attn_aux_diff<<<1024, 256, 0, stream>>>(qb, ckcvb, cvt, auxo, acc);
    finish_aux<<<1, 1, 0, stream>>>(acc, aux_out);
}

// Round 12
// 477.765 us; speedup vs baseline: 1.1739x; 1.1739x over previous
//
#include <hip/hip_runtime.h>
#include <hip/hip_bf16.h>
#include <cstddef>

typedef unsigned short u16;
typedef __attribute__((ext_vector_type(8))) short bf16x8;
typedef __attribute__((ext_vector_type(4))) float f32x4;

#define C2 0.18033688011112042f   // 0.125 * log2(e)

__device__ __forceinline__ u16 f2b(float f) {
    unsigned u = __builtin_bit_cast(unsigned, f);
    unsigned r = (u + 0x7FFF + ((u >> 16) & 1)) >> 16;
    return (u16)r;
}

__device__ __forceinline__ float exp2a(float x) {
    float r; asm("v_exp_f32 %0, %1" : "=v"(r) : "v"(x)); return r;
}

__device__ __forceinline__ unsigned cvtpk(float lo, float hi) {
    unsigned r; asm("v_cvt_pk_bf16_f32 %0, %1, %2" : "=v"(r) : "v"(lo), "v"(hi));
    return r;
}

__device__ __forceinline__ void gload_lds16(const void* g, void* l) {
    __builtin_amdgcn_global_load_lds(
        (const __attribute__((address_space(1))) unsigned int*)g,
        (__attribute__((address_space(3))) unsigned int*)l, 16, 0, 0);
}

#define VDRAIN() asm volatile("s_waitcnt vmcnt(0)" ::: "memory")
#define SBAR() do { __builtin_amdgcn_sched_barrier(0); __builtin_amdgcn_s_barrier(); } while (0)

// ---------------- elementwise fp32 -> bf16 ----------------
__global__ __launch_bounds__(256) void cvt_bf16(const float* __restrict__ in,
                                                u16* __restrict__ out, int n4)
{
    int i = blockIdx.x * 256 + threadIdx.x;
    if (i >= n4) return;
    float4 v = ((const float4*)in)[i];
    union { u16 s[4]; uint2 u; } pk;
    pk.s[0] = f2b(v.x); pk.s[1] = f2b(v.y); pk.s[2] = f2b(v.z); pk.s[3] = f2b(v.w);
    ((uint2*)out)[i] = pk.u;
}

// ---------------- kv_input concat (bf16) ----------------
__global__ __launch_bounds__(256) void concat_bf16(
    const float* __restrict__ x, const float* __restrict__ mem,
    const float* __restrict__ cmem, u16* __restrict__ out)
{
    int rowg = blockIdx.x;               // 0..9215
    int b = rowg / 2304, rr = rowg % 2304;
    const float* src = (rr < 256)  ? cmem + ((size_t)b * 256 + rr) * 1024
                     : (rr < 1280) ? mem  + ((size_t)b * 1024 + (rr - 256)) * 1024
                                   : x    + ((size_t)b * 1024 + (rr - 1280)) * 1024;
    float4 v = ((const float4*)src)[threadIdx.x];
    union { u16 s[4]; uint2 u; } pk;
    pk.s[0] = f2b(v.x); pk.s[1] = f2b(v.y); pk.s[2] = f2b(v.z); pk.s[3] = f2b(v.w);
    ((uint2*)(out + (size_t)rowg * 1024))[threadIdx.x] = pk.u;
}

// ---------------- transpose fp32 [K][N] -> bf16 [N][K] ----------------
__global__ __launch_bounds__(256) void transpose_bf16(
    const float* __restrict__ in, u16* __restrict__ out, int K, int N)
{
    __shared__ float t[32][33];
    int k0 = blockIdx.y * 32, n0 = blockIdx.x * 32;
    int tx = threadIdx.x & 31, ty = threadIdx.x >> 5;
    #pragma unroll
    for (int p = 0; p < 4; ++p)
        t[ty + 8 * p][tx] = in[(size_t)(k0 + ty + 8 * p) * N + n0 + tx];
    __syncthreads();
    #pragma unroll
    for (int p = 0; p < 4; ++p)
        out[(size_t)(n0 + ty + 8 * p) * K + k0 + tx] = f2b(t[tx][ty + 8 * p]);
}

// ---------------- conv_w[o,i,r] -> W2t[o][r*1024+i] bf16 ----------------
__global__ __launch_bounds__(256) void w2t_bf16(const float* __restrict__ cw,
                                                u16* __restrict__ out)
{
    size_t idx = (size_t)blockIdx.x * 256 + threadIdx.x;  // 1024*4096
    int o = (int)(idx >> 12), k = (int)(idx & 4095);
    out[idx] = f2b(cw[(size_t)o * 4096 + (k & 1023) * 4 + (k >> 10)]);
}

// ---------------- V half of [rows][2048] -> Vt[(bh*64+d)][rows] ----------------
__global__ __launch_bounds__(256) void transpose_v(
    const u16* __restrict__ src, int R, u16* __restrict__ dst)
{
    __shared__ u16 t[64 * 65];
    int bh = blockIdx.y, b = bh >> 4, h = bh & 15;
    int j0 = blockIdx.x * 64;
    int tid = threadIdx.x;
    #pragma unroll
    for (int p = 0; p < 2; ++p) {
        int idx = tid + p * 256;
        int j = idx >> 3, c = idx & 7;
        uint4 v = *(const uint4*)(src + ((size_t)(b * R + j0 + j)) * 2048 + 1024 + h * 64 + c * 8);
        const u16* vv = (const u16*)&v;
        #pragma unroll
        for (int u2 = 0; u2 < 8; ++u2) t[j * 65 + c * 8 + u2] = vv[u2];
    }
    __syncthreads();
    #pragma unroll
    for (int p = 0; p < 2; ++p) {
        int idx = tid + p * 256;
        int jc = idx & 7, d = idx >> 3;
        union { u16 s[8]; uint4 u; } pk;
        #pragma unroll
        for (int u2 = 0; u2 < 8; ++u2) pk.s[u2] = t[(jc * 8 + u2) * 65 + d];
        *(uint4*)(dst + ((size_t)(bh * 64 + d)) * (size_t)R + j0 + jc * 8) = pk.u;
    }
}

// ---------------- bf16 MFMA GEMM: C[M,N] = (A' @ Bt^T + bias) ----------------
// Linear grid with XCD-bijective decode: xcd=id&7 owns a contiguous band of
// row-blocks (ny must be divisible by 8). nx = 1<<nxshift column-blocks.
// A row remap: arow = row + (row>>ashift)*apad  (apad=0 -> plain).
__global__ __launch_bounds__(256) void gemm_bf16(
    const u16* __restrict__ A, const u16* __restrict__ Bt,
    const float* __restrict__ bias, float* __restrict__ Cf,
    u16* __restrict__ Cb, int M, int N, int K, float cscale,
    int apad, int ashift, int nxshift)
{
    __shared__ u16 Al[128 * 32];
    __shared__ u16 Bl[128 * 32];
    const int tid = threadIdx.x, w = tid >> 6, lane = tid & 63;
    const int lr = lane & 15, lg = lane >> 4;
    const int id = blockIdx.x;
    const int xcd = id & 7, s = id >> 3;
    const int bx = s & ((1 << nxshift) - 1);
    const int by = ((int)(gridDim.x >> 3) >> nxshift) * xcd + (s >> nxshift);
    const int bm0 = by * 128, bn0 = bx * 128;
    const int wr = (w >> 1) * 64, wc = (w & 1) * 64;

    f32x4 acc[4][4];
    const f32x4 z = {0.f, 0.f, 0.f, 0.f};
    #pragma unroll
    for (int mb = 0; mb < 4; ++mb)
        #pragma unroll
        for (int nb = 0; nb < 4; ++nb) acc[mb][nb] = z;

    for (int k0 = 0; k0 < K; k0 += 32) {
        __syncthreads();
        #pragma unroll
        for (int q = 0; q < 2; ++q) {
            int chunk = w * 2 + q;
            int row = bm0 + chunk * 16 + (lane >> 2);
            int arow = row + ((row >> ashift) * apad);
            int sg = (lane & 3) * 8;
            gload_lds16(A + (size_t)arow * K + k0 + sg, &Al[chunk * 512]);
            gload_lds16(Bt + (size_t)(bn0 + chunk * 16 + (lane >> 2)) * K + k0 + sg, &Bl[chunk * 512]);
        }
        __syncthreads();
        bf16x8 af[4], bf[4];
        #pragma unroll
        for (int mb = 0; mb < 4; ++mb)
            af[mb] = *(const bf16x8*)&Al[(wr + mb * 16 + lr) * 32 + lg * 8];
        #pragma unroll
        for (int nb = 0; nb < 4; ++nb)
            bf[nb] = *(const bf16x8*)&Bl[(wc + nb * 16 + lr) * 32 + lg * 8];
        #pragma unroll
        for (int mb = 0; mb < 4; ++mb)
            #pragma unroll
            for (int nb = 0; nb < 4; ++nb)
                acc[mb][nb] = __builtin_amdgcn_mfma_f32_16x16x32_bf16(
                    af[mb], bf[nb], acc[mb][nb], 0, 0, 0);
    }

    #pragma unroll
    for (int mb = 0; mb < 4; ++mb)
        #pragma unroll
        for (int nb = 0; nb < 4; ++nb)
            #pragma unroll
            for (int jr = 0; jr < 4; ++jr) {
                int row = bm0 + wr + mb * 16 + lg * 4 + jr;
                int col = bn0 + wc + nb * 16 + lr;
                float v = acc[mb][nb][jr] + (bias ? bias[col] : 0.f);
                if (Cf) Cf[(size_t)row * N + col] = v;
                if (Cb) Cb[(size_t)row * N + col] = f2b(v * cscale);
            }
}

// ---------------- fused main attention + aux phase-0 (no max tracking) ----------------
// q pre-scaled by C2; 1024 blocks, XCD-bijective decode. LPT ordering: i0
// DESCENDS with slot so longest blocks (nt = i0/64+21) launch first.
__global__ __launch_bounds__(256) void attn_main_fused(
    const u16* __restrict__ qb,    // (4,1024,1024) bf16, pre-scaled by C2
    const u16* __restrict__ kvb,   // (4,2304,2048) bf16 k|v
    const u16* __restrict__ vt,    // (64bh*64d, 2304) bf16  V^T
    const u16* __restrict__ peb,   // (16,2304,64) bf16
    u16* __restrict__ outb,        // (4,1024,1024) bf16
    float* __restrict__ auxo)      // (64bh,1024,64) fp32 aux phase-0 out
{
    __shared__ u16 kbuf[64 * 64];      // 8 KB
    __shared__ u16 vbuf[64 * 64];      // 8 KB  [d][j-chunks] swizzled
    __shared__ u16 pering[128 * 64];   // 16 KB ring
    __shared__ u16 pls[4][1024];       // 8 KB, XOR-swizzled P

    const int tid = threadIdx.x;
    const int w = tid >> 6, lane = tid & 63;
    const int lr = lane & 15, lg = lane >> 4;
    const int rl = lane >> 3, cch = lane & 7;
    // XCD-bijective decode: xcd = id&7 (round-robin dispatch), 8 bh per XCD
    const int id = blockIdx.x;
    const int slot = id >> 3;
    const int bh = (id & 7) + ((slot >> 4) << 3);
    const int b = bh >> 4, h = bh & 15;
    const int i0 = (15 - (slot & 15)) * 64;   // LPT: longest (i0=960) first
    const int iw = i0 + 16 * w;
    const int jb0 = 960 - i0;

    // per-thread constant pls indices
    const int lrh = lr >> 3, lrm = lr & 7;
    int pwidx[4], pridx[2];
    #pragma unroll
    for (int nb = 0; nb < 4; ++nb)
        pwidx[nb] = (((nb * 2 + lrh) ^ (lg * 2)) * 8) + lrm;
    #pragma unroll
    for (int ks = 0; ks < 2; ++ks)
        pridx[ks] = lr * 64 + (((ks * 4 + lg) ^ ((lr >> 2) * 2)) * 8);

    bf16x8 qf[2];
    #pragma unroll
    for (int ks = 0; ks < 2; ++ks)
        qf[ks] = *(const bf16x8*)(qb + ((size_t)(b * 1024 + iw + lr)) * 1024
                                  + h * 64 + ks * 32 + lg * 8);

    const f32x4 z = {0.f, 0.f, 0.f, 0.f};
    f32x4 od[4], od2[4];
    float lloc[4], ll2[4];
    #pragma unroll
    for (int nb = 0; nb < 4; ++nb) { od[nb] = z; od2[nb] = z; }
    #pragma unroll
    for (int jr = 0; jr < 4; ++jr) { lloc[jr] = 0.f; ll2[jr] = 0.f; }

    // ---- prologue: K(0), V(0), full 128-row PE band ----
    #pragma unroll
    for (int q = 0; q < 2; ++q) {
        int row = 16 * w + 8 * q + rl;
        gload_lds16(kvb + ((size_t)(b * 2304 + row)) * 2048 + h * 64 + ((cch ^ rl) * 8),
                    &kbuf[(16 * w + 8 * q) * 64]);
        gload_lds16(vt + ((size_t)(bh * 64 + row)) * 2304 + ((cch ^ rl) * 8),
                    &vbuf[(16 * w + 8 * q) * 64]);
    }
    #pragma unroll
    for (int q = 0; q < 4; ++q) {
        int rr = 32 * w + 8 * q;
        int a = jb0 + rr + rl;
        int srow = a > 2303 ? 2303 : a;
        gload_lds16(peb + ((size_t)(h * 2304 + srow)) * 64 + ((cch ^ rl) * 8),
                    &pering[((jb0 + rr) & 127) * 64]);
    }
    VDRAIN();
    __syncthreads();

    const int nt = ((i0 + 1343) >> 6) + 1;
    for (int t = 0; t < nt; ++t) {
        const int j0 = t * 64;
        const int jb = jb0 + j0;
        const bool more = (t + 1 < nt);

        // ---- QK & QP MFMA (read kbuf, pering) ----
        f32x4 qk[4], qp[5];
        #pragma unroll
        for (int nb = 0; nb < 4; ++nb) qk[nb] = z;
        #pragma unroll
        for (int f = 0; f < 5; ++f) qp[f] = z;
        __builtin_amdgcn_s_setprio(1);
        #pragma unroll
        for (int ks = 0; ks < 2; ++ks) {
            #pragma unroll
            for (int nb = 0; nb < 4; ++nb) {
                int row = nb * 16 + lr;
                bf16x8 kb = *(const bf16x8*)&kbuf[row * 64 + (((4 * ks + lg) ^ (row & 7)) * 8)];
                qk[nb] = __builtin_amdgcn_mfma_f32_16x16x32_bf16(qf[ks], kb, qk[nb], 0, 0, 0);
            }
            #pragma unroll
            for (int f = 0; f < 5; ++f) {
                int rel = 48 - 16 * w + f * 16 + lr;
                int slotp = (jb + rel) & 127;
                bf16x8 pb = *(const bf16x8*)&pering[slotp * 64 + (((4 * ks + lg) ^ (slotp & 7)) * 8)];
                qp[f] = __builtin_amdgcn_mfma_f32_16x16x32_bf16(qf[ks], pb, qp[f], 0, 0, 0);
            }
        }
        __builtin_amdgcn_s_setprio(0);

        VDRAIN();   // retire own V(t) loads (issued after barrier C of t-1)
        SBAR();     // B: publishes V(t); certifies kbuf/pering reads of tile t

        if (more) { // stage K(t+1) and PE(t+1)
            const int j0n = j0 + 64;
            #pragma unroll
            for (int q = 0; q < 2; ++q) {
                int row = 16 * w + 8 * q + rl;
                gload_lds16(kvb + ((size_t)(b * 2304 + j0n + row)) * 2048 + h * 64 + ((cch ^ rl) * 8),
                            &kbuf[(16 * w + 8 * q) * 64]);
            }
            const int A0 = jb + 128;
            #pragma unroll
            for (int q = 0; q < 2; ++q) {
                int rr = A0 + 16 * w + 8 * q;
                int a = rr + rl;
                int srow = a > 2303 ? 2303 : a;
                gload_lds16(peb + ((size_t)(h * 2304 + srow)) * 64 + ((cch ^ rl) * 8),
                            &pering[(rr & 127) * 64]);
            }
        }

        // ---- main: mask + softmax (m == 0), shuffle qp gather ----
        const bool nomask = (j0 + 63 <= iw + 1280);
        #pragma unroll
        for (int jr = 0; jr < 4; ++jr) {
            const int r = lg * 4 + jr;
            const int ia = iw + r;
            const int src = (lane & 48) | ((lr + 15 - r) & 15);
            float rot0 = __shfl(qp[0][jr], src);
            float rot1 = __shfl(qp[1][jr], src);
            float rot2 = __shfl(qp[2][jr], src);
            float rot3 = __shfl(qp[3][jr], src);
            float rot4 = __shfl(qp[4][jr], src);
            const bool hi = (lr > r);
            float s0 = qk[0][jr] + (hi ? rot1 : rot0);
            float s1 = qk[1][jr] + (hi ? rot2 : rot1);
            float s2 = qk[2][jr] + (hi ? rot3 : rot2);
            float s3 = qk[3][jr] + (hi ? rot4 : rot3);
            if (!nomask) {
                s0 = (j0 + lr      <= ia + 1280) ? s0 : -1e30f;
                s1 = (j0 + lr + 16 <= ia + 1280) ? s1 : -1e30f;
                s2 = (j0 + lr + 32 <= ia + 1280) ? s2 : -1e30f;
                s3 = (j0 + lr + 48 <= ia + 1280) ? s3 : -1e30f;
            }
            float p0 = exp2a(s0), p1 = exp2a(s1);
            float p2 = exp2a(s2), p3 = exp2a(s3);
            unsigned pkA = cvtpk(p0, p1), pkB = cvtpk(p2, p3);
            u16* pw = &pls[w][r * 64];
            pw[pwidx[0]] = (u16)pkA; pw[pwidx[1]] = (u16)(pkA >> 16);
            pw[pwidx[2]] = (u16)pkB; pw[pwidx[3]] = (u16)(pkB >> 16);
            lloc[jr] += (p0 + p1) + (p2 + p3);
        }

        // ---- main PV MFMA ----
        __builtin_amdgcn_s_setprio(1);
        #pragma unroll
        for (int ks = 0; ks < 2; ++ks) {
            bf16x8 pa = *(const bf16x8*)&pls[w][pridx[ks]];
            #pragma unroll
            for (int nb = 0; nb < 4; ++nb) {
                int d = nb * 16 + lr;
                bf16x8 vb = *(const bf16x8*)&vbuf[d * 64 + (((4 * ks + lg) ^ (d & 7)) * 8)];
                od[nb] = __builtin_amdgcn_mfma_f32_16x16x32_bf16(pa, vb, od[nb], 0, 0, 0);
            }
        }
        __builtin_amdgcn_s_setprio(0);

        // ---- aux phase-0: kv rows 256..1279 == tiles 4..19 ----
        if (t >= 4 && t <= 19) {
            #pragma unroll
            for (int jr = 0; jr < 4; ++jr) {
                const int r = lg * 4 + jr;
                float p0 = exp2a(qk[0][jr]), p1 = exp2a(qk[1][jr]);
                float p2 = exp2a(qk[2][jr]), p3 = exp2a(qk[3][jr]);
                unsigned pkA = cvtpk(p0, p1), pkB = cvtpk(p2, p3);
                u16* pw = &pls[w][r * 64];
                pw[pwidx[0]] = (u16)pkA; pw[pwidx[1]] = (u16)(pkA >> 16);
                pw[pwidx[2]] = (u16)pkB; pw[pwidx[3]] = (u16)(pkB >> 16);
                ll2[jr] += (p0 + p1) + (p2 + p3);
            }
            __builtin_amdgcn_s_setprio(1);
            #pragma unroll
            for (int ks = 0; ks < 2; ++ks) {
                bf16x8 pa = *(const bf16x8*)&pls[w][pridx[ks]];
                #pragma unroll
                for (int nb = 0; nb < 4; ++nb) {
                    int d = nb * 16 + lr;
                    bf16x8 vb = *(const bf16x8*)&vbuf[d * 64 + (((4 * ks + lg) ^ (d & 7)) * 8)];
                    od2[nb] = __builtin_amdgcn_mfma_f32_16x16x32_bf16(pa, vb, od2[nb], 0, 0, 0);
                }
            }
            __builtin_amdgcn_s_setprio(0);
        }

        VDRAIN();   // retire own K(t+1)/PE(t+1) loads
        SBAR();     // C: publishes kbuf=K(t+1), pering; certifies vbuf/pls reads

        if (more) { // stage V(t+1)
            const int j0n = j0 + 64;
            #pragma unroll
            for (int q = 0; q < 2; ++q) {
                int row = 16 * w + 8 * q + rl;
                gload_lds16(vt + ((size_t)(bh * 64 + row)) * 2304 + j0n + ((cch ^ rl) * 8),
                            &vbuf[(16 * w + 8 * q) * 64]);
            }
        }
    }

    // ---- main epilogue ----
    #pragma unroll
    for (int jr = 0; jr < 4; ++jr) {
        float l = lloc[jr];
        #pragma unroll
        for (int mk = 1; mk < 16; mk <<= 1) l += __shfl_xor(l, mk);
        float inv = 1.f / l;
        int ia = iw + lg * 4 + jr;
        #pragma unroll
        for (int nb = 0; nb < 4; ++nb)
            outb[((size_t)(b * 1024 + ia)) * 1024 + h * 64 + nb * 16 + lr] =
                f2b(od[nb][jr] * inv);
    }
    // ---- aux phase-0 epilogue ----
    #pragma unroll
    for (int jr = 0; jr < 4; ++jr) {
        float l = ll2[jr];
        #pragma unroll
        for (int mk = 1; mk < 16; mk <<= 1) l += __shfl_xor(l, mk);
        float inv = 1.f / l;
        int ig = i0 + 16 * w + lg * 4 + jr;
        #pragma unroll
        for (int nb = 0; nb < 4; ++nb)
            auxo[((size_t)(bh * 1024 + ig)) * 64 + nb * 16 + lr] = od2[nb][jr] * inv;
    }
}

// ---------------- aux phase-1 (compressed KV) + squared diff ----------------
__global__ __launch_bounds__(256) void attn_aux_diff(
    const u16* __restrict__ qb, const u16* __restrict__ ckcv,
    const u16* __restrict__ cvt, const float* __restrict__ auxo,
    float* __restrict__ acc)
{
    __shared__ u16 kbuf[64 * 64];
    __shared__ u16 vbuf[64 * 64];
    __shared__ u16 pls[4][1024];
    __shared__ float red[4];

    const int tid = threadIdx.x;
    const int w = tid >> 6, lane = tid & 63;
    const int lr = lane & 15, lg = lane >> 4;
    const int rl = lane >> 3, cch = lane & 7;
    const int id = blockIdx.x;
    const int slot = id >> 3;
    const int bh = (id & 7) + ((slot >> 4) << 3);
    const int b = bh >> 4, h = bh & 15;
    const int i0 = (slot & 15) * 64;
    const int iw = i0 + 16 * w;

    const int lrh = lr >> 3, lrm = lr & 7;
    int pwidx[4], pridx[2];
    #pragma unroll
    for (int nb = 0; nb < 4; ++nb)
        pwidx[nb] = (((nb * 2 + lrh) ^ (lg * 2)) * 8) + lrm;
    #pragma unroll
    for (int ks = 0; ks < 2; ++ks)
        pridx[ks] = lr * 64 + (((ks * 4 + lg) ^ ((lr >> 2) * 2)) * 8);

    const u16* kbase = ckcv + ((size_t)(b * 256)) * 2048 + h * 64;
    const u16* vbase = cvt + ((size_t)(bh * 64)) * 256;

    bf16x8 qf[2];
    #pragma unroll
    for (int ks = 0; ks < 2; ++ks)
        qf[ks] = *(const bf16x8*)(qb + ((size_t)(b * 1024 + iw + lr)) * 1024
                                  + h * 64 + ks * 32 + lg * 8);

    const f32x4 z = {0.f, 0.f, 0.f, 0.f};
    f32x4 od[4];
    float lloc[4];
    #pragma unroll
    for (int nb = 0; nb < 4; ++nb) od[nb] = z;
    #pragma unroll
    for (int jr = 0; jr < 4; ++jr) lloc[jr] = 0.f;

    for (int t = 0; t < 4; ++t) {
        const int j0 = t * 64;
        __syncthreads();
        #pragma unroll
        for (int q = 0; q < 2; ++q) {
            int row = 16 * w + 8 * q + rl;
            gload_lds16(kbase + (size_t)(j0 + row) * 2048 + ((cch ^ rl) * 8),
                        &kbuf[(16 * w + 8 * q) * 64]);
            gload_lds16(vbase + (size_t)row * 256 + j0 + ((cch ^ rl) * 8),
                        &vbuf[(16 * w + 8 * q) * 64]);
        }
        __syncthreads();

        f32x4 qk[4];
        #pragma unroll
        for (int nb = 0; nb < 4; ++nb) qk[nb] = z;
        #pragma unroll
        for (int ks = 0; ks < 2; ++ks)
            #pragma unroll
            for (int nb = 0; nb < 4; ++nb) {
                int row = nb * 16 + lr;
                bf16x8 kb = *(const bf16x8*)&kbuf[row * 64 + (((4 * ks + lg) ^ (row & 7)) * 8)];
                qk[nb] = __builtin_amdgcn_mfma_f32_16x16x32_bf16(qf[ks], kb, qk[nb], 0, 0, 0);
            }

        #pragma unroll
        for (int jr = 0; jr < 4; ++jr) {
            const int r = lg * 4 + jr;
            float p0 = exp2a(qk[0][jr]), p1 = exp2a(qk[1][jr]);
            float p2 = exp2a(qk[2][jr]), p3 = exp2a(qk[3][jr]);
            unsigned pkA = cvtpk(p0, p1), pkB = cvtpk(p2, p3);
            u16* pw = &pls[w][r * 64];
            pw[pwidx[0]] = (u16)pkA; pw[pwidx[1]] = (u16)(pkA >> 16);
            pw[pwidx[2]] = (u16)pkB; pw[pwidx[3]] = (u16)(pkB >> 16);
            lloc[jr] += (p0 + p1) + (p2 + p3);
        }

        #pragma unroll
        for (int ks = 0; ks < 2; ++ks) {
            bf16x8 pa = *(const bf16x8*)&pls[w][pridx[ks]];
            #pragma unroll
            for (int nb = 0; nb < 4; ++nb) {
                int d = nb * 16 + lr;
                bf16x8 vb = *(const bf16x8*)&vbuf[d * 64 + (((4 * ks + lg) ^ (d & 7)) * 8)];
                od[nb] = __builtin_amdgcn_mfma_f32_16x16x32_bf16(pa, vb, od[nb], 0, 0, 0);
            }
        }
    }

    float local = 0.f;
    #pragma unroll
    for (int jr = 0; jr < 4; ++jr) {
        float l = lloc[jr];
        #pragma unroll
        for (int mk = 1; mk < 16; mk <<= 1) l += __shfl_xor(l, mk);
        float inv = 1.f / l;
        int ig = i0 + 16 * w + lg * 4 + jr;
        #pragma unroll
        for (int nb = 0; nb < 4; ++nb) {
            float o2 = od[nb][jr] * inv;
            float o1 = auxo[((size_t)(bh * 1024 + ig)) * 64 + nb * 16 + lr];
            float d = o1 - o2;
            local += d * d;
        }
    }
    #pragma unroll
    for (int mk = 1; mk < 64; mk <<= 1) local += __shfl_xor(local, mk);
    if (lane == 0) red[w] = local;
    __syncthreads();
    if (tid == 0) atomicAdd(acc, red[0] + red[1] + red[2] + red[3]);
}

__global__ void finish_aux(const float* __restrict__ acc, float* __restrict__ out)
{
    out[0] = acc[0] * (1.0f / 4194304.0f);
}

// ---------------- launch ----------------
extern "C" void kernel_launch(void* const* d_in, const int* in_sizes, int n_in,
                              void* d_out, int out_size, void* d_ws, size_t ws_size,
                              hipStream_t stream)
{
    const float* x     = (const float*)d_in[0];
    const float* mem   = (const float*)d_in[1];
    const float* cmem  = (const float*)d_in[2];
    const float* pos   = (const float*)d_in[3];
    const float* Wq    = (const float*)d_in[5];
    const float* Wkv   = (const float*)d_in[6];
    const float* Wout  = (const float*)d_in[7];
    const float* bout  = (const float*)d_in[8];
    const float* convw = (const float*)d_in[9];
    const float* convb = (const float*)d_in[10];

    float* out      = (float*)d_out;
    float* logits   = out;
    float* new_mem  = out + 4194304;
    float* new_cmem = out + 8388608;
    float* aux_out  = out + 9437184;

    char* p = (char*)d_ws;
    u16* kvb   = (u16*)p; p += (size_t)9216 * 2048 * 2;
    u16* qb    = (u16*)p; p += (size_t)4096 * 1024 * 2;
    u16* kvin  = (u16*)p; p += (size_t)9216 * 1024 * 2;   // becomes vt AFTER all kvin readers done
    u16* wkvt  = (u16*)p; p += (size_t)2048 * 1024 * 2;
    u16* wqt   = (u16*)p; p += (size_t)1024 * 1024 * 2;
    u16* woutt = (u16*)p; p += (size_t)1024 * 1024 * 2;
    u16* w2t   = (u16*)p; p += (size_t)1024 * 4096 * 2;   // becomes cvt AFTER compress GEMM
    u16* peb   = (u16*)p; p += (size_t)16 * 2304 * 64 * 2;
    u16* xb    = (u16*)p; p += (size_t)4096 * 1024 * 2;   // auxo overlay region
    u16* memb  = (u16*)p; p += (size_t)4096 * 1024 * 2;
    u16* cmpb  = (u16*)p; p += (size_t)1024 * 1024 * 2;
    u16* ckcvb = (u16*)p; p += (size_t)1024 * 2048 * 2;
    u16* aob   = (u16*)p; p += (size_t)4096 * 1024 * 2;
    float* acc = (float*)p;
    u16* vt   = kvin;          // 4096 x 2304 u16, exact fit
    u16* cvt  = w2t;           // 4096 x 256 u16, fits
    float* auxo = (float*)xb;  // 4,194,304 f32 == xb+memb region exactly
    (void)memb;

    hipMemcpyAsync(new_mem, x, (size_t)4194304 * sizeof(float),
                   hipMemcpyDeviceToDevice, stream);

    cvt_bf16<<<2304, 256, 0, stream>>>(pos, peb, 589824);
    concat_bf16<<<9216, 256, 0, stream>>>(x, mem, cmem, kvin);
    transpose_bf16<<<dim3(64, 32), 256, 0, stream>>>(Wkv, wkvt, 1024, 2048);
    transpose_bf16<<<dim3(32, 32), 256, 0, stream>>>(Wq, wqt, 1024, 1024);
    transpose_bf16<<<dim3(32, 32), 256, 0, stream>>>(Wout, woutt, 1024, 1024);
    w2t_bf16<<<16384, 256, 0, stream>>>(convw, w2t);

    // ---- all kvin readers FIRST (kvin is clobbered by transpose_v below) ----
    // kv GEMM: ny=72, nx=16
    gemm_bf16<<<1152, 256, 0, stream>>>(kvin, wkvt, nullptr, nullptr, kvb, 9216, 2048, 1024, 1.f, 0, 10, 4);
    // Q = x @ Wq; A = kvin rows 1280.. per 2304-row batch; ny=32, nx=8
    gemm_bf16<<<256, 256, 0, stream>>>(kvin + (size_t)1280 * 1024, wqt, nullptr, nullptr, qb,
                                       4096, 1024, 1024, C2, 1280, 10, 3);
    // compressed = mem @ W2 + convb; A = kvin rows 256.. (256-row batches, K=4096); ny=8, nx=8
    gemm_bf16<<<64, 256, 0, stream>>>(kvin + (size_t)256 * 1024, w2t, convb, new_cmem, cmpb,
                                      1024, 1024, 4096, 1.f, 320, 8, 3);
    // ckcv: ny=8, nx=16
    gemm_bf16<<<128, 256, 0, stream>>>(cmpb, wkvt, nullptr, nullptr, ckcvb, 1024, 2048, 1024, 1.f, 0, 10, 4);

    // ---- now kvin and w2t are dead: overlay with vt / cvt ----
    transpose_v<<<dim3(36, 64), 256, 0, stream>>>(kvb, 2304, vt);
    transpose_v<<<dim3(4, 64), 256, 0, stream>>>(ckcvb, 256, cvt);

    attn_main_fused<<<1024, 256, 0, stream>>>(qb, kvb, vt, peb, aob, auxo);
    // out GEMM: ny=32, nx=8
    gemm_bf16<<<256, 256, 0, stream>>>(aob, woutt, bout, logits, nullptr, 4096, 1024, 1024, 1.f, 0, 10, 3);

    hipMemsetAsync(acc, 0, sizeof(float), stream);
    attn_aux_diff<<<1024, 256, 0, stream>>>(qb, ckcvb, cvt, auxo, acc);
    finish_aux<<<1, 1, 0, stream>>>(acc, aux_out);
}

// Round 13
// 461.225 us; speedup vs baseline: 1.2160x; 1.0359x over previous
//
#include <hip/hip_runtime.h>
#include <hip/hip_bf16.h>
#include <cstddef>

typedef unsigned short u16;
typedef __attribute__((ext_vector_type(8))) short bf16x8;
typedef __attribute__((ext_vector_type(4))) float f32x4;

#define C2 0.18033688011112042f   // 0.125 * log2(e)

__device__ __forceinline__ u16 f2b(float f) {
    unsigned u = __builtin_bit_cast(unsigned, f);
    unsigned r = (u + 0x7FFF + ((u >> 16) & 1)) >> 16;
    return (u16)r;
}

__device__ __forceinline__ float exp2a(float x) {
    float r; asm("v_exp_f32 %0, %1" : "=v"(r) : "v"(x)); return r;
}

__device__ __forceinline__ unsigned cvtpk(float lo, float hi) {
    unsigned r; asm("v_cvt_pk_bf16_f32 %0, %1, %2" : "=v"(r) : "v"(lo), "v"(hi));
    return r;
}

__device__ __forceinline__ void gload_lds16(const void* g, void* l) {
    __builtin_amdgcn_global_load_lds(
        (const __attribute__((address_space(1))) unsigned int*)g,
        (__attribute__((address_space(3))) unsigned int*)l, 16, 0, 0);
}

#define VDRAIN() asm volatile("s_waitcnt vmcnt(0)" ::: "memory")
#define SBAR() do { __builtin_amdgcn_sched_barrier(0); __builtin_amdgcn_s_barrier(); } while (0)

// ---------------- elementwise fp32 -> bf16 ----------------
__global__ __launch_bounds__(256) void cvt_bf16(const float* __restrict__ in,
                                                u16* __restrict__ out, int n4)
{
    int i = blockIdx.x * 256 + threadIdx.x;
    if (i >= n4) return;
    float4 v = ((const float4*)in)[i];
    union { u16 s[4]; uint2 u; } pk;
    pk.s[0] = f2b(v.x); pk.s[1] = f2b(v.y); pk.s[2] = f2b(v.z); pk.s[3] = f2b(v.w);
    ((uint2*)out)[i] = pk.u;
}

// ---------------- kv_input concat (bf16) ----------------
__global__ __launch_bounds__(256) void concat_bf16(
    const float* __restrict__ x, const float* __restrict__ mem,
    const float* __restrict__ cmem, u16* __restrict__ out)
{
    int rowg = blockIdx.x;               // 0..9215
    int b = rowg / 2304, rr = rowg % 2304;
    const float* src = (rr < 256)  ? cmem + ((size_t)b * 256 + rr) * 1024
                     : (rr < 1280) ? mem  + ((size_t)b * 1024 + (rr - 256)) * 1024
                                   : x    + ((size_t)b * 1024 + (rr - 1280)) * 1024;
    float4 v = ((const float4*)src)[threadIdx.x];
    union { u16 s[4]; uint2 u; } pk;
    pk.s[0] = f2b(v.x); pk.s[1] = f2b(v.y); pk.s[2] = f2b(v.z); pk.s[3] = f2b(v.w);
    ((uint2*)(out + (size_t)rowg * 1024))[threadIdx.x] = pk.u;
}

// ---------------- transpose fp32 [K][N] -> bf16 [N][K] ----------------
__global__ __launch_bounds__(256) void transpose_bf16(
    const float* __restrict__ in, u16* __restrict__ out, int K, int N)
{
    __shared__ float t[32][33];
    int k0 = blockIdx.y * 32, n0 = blockIdx.x * 32;
    int tx = threadIdx.x & 31, ty = threadIdx.x >> 5;
    #pragma unroll
    for (int p = 0; p < 4; ++p)
        t[ty + 8 * p][tx] = in[(size_t)(k0 + ty + 8 * p) * N + n0 + tx];
    __syncthreads();
    #pragma unroll
    for (int p = 0; p < 4; ++p)
        out[(size_t)(n0 + ty + 8 * p) * K + k0 + tx] = f2b(t[tx][ty + 8 * p]);
}

// ---------------- conv_w[o,i,r] -> W2t[o][r*1024+i] bf16 ----------------
__global__ __launch_bounds__(256) void w2t_bf16(const float* __restrict__ cw,
                                                u16* __restrict__ out)
{
    size_t idx = (size_t)blockIdx.x * 256 + threadIdx.x;  // 1024*4096
    int o = (int)(idx >> 12), k = (int)(idx & 4095);
    out[idx] = f2b(cw[(size_t)o * 4096 + (k & 1023) * 4 + (k >> 10)]);
}

// ---------------- V half of [rows][2048] -> Vt[(bh*64+d)][rows] ----------------
__global__ __launch_bounds__(256) void transpose_v(
    const u16* __restrict__ src, int R, u16* __restrict__ dst)
{
    __shared__ u16 t[64 * 65];
    int bh = blockIdx.y, b = bh >> 4, h = bh & 15;
    int j0 = blockIdx.x * 64;
    int tid = threadIdx.x;
    #pragma unroll
    for (int p = 0; p < 2; ++p) {
        int idx = tid + p * 256;
        int j = idx >> 3, c = idx & 7;
        uint4 v = *(const uint4*)(src + ((size_t)(b * R + j0 + j)) * 2048 + 1024 + h * 64 + c * 8);
        const u16* vv = (const u16*)&v;
        #pragma unroll
        for (int u2 = 0; u2 < 8; ++u2) t[j * 65 + c * 8 + u2] = vv[u2];
    }
    __syncthreads();
    #pragma unroll
    for (int p = 0; p < 2; ++p) {
        int idx = tid + p * 256;
        int jc = idx & 7, d = idx >> 3;
        union { u16 s[8]; uint4 u; } pk;
        #pragma unroll
        for (int u2 = 0; u2 < 8; ++u2) pk.s[u2] = t[(jc * 8 + u2) * 65 + d];
        *(uint4*)(dst + ((size_t)(bh * 64 + d)) * (size_t)R + j0 + jc * 8) = pk.u;
    }
}

// ---------------- bf16 MFMA GEMM: C[M,N] = (A' @ Bt^T + bias) ----------------
// Linear grid with XCD-bijective decode: xcd=id&7 owns a contiguous band of
// row-blocks (ny must be divisible by 8). nx = 1<<nxshift column-blocks.
// A row remap: arow = row + (row>>ashift)*apad  (apad=0 -> plain).
__global__ __launch_bounds__(256) void gemm_bf16(
    const u16* __restrict__ A, const u16* __restrict__ Bt,
    const float* __restrict__ bias, float* __restrict__ Cf,
    u16* __restrict__ Cb, int M, int N, int K, float cscale,
    int apad, int ashift, int nxshift)
{
    __shared__ u16 Al[128 * 32];
    __shared__ u16 Bl[128 * 32];
    const int tid = threadIdx.x, w = tid >> 6, lane = tid & 63;
    const int lr = lane & 15, lg = lane >> 4;
    const int id = blockIdx.x;
    const int xcd = id & 7, s = id >> 3;
    const int bx = s & ((1 << nxshift) - 1);
    const int by = ((int)(gridDim.x >> 3) >> nxshift) * xcd + (s >> nxshift);
    const int bm0 = by * 128, bn0 = bx * 128;
    const int wr = (w >> 1) * 64, wc = (w & 1) * 64;

    f32x4 acc[4][4];
    const f32x4 z = {0.f, 0.f, 0.f, 0.f};
    #pragma unroll
    for (int mb = 0; mb < 4; ++mb)
        #pragma unroll
        for (int nb = 0; nb < 4; ++nb) acc[mb][nb] = z;

    for (int k0 = 0; k0 < K; k0 += 32) {
        __syncthreads();
        #pragma unroll
        for (int q = 0; q < 2; ++q) {
            int chunk = w * 2 + q;
            int row = bm0 + chunk * 16 + (lane >> 2);
            int arow = row + ((row >> ashift) * apad);
            int sg = (lane & 3) * 8;
            gload_lds16(A + (size_t)arow * K + k0 + sg, &Al[chunk * 512]);
            gload_lds16(Bt + (size_t)(bn0 + chunk * 16 + (lane >> 2)) * K + k0 + sg, &Bl[chunk * 512]);
        }
        __syncthreads();
        bf16x8 af[4], bf[4];
        #pragma unroll
        for (int mb = 0; mb < 4; ++mb)
            af[mb] = *(const bf16x8*)&Al[(wr + mb * 16 + lr) * 32 + lg * 8];
        #pragma unroll
        for (int nb = 0; nb < 4; ++nb)
            bf[nb] = *(const bf16x8*)&Bl[(wc + nb * 16 + lr) * 32 + lg * 8];
        #pragma unroll
        for (int mb = 0; mb < 4; ++mb)
            #pragma unroll
            for (int nb = 0; nb < 4; ++nb)
                acc[mb][nb] = __builtin_amdgcn_mfma_f32_16x16x32_bf16(
                    af[mb], bf[nb], acc[mb][nb], 0, 0, 0);
    }

    #pragma unroll
    for (int mb = 0; mb < 4; ++mb)
        #pragma unroll
        for (int nb = 0; nb < 4; ++nb)
            #pragma unroll
            for (int jr = 0; jr < 4; ++jr) {
                int row = bm0 + wr + mb * 16 + lg * 4 + jr;
                int col = bn0 + wc + nb * 16 + lr;
                float v = acc[mb][nb][jr] + (bias ? bias[col] : 0.f);
                if (Cf) Cf[(size_t)row * N + col] = v;
                if (Cb) Cb[(size_t)row * N + col] = f2b(v * cscale);
            }
}

// ---------------- fused main attention + FULL aux loss ----------------
// q pre-scaled by C2; 1024 blocks, XCD-bijective + LPT. After the main loop,
// od/lloc are reused as aux phase-1 (compressed KV) accumulators; od2 keeps
// the normalized phase-0 output in registers; squared diff -> atomicAdd.
__global__ __launch_bounds__(256) void attn_main_fused(
    const u16* __restrict__ qb,    // (4,1024,1024) bf16, pre-scaled by C2
    const u16* __restrict__ kvb,   // (4,2304,2048) bf16 k|v
    const u16* __restrict__ vt,    // (64bh*64d, 2304) bf16  V^T
    const u16* __restrict__ peb,   // (16,2304,64) bf16
    const u16* __restrict__ ckcv,  // (4,256,2048) bf16 compressed k|v
    const u16* __restrict__ cvt,   // (64bh*64d, 256) bf16 compressed V^T
    u16* __restrict__ outb,        // (4,1024,1024) bf16
    float* __restrict__ acc)       // aux loss accumulator
{
    __shared__ u16 kbuf[64 * 64];      // 8 KB
    __shared__ u16 vbuf[64 * 64];      // 8 KB  [d][j-chunks] swizzled
    __shared__ u16 pering[128 * 64];   // 16 KB ring
    __shared__ u16 pls[4][1024];       // 8 KB, XOR-swizzled P
    __shared__ float red[4];

    const int tid = threadIdx.x;
    const int w = tid >> 6, lane = tid & 63;
    const int lr = lane & 15, lg = lane >> 4;
    const int rl = lane >> 3, cch = lane & 7;
    // XCD-bijective decode: xcd = id&7 (round-robin dispatch), 8 bh per XCD
    const int id = blockIdx.x;
    const int slot = id >> 3;
    const int bh = (id & 7) + ((slot >> 4) << 3);
    const int b = bh >> 4, h = bh & 15;
    const int i0 = (15 - (slot & 15)) * 64;   // LPT: longest (i0=960) first
    const int iw = i0 + 16 * w;
    const int jb0 = 960 - i0;

    // per-thread constant pls indices
    const int lrh = lr >> 3, lrm = lr & 7;
    int pwidx[4], pridx[2];
    #pragma unroll
    for (int nb = 0; nb < 4; ++nb)
        pwidx[nb] = (((nb * 2 + lrh) ^ (lg * 2)) * 8) + lrm;
    #pragma unroll
    for (int ks = 0; ks < 2; ++ks)
        pridx[ks] = lr * 64 + (((ks * 4 + lg) ^ ((lr >> 2) * 2)) * 8);

    bf16x8 qf[2];
    #pragma unroll
    for (int ks = 0; ks < 2; ++ks)
        qf[ks] = *(const bf16x8*)(qb + ((size_t)(b * 1024 + iw + lr)) * 1024
                                  + h * 64 + ks * 32 + lg * 8);

    const f32x4 z = {0.f, 0.f, 0.f, 0.f};
    f32x4 od[4], od2[4];
    float lloc[4], ll2[4];
    #pragma unroll
    for (int nb = 0; nb < 4; ++nb) { od[nb] = z; od2[nb] = z; }
    #pragma unroll
    for (int jr = 0; jr < 4; ++jr) { lloc[jr] = 0.f; ll2[jr] = 0.f; }

    // ---- prologue: K(0), V(0), full 128-row PE band ----
    #pragma unroll
    for (int q = 0; q < 2; ++q) {
        int row = 16 * w + 8 * q + rl;
        gload_lds16(kvb + ((size_t)(b * 2304 + row)) * 2048 + h * 64 + ((cch ^ rl) * 8),
                    &kbuf[(16 * w + 8 * q) * 64]);
        gload_lds16(vt + ((size_t)(bh * 64 + row)) * 2304 + ((cch ^ rl) * 8),
                    &vbuf[(16 * w + 8 * q) * 64]);
    }
    #pragma unroll
    for (int q = 0; q < 4; ++q) {
        int rr = 32 * w + 8 * q;
        int a = jb0 + rr + rl;
        int srow = a > 2303 ? 2303 : a;
        gload_lds16(peb + ((size_t)(h * 2304 + srow)) * 64 + ((cch ^ rl) * 8),
                    &pering[((jb0 + rr) & 127) * 64]);
    }
    VDRAIN();
    __syncthreads();

    const int nt = ((i0 + 1343) >> 6) + 1;
    for (int t = 0; t < nt; ++t) {
        const int j0 = t * 64;
        const int jb = jb0 + j0;
        const bool more = (t + 1 < nt);

        // ---- QK & QP MFMA (read kbuf, pering) ----
        f32x4 qk[4], qp[5];
        #pragma unroll
        for (int nb = 0; nb < 4; ++nb) qk[nb] = z;
        #pragma unroll
        for (int f = 0; f < 5; ++f) qp[f] = z;
        __builtin_amdgcn_s_setprio(1);
        #pragma unroll
        for (int ks = 0; ks < 2; ++ks) {
            #pragma unroll
            for (int nb = 0; nb < 4; ++nb) {
                int row = nb * 16 + lr;
                bf16x8 kb = *(const bf16x8*)&kbuf[row * 64 + (((4 * ks + lg) ^ (row & 7)) * 8)];
                qk[nb] = __builtin_amdgcn_mfma_f32_16x16x32_bf16(qf[ks], kb, qk[nb], 0, 0, 0);
            }
            #pragma unroll
            for (int f = 0; f < 5; ++f) {
                int rel = 48 - 16 * w + f * 16 + lr;
                int slotp = (jb + rel) & 127;
                bf16x8 pb = *(const bf16x8*)&pering[slotp * 64 + (((4 * ks + lg) ^ (slotp & 7)) * 8)];
                qp[f] = __builtin_amdgcn_mfma_f32_16x16x32_bf16(qf[ks], pb, qp[f], 0, 0, 0);
            }
        }
        __builtin_amdgcn_s_setprio(0);

        VDRAIN();   // retire own V(t) loads (issued after barrier C of t-1)
        SBAR();     // B: publishes V(t); certifies kbuf/pering reads of tile t

        if (more) { // stage K(t+1) and PE(t+1)
            const int j0n = j0 + 64;
            #pragma unroll
            for (int q = 0; q < 2; ++q) {
                int row = 16 * w + 8 * q + rl;
                gload_lds16(kvb + ((size_t)(b * 2304 + j0n + row)) * 2048 + h * 64 + ((cch ^ rl) * 8),
                            &kbuf[(16 * w + 8 * q) * 64]);
            }
            const int A0 = jb + 128;
            #pragma unroll
            for (int q = 0; q < 2; ++q) {
                int rr = A0 + 16 * w + 8 * q;
                int a = rr + rl;
                int srow = a > 2303 ? 2303 : a;
                gload_lds16(peb + ((size_t)(h * 2304 + srow)) * 64 + ((cch ^ rl) * 8),
                            &pering[(rr & 127) * 64]);
            }
        }

        // ---- main: mask + softmax (m == 0), shuffle qp gather ----
        const bool nomask = (j0 + 63 <= iw + 1280);
        #pragma unroll
        for (int jr = 0; jr < 4; ++jr) {
            const int r = lg * 4 + jr;
            const int ia = iw + r;
            const int src = (lane & 48) | ((lr + 15 - r) & 15);
            float rot0 = __shfl(qp[0][jr], src);
            float rot1 = __shfl(qp[1][jr], src);
            float rot2 = __shfl(qp[2][jr], src);
            float rot3 = __shfl(qp[3][jr], src);
            float rot4 = __shfl(qp[4][jr], src);
            const bool hi = (lr > r);
            float s0 = qk[0][jr] + (hi ? rot1 : rot0);
            float s1 = qk[1][jr] + (hi ? rot2 : rot1);
            float s2 = qk[2][jr] + (hi ? rot3 : rot2);
            float s3 = qk[3][jr] + (hi ? rot4 : rot3);
            if (!nomask) {
                s0 = (j0 + lr      <= ia + 1280) ? s0 : -1e30f;
                s1 = (j0 + lr + 16 <= ia + 1280) ? s1 : -1e30f;
                s2 = (j0 + lr + 32 <= ia + 1280) ? s2 : -1e30f;
                s3 = (j0 + lr + 48 <= ia + 1280) ? s3 : -1e30f;
            }
            float p0 = exp2a(s0), p1 = exp2a(s1);
            float p2 = exp2a(s2), p3 = exp2a(s3);
            unsigned pkA = cvtpk(p0, p1), pkB = cvtpk(p2, p3);
            u16* pw = &pls[w][r * 64];
            pw[pwidx[0]] = (u16)pkA; pw[pwidx[1]] = (u16)(pkA >> 16);
            pw[pwidx[2]] = (u16)pkB; pw[pwidx[3]] = (u16)(pkB >> 16);
            lloc[jr] += (p0 + p1) + (p2 + p3);
        }

        // ---- main PV MFMA ----
        __builtin_amdgcn_s_setprio(1);
        #pragma unroll
        for (int ks = 0; ks < 2; ++ks) {
            bf16x8 pa = *(const bf16x8*)&pls[w][pridx[ks]];
            #pragma unroll
            for (int nb = 0; nb < 4; ++nb) {
                int d = nb * 16 + lr;
                bf16x8 vb = *(const bf16x8*)&vbuf[d * 64 + (((4 * ks + lg) ^ (d & 7)) * 8)];
                od[nb] = __builtin_amdgcn_mfma_f32_16x16x32_bf16(pa, vb, od[nb], 0, 0, 0);
            }
        }
        __builtin_amdgcn_s_setprio(0);

        // ---- aux phase-0: kv rows 256..1279 == tiles 4..19 ----
        if (t >= 4 && t <= 19) {
            #pragma unroll
            for (int jr = 0; jr < 4; ++jr) {
                const int r = lg * 4 + jr;
                float p0 = exp2a(qk[0][jr]), p1 = exp2a(qk[1][jr]);
                float p2 = exp2a(qk[2][jr]), p3 = exp2a(qk[3][jr]);
                unsigned pkA = cvtpk(p0, p1), pkB = cvtpk(p2, p3);
                u16* pw = &pls[w][r * 64];
                pw[pwidx[0]] = (u16)pkA; pw[pwidx[1]] = (u16)(pkA >> 16);
                pw[pwidx[2]] = (u16)pkB; pw[pwidx[3]] = (u16)(pkB >> 16);
                ll2[jr] += (p0 + p1) + (p2 + p3);
            }
            __builtin_amdgcn_s_setprio(1);
            #pragma unroll
            for (int ks = 0; ks < 2; ++ks) {
                bf16x8 pa = *(const bf16x8*)&pls[w][pridx[ks]];
                #pragma unroll
                for (int nb = 0; nb < 4; ++nb) {
                    int d = nb * 16 + lr;
                    bf16x8 vb = *(const bf16x8*)&vbuf[d * 64 + (((4 * ks + lg) ^ (d & 7)) * 8)];
                    od2[nb] = __builtin_amdgcn_mfma_f32_16x16x32_bf16(pa, vb, od2[nb], 0, 0, 0);
                }
            }
            __builtin_amdgcn_s_setprio(0);
        }

        VDRAIN();   // retire own K(t+1)/PE(t+1) loads
        SBAR();     // C: publishes kbuf=K(t+1), pering; certifies vbuf/pls reads

        if (more) { // stage V(t+1)
            const int j0n = j0 + 64;
            #pragma unroll
            for (int q = 0; q < 2; ++q) {
                int row = 16 * w + 8 * q + rl;
                gload_lds16(vt + ((size_t)(bh * 64 + row)) * 2304 + j0n + ((cch ^ rl) * 8),
                            &vbuf[(16 * w + 8 * q) * 64]);
            }
        }
    }

    // ---- main epilogue (frees od/lloc) ----
    #pragma unroll
    for (int jr = 0; jr < 4; ++jr) {
        float l = lloc[jr];
        #pragma unroll
        for (int mk = 1; mk < 16; mk <<= 1) l += __shfl_xor(l, mk);
        float inv = 1.f / l;
        int ia = iw + lg * 4 + jr;
        #pragma unroll
        for (int nb = 0; nb < 4; ++nb)
            outb[((size_t)(b * 1024 + ia)) * 1024 + h * 64 + nb * 16 + lr] =
                f2b(od[nb][jr] * inv);
    }
    // ---- aux phase-0 finalize: normalize od2 in registers ----
    #pragma unroll
    for (int jr = 0; jr < 4; ++jr) {
        float l = ll2[jr];
        #pragma unroll
        for (int mk = 1; mk < 16; mk <<= 1) l += __shfl_xor(l, mk);
        float inv = 1.f / l;
        #pragma unroll
        for (int nb = 0; nb < 4; ++nb) od2[nb][jr] *= inv;
    }

    // ---- aux phase-1: compressed KV (4 tiles), reuse od/lloc ----
    #pragma unroll
    for (int nb = 0; nb < 4; ++nb) od[nb] = z;
    #pragma unroll
    for (int jr = 0; jr < 4; ++jr) lloc[jr] = 0.f;
    const u16* kbase = ckcv + ((size_t)(b * 256)) * 2048 + h * 64;
    const u16* vbase = cvt + ((size_t)(bh * 64)) * 256;

    for (int t = 0; t < 4; ++t) {
        const int j0 = t * 64;
        __syncthreads();   // certify prior kbuf/vbuf/pls reads block-wide
        #pragma unroll
        for (int q = 0; q < 2; ++q) {
            int row = 16 * w + 8 * q + rl;
            gload_lds16(kbase + (size_t)(j0 + row) * 2048 + ((cch ^ rl) * 8),
                        &kbuf[(16 * w + 8 * q) * 64]);
            gload_lds16(vbase + (size_t)row * 256 + j0 + ((cch ^ rl) * 8),
                        &vbuf[(16 * w + 8 * q) * 64]);
        }
        VDRAIN();
        __syncthreads();

        f32x4 qk[4];
        #pragma unroll
        for (int nb = 0; nb < 4; ++nb) qk[nb] = z;
        #pragma unroll
        for (int ks = 0; ks < 2; ++ks)
            #pragma unroll
            for (int nb = 0; nb < 4; ++nb) {
                int row = nb * 16 + lr;
                bf16x8 kb = *(const bf16x8*)&kbuf[row * 64 + (((4 * ks + lg) ^ (row & 7)) * 8)];
                qk[nb] = __builtin_amdgcn_mfma_f32_16x16x32_bf16(qf[ks], kb, qk[nb], 0, 0, 0);
            }

        #pragma unroll
        for (int jr = 0; jr < 4; ++jr) {
            const int r = lg * 4 + jr;
            float p0 = exp2a(qk[0][jr]), p1 = exp2a(qk[1][jr]);
            float p2 = exp2a(qk[2][jr]), p3 = exp2a(qk[3][jr]);
            unsigned pkA = cvtpk(p0, p1), pkB = cvtpk(p2, p3);
            u16* pw = &pls[w][r * 64];
            pw[pwidx[0]] = (u16)pkA; pw[pwidx[1]] = (u16)(pkA >> 16);
            pw[pwidx[2]] = (u16)pkB; pw[pwidx[3]] = (u16)(pkB >> 16);
            lloc[jr] += (p0 + p1) + (p2 + p3);
        }

        #pragma unroll
        for (int ks = 0; ks < 2; ++ks) {
            bf16x8 pa = *(const bf16x8*)&pls[w][pridx[ks]];
            #pragma unroll
            for (int nb = 0; nb < 4; ++nb) {
                int d = nb * 16 + lr;
                bf16x8 vb = *(const bf16x8*)&vbuf[d * 64 + (((4 * ks + lg) ^ (d & 7)) * 8)];
                od[nb] = __builtin_amdgcn_mfma_f32_16x16x32_bf16(pa, vb, od[nb], 0, 0, 0);
            }
        }
    }

    // ---- squared diff + block reduce + atomic ----
    float local = 0.f;
    #pragma unroll
    for (int jr = 0; jr < 4; ++jr) {
        float l = lloc[jr];
        #pragma unroll
        for (int mk = 1; mk < 16; mk <<= 1) l += __shfl_xor(l, mk);
        float inv = 1.f / l;
        #pragma unroll
        for (int nb = 0; nb < 4; ++nb) {
            float d = od2[nb][jr] - od[nb][jr] * inv;
            local += d * d;
        }
    }
    #pragma unroll
    for (int mk = 1; mk < 64; mk <<= 1) local += __shfl_xor(local, mk);
    if (lane == 0) red[w] = local;
    __syncthreads();
    if (tid == 0) atomicAdd(acc, red[0] + red[1] + red[2] + red[3]);
}

__global__ void finish_aux(const float* __restrict__ acc, float* __restrict__ out)
{
    out[0] = acc[0] * (1.0f / 4194304.0f);
}

// ---------------- launch ----------------
extern "C" void kernel_launch(void* const* d_in, const int* in_sizes, int n_in,
                              void* d_out, int out_size, void* d_ws, size_t ws_size,
                              hipStream_t stream)
{
    const float* x     = (const float*)d_in[0];
    const float* mem   = (const float*)d_in[1];
    const float* cmem  = (const float*)d_in[2];
    const float* pos   = (const float*)d_in[3];
    const float* Wq    = (const float*)d_in[5];
    const float* Wkv   = (const float*)d_in[6];
    const float* Wout  = (const float*)d_in[7];
    const float* bout  = (const float*)d_in[8];
    const float* convw = (const float*)d_in[9];
    const float* convb = (const float*)d_in[10];

    float* out      = (float*)d_out;
    float* logits   = out;
    float* new_mem  = out + 4194304;
    float* new_cmem = out + 8388608;
    float* aux_out  = out + 9437184;

    char* p = (char*)d_ws;
    u16* kvb   = (u16*)p; p += (size_t)9216 * 2048 * 2;
    u16* qb    = (u16*)p; p += (size_t)4096 * 1024 * 2;
    u16* kvin  = (u16*)p; p += (size_t)9216 * 1024 * 2;   // becomes vt AFTER all kvin readers done
    u16* wkvt  = (u16*)p; p += (size_t)2048 * 1024 * 2;
    u16* wqt   = (u16*)p; p += (size_t)1024 * 1024 * 2;
    u16* woutt = (u16*)p; p += (size_t)1024 * 1024 * 2;
    u16* w2t   = (u16*)p; p += (size_t)1024 * 4096 * 2;   // becomes cvt AFTER compress GEMM
    u16* peb   = (u16*)p; p += (size_t)16 * 2304 * 64 * 2;
    u16* xb    = (u16*)p; p += (size_t)4096 * 1024 * 2;   // unused (spare)
    u16* memb  = (u16*)p; p += (size_t)4096 * 1024 * 2;
    u16* cmpb  = (u16*)p; p += (size_t)1024 * 1024 * 2;
    u16* ckcvb = (u16*)p; p += (size_t)1024 * 2048 * 2;
    u16* aob   = (u16*)p; p += (size_t)4096 * 1024 * 2;
    float* acc = (float*)p;
    u16* vt   = kvin;          // 4096 x 2304 u16, exact fit
    u16* cvt  = w2t;           // 4096 x 256 u16, fits
    (void)xb; (void)memb;

    hipMemcpyAsync(new_mem, x, (size_t)4194304 * sizeof(float),
                   hipMemcpyDeviceToDevice, stream);

    cvt_bf16<<<2304, 256, 0, stream>>>(pos, peb, 589824);
    concat_bf16<<<9216, 256, 0, stream>>>(x, mem, cmem, kvin);
    transpose_bf16<<<dim3(64, 32), 256, 0, stream>>>(Wkv, wkvt, 1024, 2048);
    transpose_bf16<<<dim3(32, 32), 256, 0, stream>>>(Wq, wqt, 1024, 1024);
    transpose_bf16<<<dim3(32, 32), 256, 0, stream>>>(Wout, woutt, 1024, 1024);
    w2t_bf16<<<16384, 256, 0, stream>>>(convw, w2t);

    // ---- all kvin readers FIRST (kvin is clobbered by transpose_v below) ----
    // kv GEMM: ny=72, nx=16
    gemm_bf16<<<1152, 256, 0, stream>>>(kvin, wkvt, nullptr, nullptr, kvb, 9216, 2048, 1024, 1.f, 0, 10, 4);
    // Q = x @ Wq; A = kvin rows 1280.. per 2304-row batch; ny=32, nx=8
    gemm_bf16<<<256, 256, 0, stream>>>(kvin + (size_t)1280 * 1024, wqt, nullptr, nullptr, qb,
                                       4096, 1024, 1024, C2, 1280, 10, 3);
    // compressed = mem @ W2 + convb; A = kvin rows 256.. (256-row batches, K=4096); ny=8, nx=8
    gemm_bf16<<<64, 256, 0, stream>>>(kvin + (size_t)256 * 1024, w2t, convb, new_cmem, cmpb,
                                      1024, 1024, 4096, 1.f, 320, 8, 3);
    // ckcv: ny=8, nx=16
    gemm_bf16<<<128, 256, 0, stream>>>(cmpb, wkvt, nullptr, nullptr, ckcvb, 1024, 2048, 1024, 1.f, 0, 10, 4);

    // ---- now kvin and w2t are dead: overlay with vt / cvt ----
    transpose_v<<<dim3(36, 64), 256, 0, stream>>>(kvb, 2304, vt);
    transpose_v<<<dim3(4, 64), 256, 0, stream>>>(ckcvb, 256, cvt);

    hipMemsetAsync(acc, 0, sizeof(float), stream);
    attn_main_fused<<<1024, 256, 0, stream>>>(qb, kvb, vt, peb, ckcvb, cvt, aob, acc);
    // out GEMM: ny=32, nx=8
    gemm_bf16<<<256, 256, 0, stream>>>(aob, woutt, bout, logits, nullptr, 4096, 1024, 1024, 1.f, 0, 10, 3);

    finish_aux<<<1, 1, 0, stream>>>(acc, aux_out);
}

// Round 14
// 419.188 us; speedup vs baseline: 1.3379x; 1.1003x over previous
//
#include <hip/hip_runtime.h>
#include <hip/hip_bf16.h>
#include <cstddef>

typedef unsigned short u16;
typedef __attribute__((ext_vector_type(8))) short bf16x8;
typedef __attribute__((ext_vector_type(4))) float f32x4;

#define C2 0.18033688011112042f   // 0.125 * log2(e)

__device__ __forceinline__ u16 f2b(float f) {
    unsigned u = __builtin_bit_cast(unsigned, f);
    unsigned r = (u + 0x7FFF + ((u >> 16) & 1)) >> 16;
    return (u16)r;
}

__device__ __forceinline__ float exp2a(float x) {
    float r; asm("v_exp_f32 %0, %1" : "=v"(r) : "v"(x)); return r;
}

__device__ __forceinline__ unsigned cvtpk(float lo, float hi) {
    unsigned r; asm("v_cvt_pk_bf16_f32 %0, %1, %2" : "=v"(r) : "v"(lo), "v"(hi));
    return r;
}

__device__ __forceinline__ void gload_lds16(const void* g, void* l) {
    __builtin_amdgcn_global_load_lds(
        (const __attribute__((address_space(1))) unsigned int*)g,
        (__attribute__((address_space(3))) unsigned int*)l, 16, 0, 0);
}

#define VDRAIN() asm volatile("s_waitcnt vmcnt(0)" ::: "memory")
#define SBAR() do { __builtin_amdgcn_sched_barrier(0); __builtin_amdgcn_s_barrier(); } while (0)

// ---------------- fused prep: cvt(pos) | concat | W transposes | w2t ----------------
__device__ __forceinline__ void transpose_body(
    const float* __restrict__ in, u16* __restrict__ out, int K, int N,
    int bx, int by, float (*t)[33], int tid)
{
    int k0 = by * 32, n0 = bx * 32;
    int tx = tid & 31, ty = tid >> 5;
    #pragma unroll
    for (int p = 0; p < 4; ++p)
        t[ty + 8 * p][tx] = in[(size_t)(k0 + ty + 8 * p) * N + n0 + tx];
    __syncthreads();
    #pragma unroll
    for (int p = 0; p < 4; ++p)
        out[(size_t)(n0 + ty + 8 * p) * K + k0 + tx] = f2b(t[tx][ty + 8 * p]);
}

__global__ __launch_bounds__(256) void megaprep(
    const float* __restrict__ pos, u16* __restrict__ peb,
    const float* __restrict__ x, const float* __restrict__ mem,
    const float* __restrict__ cmem, u16* __restrict__ kvin,
    const float* __restrict__ Wkv, u16* __restrict__ wkvt,
    const float* __restrict__ Wq, u16* __restrict__ wqt,
    const float* __restrict__ Wout, u16* __restrict__ woutt,
    const float* __restrict__ convw, u16* __restrict__ w2t)
{
    __shared__ float t[32][33];
    const int bid = blockIdx.x, tid = threadIdx.x;
    if (bid < 2304) {                         // cvt pos: 589824 float4
        int i = bid * 256 + tid;
        float4 v = ((const float4*)pos)[i];
        union { u16 s[4]; uint2 u; } pk;
        pk.s[0] = f2b(v.x); pk.s[1] = f2b(v.y); pk.s[2] = f2b(v.z); pk.s[3] = f2b(v.w);
        ((uint2*)peb)[i] = pk.u;
    } else if (bid < 11520) {                 // concat kv_input
        int rowg = bid - 2304;
        int b = rowg / 2304, rr = rowg % 2304;
        const float* src = (rr < 256)  ? cmem + ((size_t)b * 256 + rr) * 1024
                         : (rr < 1280) ? mem  + ((size_t)b * 1024 + (rr - 256)) * 1024
                                       : x    + ((size_t)b * 1024 + (rr - 1280)) * 1024;
        float4 v = ((const float4*)src)[tid];
        union { u16 s[4]; uint2 u; } pk;
        pk.s[0] = f2b(v.x); pk.s[1] = f2b(v.y); pk.s[2] = f2b(v.z); pk.s[3] = f2b(v.w);
        ((uint2*)(kvin + (size_t)rowg * 1024))[tid] = pk.u;
    } else if (bid < 13568) {                 // Wkv^T (N=2048: 64x32 blocks)
        int m = bid - 11520;
        transpose_body(Wkv, wkvt, 1024, 2048, m % 64, m / 64, t, tid);
    } else if (bid < 14592) {                 // Wq^T
        int m = bid - 13568;
        transpose_body(Wq, wqt, 1024, 1024, m % 32, m / 32, t, tid);
    } else if (bid < 15616) {                 // Wout^T
        int m = bid - 14592;
        transpose_body(Wout, woutt, 1024, 1024, m % 32, m / 32, t, tid);
    } else {                                  // w2t: conv_w[o,i,r] -> w2t[o][r*1024+i]
        int m = bid - 15616;                  // 4096 blocks
        int pidx = m * 256 + tid;             // (o,i) pair
        int o = pidx >> 10, i = pidx & 1023;
        float4 v = *(const float4*)(convw + ((size_t)o << 12) + 4 * i);
        size_t base = (size_t)o * 4096 + i;
        w2t[base]          = f2b(v.x);
        w2t[base + 1024]   = f2b(v.y);
        w2t[base + 2048]   = f2b(v.z);
        w2t[base + 3072]   = f2b(v.w);
    }
}

// ---------------- merged V transposes ----------------
__global__ __launch_bounds__(256) void transpose_v2(
    const u16* __restrict__ src1, u16* __restrict__ dst1,   // main, R=2304
    const u16* __restrict__ src2, u16* __restrict__ dst2)   // compressed, R=256
{
    __shared__ u16 t[64 * 65];
    const int bid = blockIdx.x, tid = threadIdx.x;
    const u16* src; u16* dst; int R, bh, j0;
    if (bid < 2304) { src = src1; dst = dst1; R = 2304; bh = bid / 36; j0 = (bid % 36) * 64; }
    else { int m = bid - 2304; src = src2; dst = dst2; R = 256; bh = m / 4; j0 = (m % 4) * 64; }
    const int b = bh >> 4, h = bh & 15;
    #pragma unroll
    for (int p = 0; p < 2; ++p) {
        int idx = tid + p * 256;
        int j = idx >> 3, c = idx & 7;
        uint4 v = *(const uint4*)(src + ((size_t)(b * R + j0 + j)) * 2048 + 1024 + h * 64 + c * 8);
        const u16* vv = (const u16*)&v;
        #pragma unroll
        for (int u2 = 0; u2 < 8; ++u2) t[j * 65 + c * 8 + u2] = vv[u2];
    }
    __syncthreads();
    #pragma unroll
    for (int p = 0; p < 2; ++p) {
        int idx = tid + p * 256;
        int jc = idx & 7, d = idx >> 3;
        union { u16 s[8]; uint4 u; } pk;
        #pragma unroll
        for (int u2 = 0; u2 < 8; ++u2) pk.s[u2] = t[(jc * 8 + u2) * 65 + d];
        *(uint4*)(dst + ((size_t)(bh * 64 + d)) * (size_t)R + j0 + jc * 8) = pk.u;
    }
}

// ---------------- bf16 MFMA GEMM body (XCD-bijective linear decode) ----------------
__device__ __forceinline__ void gemm_body(
    const u16* __restrict__ A, const u16* __restrict__ Bt,
    const float* __restrict__ bias, float* __restrict__ Cf,
    u16* __restrict__ Cb, int N, int K, float cscale,
    int apad, int ashift, int nxshift, int nyper, int id,
    u16* Al, u16* Bl)
{
    const int tid = threadIdx.x, w = tid >> 6, lane = tid & 63;
    const int lr = lane & 15, lg = lane >> 4;
    const int xcd = id & 7, s = id >> 3;
    const int bx = s & ((1 << nxshift) - 1);
    const int by = nyper * xcd + (s >> nxshift);
    const int bm0 = by * 128, bn0 = bx * 128;
    const int wr = (w >> 1) * 64, wc = (w & 1) * 64;

    f32x4 acc[4][4];
    const f32x4 z = {0.f, 0.f, 0.f, 0.f};
    #pragma unroll
    for (int mb = 0; mb < 4; ++mb)
        #pragma unroll
        for (int nb = 0; nb < 4; ++nb) acc[mb][nb] = z;

    for (int k0 = 0; k0 < K; k0 += 32) {
        __syncthreads();
        #pragma unroll
        for (int q = 0; q < 2; ++q) {
            int chunk = w * 2 + q;
            int row = bm0 + chunk * 16 + (lane >> 2);
            int arow = row + ((row >> ashift) * apad);
            int sg = (lane & 3) * 8;
            gload_lds16(A + (size_t)arow * K + k0 + sg, &Al[chunk * 512]);
            gload_lds16(Bt + (size_t)(bn0 + chunk * 16 + (lane >> 2)) * K + k0 + sg, &Bl[chunk * 512]);
        }
        __syncthreads();
        bf16x8 af[4], bf[4];
        #pragma unroll
        for (int mb = 0; mb < 4; ++mb)
            af[mb] = *(const bf16x8*)&Al[(wr + mb * 16 + lr) * 32 + lg * 8];
        #pragma unroll
        for (int nb = 0; nb < 4; ++nb)
            bf[nb] = *(const bf16x8*)&Bl[(wc + nb * 16 + lr) * 32 + lg * 8];
        #pragma unroll
        for (int mb = 0; mb < 4; ++mb)
            #pragma unroll
            for (int nb = 0; nb < 4; ++nb)
                acc[mb][nb] = __builtin_amdgcn_mfma_f32_16x16x32_bf16(
                    af[mb], bf[nb], acc[mb][nb], 0, 0, 0);
    }

    #pragma unroll
    for (int mb = 0; mb < 4; ++mb)
        #pragma unroll
        for (int nb = 0; nb < 4; ++nb)
            #pragma unroll
            for (int jr = 0; jr < 4; ++jr) {
                int row = bm0 + wr + mb * 16 + lg * 4 + jr;
                int col = bn0 + wc + nb * 16 + lr;
                float v = acc[mb][nb][jr] + (bias ? bias[col] : 0.f);
                if (Cf) Cf[(size_t)row * N + col] = v;
                if (Cb) Cb[(size_t)row * N + col] = f2b(v * cscale);
            }
}

__global__ __launch_bounds__(256) void gemm_bf16(
    const u16* __restrict__ A, const u16* __restrict__ Bt,
    const float* __restrict__ bias, float* __restrict__ Cf,
    u16* __restrict__ Cb, int N, int K, float cscale,
    int apad, int ashift, int nxshift, int nyper)
{
    __shared__ u16 Al[128 * 32];
    __shared__ u16 Bl[128 * 32];
    gemm_body(A, Bt, bias, Cf, Cb, N, K, cscale, apad, ashift, nxshift, nyper,
              blockIdx.x, Al, Bl);
}

// two independent GEMMs in one launch (blocks [0,split) -> set a, rest -> set b)
__global__ __launch_bounds__(256) void gemm_dual(
    const u16* Aa, const u16* Bta, const float* biasa, float* Cfa, u16* Cba,
    int Na, int Ka, float csa, int apa, int asa, int nxa, int nya, int split,
    const u16* Ab, const u16* Btb, const float* biasb, float* Cfb, u16* Cbb,
    int Nb, int Kb, float csb, int apb, int asb, int nxb, int nyb)
{
    __shared__ u16 Al[128 * 32];
    __shared__ u16 Bl[128 * 32];
    if ((int)blockIdx.x < split)
        gemm_body(Aa, Bta, biasa, Cfa, Cba, Na, Ka, csa, apa, asa, nxa, nya,
                  blockIdx.x, Al, Bl);
    else
        gemm_body(Ab, Btb, biasb, Cfb, Cbb, Nb, Kb, csb, apb, asb, nxb, nyb,
                  blockIdx.x - split, Al, Bl);
}

// ---------------- fused main attention + FULL aux loss ----------------
__global__ __launch_bounds__(256) void attn_main_fused(
    const u16* __restrict__ qb,    // (4,1024,1024) bf16, pre-scaled by C2
    const u16* __restrict__ kvb,   // (4,2304,2048) bf16 k|v
    const u16* __restrict__ vt,    // (64bh*64d, 2304) bf16  V^T
    const u16* __restrict__ peb,   // (16,2304,64) bf16
    const u16* __restrict__ ckcv,  // (4,256,2048) bf16 compressed k|v
    const u16* __restrict__ cvt,   // (64bh*64d, 256) bf16 compressed V^T
    u16* __restrict__ outb,        // (4,1024,1024) bf16
    float* __restrict__ acc)       // aux loss accumulator
{
    __shared__ u16 kbuf[64 * 64];
    __shared__ u16 vbuf[64 * 64];
    __shared__ u16 pering[128 * 64];
    __shared__ u16 pls[4][1024];
    __shared__ float red[4];

    const int tid = threadIdx.x;
    const int w = tid >> 6, lane = tid & 63;
    const int lr = lane & 15, lg = lane >> 4;
    const int rl = lane >> 3, cch = lane & 7;
    const int id = blockIdx.x;
    const int slot = id >> 3;
    const int bh = (id & 7) + ((slot >> 4) << 3);
    const int b = bh >> 4, h = bh & 15;
    const int i0 = (15 - (slot & 15)) * 64;   // LPT: longest (i0=960) first
    const int iw = i0 + 16 * w;
    const int jb0 = 960 - i0;

    const int lrh = lr >> 3, lrm = lr & 7;
    int pwidx[4], pridx[2];
    #pragma unroll
    for (int nb = 0; nb < 4; ++nb)
        pwidx[nb] = (((nb * 2 + lrh) ^ (lg * 2)) * 8) + lrm;
    #pragma unroll
    for (int ks = 0; ks < 2; ++ks)
        pridx[ks] = lr * 64 + (((ks * 4 + lg) ^ ((lr >> 2) * 2)) * 8);

    bf16x8 qf[2];
    #pragma unroll
    for (int ks = 0; ks < 2; ++ks)
        qf[ks] = *(const bf16x8*)(qb + ((size_t)(b * 1024 + iw + lr)) * 1024
                                  + h * 64 + ks * 32 + lg * 8);

    const f32x4 z = {0.f, 0.f, 0.f, 0.f};
    f32x4 od[4], od2[4];
    float lloc[4], ll2[4];
    #pragma unroll
    for (int nb = 0; nb < 4; ++nb) { od[nb] = z; od2[nb] = z; }
    #pragma unroll
    for (int jr = 0; jr < 4; ++jr) { lloc[jr] = 0.f; ll2[jr] = 0.f; }

    // ---- prologue: K(0), V(0), full 128-row PE band ----
    #pragma unroll
    for (int q = 0; q < 2; ++q) {
        int row = 16 * w + 8 * q + rl;
        gload_lds16(kvb + ((size_t)(b * 2304 + row)) * 2048 + h * 64 + ((cch ^ rl) * 8),
                    &kbuf[(16 * w + 8 * q) * 64]);
        gload_lds16(vt + ((size_t)(bh * 64 + row)) * 2304 + ((cch ^ rl) * 8),
                    &vbuf[(16 * w + 8 * q) * 64]);
    }
    #pragma unroll
    for (int q = 0; q < 4; ++q) {
        int rr = 32 * w + 8 * q;
        int a = jb0 + rr + rl;
        int srow = a > 2303 ? 2303 : a;
        gload_lds16(peb + ((size_t)(h * 2304 + srow)) * 64 + ((cch ^ rl) * 8),
                    &pering[((jb0 + rr) & 127) * 64]);
    }
    VDRAIN();
    __syncthreads();

    const int nt = ((i0 + 1343) >> 6) + 1;
    for (int t = 0; t < nt; ++t) {
        const int j0 = t * 64;
        const int jb = jb0 + j0;
        const bool more = (t + 1 < nt);

        f32x4 qk[4], qp[5];
        #pragma unroll
        for (int nb = 0; nb < 4; ++nb) qk[nb] = z;
        #pragma unroll
        for (int f = 0; f < 5; ++f) qp[f] = z;
        __builtin_amdgcn_s_setprio(1);
        #pragma unroll
        for (int ks = 0; ks < 2; ++ks) {
            #pragma unroll
            for (int nb = 0; nb < 4; ++nb) {
                int row = nb * 16 + lr;
                bf16x8 kb = *(const bf16x8*)&kbuf[row * 64 + (((4 * ks + lg) ^ (row & 7)) * 8)];
                qk[nb] = __builtin_amdgcn_mfma_f32_16x16x32_bf16(qf[ks], kb, qk[nb], 0, 0, 0);
            }
            #pragma unroll
            for (int f = 0; f < 5; ++f) {
                int rel = 48 - 16 * w + f * 16 + lr;
                int slotp = (jb + rel) & 127;
                bf16x8 pb = *(const bf16x8*)&pering[slotp * 64 + (((4 * ks + lg) ^ (slotp & 7)) * 8)];
                qp[f] = __builtin_amdgcn_mfma_f32_16x16x32_bf16(qf[ks], pb, qp[f], 0, 0, 0);
            }
        }
        __builtin_amdgcn_s_setprio(0);

        VDRAIN();
        SBAR();     // B: publishes V(t); certifies kbuf/pering reads of tile t

        if (more) {
            const int j0n = j0 + 64;
            #pragma unroll
            for (int q = 0; q < 2; ++q) {
                int row = 16 * w + 8 * q + rl;
                gload_lds16(kvb + ((size_t)(b * 2304 + j0n + row)) * 2048 + h * 64 + ((cch ^ rl) * 8),
                            &kbuf[(16 * w + 8 * q) * 64]);
            }
            const int A0 = jb + 128;
            #pragma unroll
            for (int q = 0; q < 2; ++q) {
                int rr = A0 + 16 * w + 8 * q;
                int a = rr + rl;
                int srow = a > 2303 ? 2303 : a;
                gload_lds16(peb + ((size_t)(h * 2304 + srow)) * 64 + ((cch ^ rl) * 8),
                            &pering[(rr & 127) * 64]);
            }
        }

        const bool nomask = (j0 + 63 <= iw + 1280);
        #pragma unroll
        for (int jr = 0; jr < 4; ++jr) {
            const int r = lg * 4 + jr;
            const int ia = iw + r;
            const int src = (lane & 48) | ((lr + 15 - r) & 15);
            float rot0 = __shfl(qp[0][jr], src);
            float rot1 = __shfl(qp[1][jr], src);
            float rot2 = __shfl(qp[2][jr], src);
            float rot3 = __shfl(qp[3][jr], src);
            float rot4 = __shfl(qp[4][jr], src);
            const bool hi = (lr > r);
            float s0 = qk[0][jr] + (hi ? rot1 : rot0);
            float s1 = qk[1][jr] + (hi ? rot2 : rot1);
            float s2 = qk[2][jr] + (hi ? rot3 : rot2);
            float s3 = qk[3][jr] + (hi ? rot4 : rot3);
            if (!nomask) {
                s0 = (j0 + lr      <= ia + 1280) ? s0 : -1e30f;
                s1 = (j0 + lr + 16 <= ia + 1280) ? s1 : -1e30f;
                s2 = (j0 + lr + 32 <= ia + 1280) ? s2 : -1e30f;
                s3 = (j0 + lr + 48 <= ia + 1280) ? s3 : -1e30f;
            }
            float p0 = exp2a(s0), p1 = exp2a(s1);
            float p2 = exp2a(s2), p3 = exp2a(s3);
            unsigned pkA = cvtpk(p0, p1), pkB = cvtpk(p2, p3);
            u16* pw = &pls[w][r * 64];
            pw[pwidx[0]] = (u16)pkA; pw[pwidx[1]] = (u16)(pkA >> 16);
            pw[pwidx[2]] = (u16)pkB; pw[pwidx[3]] = (u16)(pkB >> 16);
            lloc[jr] += (p0 + p1) + (p2 + p3);
        }

        __builtin_amdgcn_s_setprio(1);
        #pragma unroll
        for (int ks = 0; ks < 2; ++ks) {
            bf16x8 pa = *(const bf16x8*)&pls[w][pridx[ks]];
            #pragma unroll
            for (int nb = 0; nb < 4; ++nb) {
                int d = nb * 16 + lr;
                bf16x8 vb = *(const bf16x8*)&vbuf[d * 64 + (((4 * ks + lg) ^ (d & 7)) * 8)];
                od[nb] = __builtin_amdgcn_mfma_f32_16x16x32_bf16(pa, vb, od[nb], 0, 0, 0);
            }
        }
        __builtin_amdgcn_s_setprio(0);

        if (t >= 4 && t <= 19) {
            #pragma unroll
            for (int jr = 0; jr < 4; ++jr) {
                const int r = lg * 4 + jr;
                float p0 = exp2a(qk[0][jr]), p1 = exp2a(qk[1][jr]);
                float p2 = exp2a(qk[2][jr]), p3 = exp2a(qk[3][jr]);
                unsigned pkA = cvtpk(p0, p1), pkB = cvtpk(p2, p3);
                u16* pw = &pls[w][r * 64];
                pw[pwidx[0]] = (u16)pkA; pw[pwidx[1]] = (u16)(pkA >> 16);
                pw[pwidx[2]] = (u16)pkB; pw[pwidx[3]] = (u16)(pkB >> 16);
                ll2[jr] += (p0 + p1) + (p2 + p3);
            }
            __builtin_amdgcn_s_setprio(1);
            #pragma unroll
            for (int ks = 0; ks < 2; ++ks) {
                bf16x8 pa = *(const bf16x8*)&pls[w][pridx[ks]];
                #pragma unroll
                for (int nb = 0; nb < 4; ++nb) {
                    int d = nb * 16 + lr;
                    bf16x8 vb = *(const bf16x8*)&vbuf[d * 64 + (((4 * ks + lg) ^ (d & 7)) * 8)];
                    od2[nb] = __builtin_amdgcn_mfma_f32_16x16x32_bf16(pa, vb, od2[nb], 0, 0, 0);
                }
            }
            __builtin_amdgcn_s_setprio(0);
        }

        VDRAIN();
        SBAR();     // C: publishes kbuf=K(t+1), pering; certifies vbuf/pls reads

        if (more) {
            const int j0n = j0 + 64;
            #pragma unroll
            for (int q = 0; q < 2; ++q) {
                int row = 16 * w + 8 * q + rl;
                gload_lds16(vt + ((size_t)(bh * 64 + row)) * 2304 + j0n + ((cch ^ rl) * 8),
                            &vbuf[(16 * w + 8 * q) * 64]);
            }
        }
    }

    // ---- main epilogue (frees od/lloc) ----
    #pragma unroll
    for (int jr = 0; jr < 4; ++jr) {
        float l = lloc[jr];
        #pragma unroll
        for (int mk = 1; mk < 16; mk <<= 1) l += __shfl_xor(l, mk);
        float inv = 1.f / l;
        int ia = iw + lg * 4 + jr;
        #pragma unroll
        for (int nb = 0; nb < 4; ++nb)
            outb[((size_t)(b * 1024 + ia)) * 1024 + h * 64 + nb * 16 + lr] =
                f2b(od[nb][jr] * inv);
    }
    // ---- aux phase-0 finalize in registers ----
    #pragma unroll
    for (int jr = 0; jr < 4; ++jr) {
        float l = ll2[jr];
        #pragma unroll
        for (int mk = 1; mk < 16; mk <<= 1) l += __shfl_xor(l, mk);
        float inv = 1.f / l;
        #pragma unroll
        for (int nb = 0; nb < 4; ++nb) od2[nb][jr] *= inv;
    }

    // ---- aux phase-1: compressed KV (4 tiles), reuse od/lloc ----
    #pragma unroll
    for (int nb = 0; nb < 4; ++nb) od[nb] = z;
    #pragma unroll
    for (int jr = 0; jr < 4; ++jr) lloc[jr] = 0.f;
    const u16* kbase = ckcv + ((size_t)(b * 256)) * 2048 + h * 64;
    const u16* vbase = cvt + ((size_t)(bh * 64)) * 256;

    for (int t = 0; t < 4; ++t) {
        const int j0 = t * 64;
        __syncthreads();
        #pragma unroll
        for (int q = 0; q < 2; ++q) {
            int row = 16 * w + 8 * q + rl;
            gload_lds16(kbase + (size_t)(j0 + row) * 2048 + ((cch ^ rl) * 8),
                        &kbuf[(16 * w + 8 * q) * 64]);
            gload_lds16(vbase + (size_t)row * 256 + j0 + ((cch ^ rl) * 8),
                        &vbuf[(16 * w + 8 * q) * 64]);
        }
        VDRAIN();
        __syncthreads();

        f32x4 qk[4];
        #pragma unroll
        for (int nb = 0; nb < 4; ++nb) qk[nb] = z;
        #pragma unroll
        for (int ks = 0; ks < 2; ++ks)
            #pragma unroll
            for (int nb = 0; nb < 4; ++nb) {
                int row = nb * 16 + lr;
                bf16x8 kb = *(const bf16x8*)&kbuf[row * 64 + (((4 * ks + lg) ^ (row & 7)) * 8)];
                qk[nb] = __builtin_amdgcn_mfma_f32_16x16x32_bf16(qf[ks], kb, qk[nb], 0, 0, 0);
            }

        #pragma unroll
        for (int jr = 0; jr < 4; ++jr) {
            const int r = lg * 4 + jr;
            float p0 = exp2a(qk[0][jr]), p1 = exp2a(qk[1][jr]);
            float p2 = exp2a(qk[2][jr]), p3 = exp2a(qk[3][jr]);
            unsigned pkA = cvtpk(p0, p1), pkB = cvtpk(p2, p3);
            u16* pw = &pls[w][r * 64];
            pw[pwidx[0]] = (u16)pkA; pw[pwidx[1]] = (u16)(pkA >> 16);
            pw[pwidx[2]] = (u16)pkB; pw[pwidx[3]] = (u16)(pkB >> 16);
            lloc[jr] += (p0 + p1) + (p2 + p3);
        }

        #pragma unroll
        for (int ks = 0; ks < 2; ++ks) {
            bf16x8 pa = *(const bf16x8*)&pls[w][pridx[ks]];
            #pragma unroll
            for (int nb = 0; nb < 4; ++nb) {
                int d = nb * 16 + lr;
                bf16x8 vb = *(const bf16x8*)&vbuf[d * 64 + (((4 * ks + lg) ^ (d & 7)) * 8)];
                od[nb] = __builtin_amdgcn_mfma_f32_16x16x32_bf16(pa, vb, od[nb], 0, 0, 0);
            }
        }
    }

    float local = 0.f;
    #pragma unroll
    for (int jr = 0; jr < 4; ++jr) {
        float l = lloc[jr];
        #pragma unroll
        for (int mk = 1; mk < 16; mk <<= 1) l += __shfl_xor(l, mk);
        float inv = 1.f / l;
        #pragma unroll
        for (int nb = 0; nb < 4; ++nb) {
            float d = od2[nb][jr] - od[nb][jr] * inv;
            local += d * d;
        }
    }
    #pragma unroll
    for (int mk = 1; mk < 64; mk <<= 1) local += __shfl_xor(local, mk);
    if (lane == 0) red[w] = local;
    __syncthreads();
    if (tid == 0) atomicAdd(acc, red[0] + red[1] + red[2] + red[3]);
}

__global__ void finish_aux(const float* __restrict__ acc, float* __restrict__ out)
{
    out[0] = acc[0] * (1.0f / 4194304.0f);
}

// ---------------- launch ----------------
extern "C" void kernel_launch(void* const* d_in, const int* in_sizes, int n_in,
                              void* d_out, int out_size, void* d_ws, size_t ws_size,
                              hipStream_t stream)
{
    const float* x     = (const float*)d_in[0];
    const float* mem   = (const float*)d_in[1];
    const float* cmem  = (const float*)d_in[2];
    const float* pos   = (const float*)d_in[3];
    const float* Wq    = (const float*)d_in[5];
    const float* Wkv   = (const float*)d_in[6];
    const float* Wout  = (const float*)d_in[7];
    const float* bout  = (const float*)d_in[8];
    const float* convw = (const float*)d_in[9];
    const float* convb = (const float*)d_in[10];

    float* out      = (float*)d_out;
    float* logits   = out;
    float* new_mem  = out + 4194304;
    float* new_cmem = out + 8388608;
    float* aux_out  = out + 9437184;

    char* p = (char*)d_ws;
    u16* kvb   = (u16*)p; p += (size_t)9216 * 2048 * 2;
    u16* qb    = (u16*)p; p += (size_t)4096 * 1024 * 2;
    u16* kvin  = (u16*)p; p += (size_t)9216 * 1024 * 2;   // becomes vt AFTER all kvin readers done
    u16* wkvt  = (u16*)p; p += (size_t)2048 * 1024 * 2;
    u16* wqt   = (u16*)p; p += (size_t)1024 * 1024 * 2;
    u16* woutt = (u16*)p; p += (size_t)1024 * 1024 * 2;
    u16* w2t   = (u16*)p; p += (size_t)1024 * 4096 * 2;   // becomes cvt AFTER compress GEMM
    u16* peb   = (u16*)p; p += (size_t)16 * 2304 * 64 * 2;
    u16* xb    = (u16*)p; p += (size_t)4096 * 1024 * 2;   // spare
    u16* memb  = (u16*)p; p += (size_t)4096 * 1024 * 2;
    u16* cmpb  = (u16*)p; p += (size_t)1024 * 1024 * 2;
    u16* ckcvb = (u16*)p; p += (size_t)1024 * 2048 * 2;
    u16* aob   = (u16*)p; p += (size_t)4096 * 1024 * 2;
    float* acc = (float*)p;
    u16* vt   = kvin;          // 4096 x 2304 u16, exact fit
    u16* cvt  = w2t;           // 4096 x 256 u16, fits
    (void)xb; (void)memb;

    hipMemcpyAsync(new_mem, x, (size_t)4194304 * sizeof(float),
                   hipMemcpyDeviceToDevice, stream);

    // one launch: cvt(pos) | concat | Wkv^T | Wq^T | Wout^T | w2t  (19712 blocks)
    megaprep<<<19712, 256, 0, stream>>>(pos, peb, x, mem, cmem, kvin,
                                        Wkv, wkvt, Wq, wqt, Wout, woutt, convw, w2t);

    // kv GEMM: ny=72 (nyper 9), nx=16
    gemm_bf16<<<1152, 256, 0, stream>>>(kvin, wkvt, nullptr, nullptr, kvb,
                                        2048, 1024, 1.f, 0, 10, 4, 9);
    // Q GEMM (256 blocks) || compress GEMM (64 blocks) in one launch
    gemm_dual<<<320, 256, 0, stream>>>(
        kvin + (size_t)1280 * 1024, wqt, nullptr, nullptr, qb,
        1024, 1024, C2, 1280, 10, 3, 4, 256,
        kvin + (size_t)256 * 1024, w2t, convb, new_cmem, cmpb,
        1024, 4096, 1.f, 320, 8, 3, 1);
    // ckcv: ny=8 (nyper 1), nx=16
    gemm_bf16<<<128, 256, 0, stream>>>(cmpb, wkvt, nullptr, nullptr, ckcvb,
                                       2048, 1024, 1.f, 0, 10, 4, 1);

    // merged V transposes (kvin/w2t dead now -> vt/cvt overlays)
    transpose_v2<<<2560, 256, 0, stream>>>(kvb, vt, ckcvb, cvt);

    hipMemsetAsync(acc, 0, sizeof(float), stream);
    attn_main_fused<<<1024, 256, 0, stream>>>(qb, kvb, vt, peb, ckcvb, cvt, aob, acc);
    // out GEMM: ny=32 (nyper 4), nx=8
    gemm_bf16<<<256, 256, 0, stream>>>(aob, woutt, bout, logits, nullptr,
                                       1024, 1024, 1.f, 0, 10, 3, 4);

    finish_aux<<<1, 1, 0, stream>>>(acc, aux_out);
}

// Round 15
// 362.691 us; speedup vs baseline: 1.5464x; 1.1558x over previous
//
#include <hip/hip_runtime.h>
#include <hip/hip_bf16.h>
#include <cstddef>

typedef unsigned short u16;
typedef __attribute__((ext_vector_type(8))) short bf16x8;
typedef __attribute__((ext_vector_type(4))) float f32x4;

#define C2 0.18033688011112042f   // 0.125 * log2(e)

__device__ __forceinline__ u16 f2b(float f) {
    unsigned u = __builtin_bit_cast(unsigned, f);
    unsigned r = (u + 0x7FFF + ((u >> 16) & 1)) >> 16;
    return (u16)r;
}

__device__ __forceinline__ float exp2a(float x) {
    float r; asm("v_exp_f32 %0, %1" : "=v"(r) : "v"(x)); return r;
}

__device__ __forceinline__ unsigned cvtpk(float lo, float hi) {
    unsigned r; asm("v_cvt_pk_bf16_f32 %0, %1, %2" : "=v"(r) : "v"(lo), "v"(hi));
    return r;
}

__device__ __forceinline__ void gload_lds16(const void* g, void* l) {
    __builtin_amdgcn_global_load_lds(
        (const __attribute__((address_space(1))) unsigned int*)g,
        (__attribute__((address_space(3))) unsigned int*)l, 16, 0, 0);
}

#define VDRAIN() asm volatile("s_waitcnt vmcnt(0)" ::: "memory")
#define SBAR() do { __builtin_amdgcn_sched_barrier(0); __builtin_amdgcn_s_barrier(); } while (0)

// ---------------- fused prep ----------------
__device__ __forceinline__ void transpose_body(
    const float* __restrict__ in, u16* __restrict__ out, int K, int N,
    int bx, int by, float (*t)[33], int tid)
{
    int k0 = by * 32, n0 = bx * 32;
    int tx = tid & 31, ty = tid >> 5;
    #pragma unroll
    for (int p = 0; p < 4; ++p)
        t[ty + 8 * p][tx] = in[(size_t)(k0 + ty + 8 * p) * N + n0 + tx];
    __syncthreads();
    #pragma unroll
    for (int p = 0; p < 4; ++p)
        out[(size_t)(n0 + ty + 8 * p) * K + k0 + tx] = f2b(t[tx][ty + 8 * p]);
}

// copy(new_mem=x) | cvt(pos) | concat | Wkv^T | Wq^T | Wout^T | w2t | zero(acc)
__global__ __launch_bounds__(256) void megaprep(
    const float* __restrict__ pos, u16* __restrict__ peb,
    const float* __restrict__ x, const float* __restrict__ mem,
    const float* __restrict__ cmem, u16* __restrict__ kvin,
    const float* __restrict__ Wkv, u16* __restrict__ wkvt,
    const float* __restrict__ Wq, u16* __restrict__ wqt,
    const float* __restrict__ Wout, u16* __restrict__ woutt,
    const float* __restrict__ convw, u16* __restrict__ w2t,
    float* __restrict__ new_mem, float* __restrict__ acc)
{
    __shared__ float t[32][33];
    const int bid = blockIdx.x, tid = threadIdx.x;
    if (bid == 0 && tid == 0) acc[0] = 0.f;
    if (bid < 4096) {                         // new_mem = x (fp32 copy)
        int i = bid * 256 + tid;
        ((float4*)new_mem)[i] = ((const float4*)x)[i];
    } else if (bid < 6400) {                  // cvt pos
        int i = (bid - 4096) * 256 + tid;
        float4 v = ((const float4*)pos)[i];
        union { u16 s[4]; uint2 u; } pk;
        pk.s[0] = f2b(v.x); pk.s[1] = f2b(v.y); pk.s[2] = f2b(v.z); pk.s[3] = f2b(v.w);
        ((uint2*)peb)[i] = pk.u;
    } else if (bid < 15616) {                 // concat kv_input
        int rowg = bid - 6400;
        int b = rowg / 2304, rr = rowg % 2304;
        const float* src = (rr < 256)  ? cmem + ((size_t)b * 256 + rr) * 1024
                         : (rr < 1280) ? mem  + ((size_t)b * 1024 + (rr - 256)) * 1024
                                       : x    + ((size_t)b * 1024 + (rr - 1280)) * 1024;
        float4 v = ((const float4*)src)[tid];
        union { u16 s[4]; uint2 u; } pk;
        pk.s[0] = f2b(v.x); pk.s[1] = f2b(v.y); pk.s[2] = f2b(v.z); pk.s[3] = f2b(v.w);
        ((uint2*)(kvin + (size_t)rowg * 1024))[tid] = pk.u;
    } else if (bid < 17664) {                 // Wkv^T (64x32 tile blocks)
        int m = bid - 15616;
        transpose_body(Wkv, wkvt, 1024, 2048, m % 64, m / 64, t, tid);
    } else if (bid < 18688) {                 // Wq^T
        int m = bid - 17664;
        transpose_body(Wq, wqt, 1024, 1024, m % 32, m / 32, t, tid);
    } else if (bid < 19712) {                 // Wout^T
        int m = bid - 18688;
        transpose_body(Wout, woutt, 1024, 1024, m % 32, m / 32, t, tid);
    } else {                                  // w2t: conv_w[o,i,r] -> w2t[o][r*1024+i]
        int m = bid - 19712;                  // 4096 blocks
        int pidx = m * 256 + tid;
        int o = pidx >> 10, i = pidx & 1023;
        float4 v = *(const float4*)(convw + ((size_t)o << 12) + 4 * i);
        size_t base = (size_t)o * 4096 + i;
        w2t[base]        = f2b(v.x);
        w2t[base + 1024] = f2b(v.y);
        w2t[base + 2048] = f2b(v.z);
        w2t[base + 3072] = f2b(v.w);
    }
}

// ---------------- bf16 MFMA GEMM body (XCD-bijective linear decode) ----------------
__device__ __forceinline__ void gemm_body(
    const u16* __restrict__ A, const u16* __restrict__ Bt,
    const float* __restrict__ bias, float* __restrict__ Cf,
    u16* __restrict__ Cb, int N, int K, float cscale,
    int apad, int ashift, int nxshift, int nyper, int id,
    u16* Al, u16* Bl)
{
    const int tid = threadIdx.x, w = tid >> 6, lane = tid & 63;
    const int lr = lane & 15, lg = lane >> 4;
    const int xcd = id & 7, s = id >> 3;
    const int bx = s & ((1 << nxshift) - 1);
    const int by = nyper * xcd + (s >> nxshift);
    const int bm0 = by * 128, bn0 = bx * 128;
    const int wr = (w >> 1) * 64, wc = (w & 1) * 64;

    f32x4 acc[4][4];
    const f32x4 z = {0.f, 0.f, 0.f, 0.f};
    #pragma unroll
    for (int mb = 0; mb < 4; ++mb)
        #pragma unroll
        for (int nb = 0; nb < 4; ++nb) acc[mb][nb] = z;

    for (int k0 = 0; k0 < K; k0 += 32) {
        __syncthreads();
        #pragma unroll
        for (int q = 0; q < 2; ++q) {
            int chunk = w * 2 + q;
            int row = bm0 + chunk * 16 + (lane >> 2);
            int arow = row + ((row >> ashift) * apad);
            int sg = (lane & 3) * 8;
            gload_lds16(A + (size_t)arow * K + k0 + sg, &Al[chunk * 512]);
            gload_lds16(Bt + (size_t)(bn0 + chunk * 16 + (lane >> 2)) * K + k0 + sg, &Bl[chunk * 512]);
        }
        __syncthreads();
        bf16x8 af[4], bf[4];
        #pragma unroll
        for (int mb = 0; mb < 4; ++mb)
            af[mb] = *(const bf16x8*)&Al[(wr + mb * 16 + lr) * 32 + lg * 8];
        #pragma unroll
        for (int nb = 0; nb < 4; ++nb)
            bf[nb] = *(const bf16x8*)&Bl[(wc + nb * 16 + lr) * 32 + lg * 8];
        #pragma unroll
        for (int mb = 0; mb < 4; ++mb)
            #pragma unroll
            for (int nb = 0; nb < 4; ++nb)
                acc[mb][nb] = __builtin_amdgcn_mfma_f32_16x16x32_bf16(
                    af[mb], bf[nb], acc[mb][nb], 0, 0, 0);
    }

    #pragma unroll
    for (int mb = 0; mb < 4; ++mb)
        #pragma unroll
        for (int nb = 0; nb < 4; ++nb)
            #pragma unroll
            for (int jr = 0; jr < 4; ++jr) {
                int row = bm0 + wr + mb * 16 + lg * 4 + jr;
                int col = bn0 + wc + nb * 16 + lr;
                float v = acc[mb][nb][jr] + (bias ? bias[col] : 0.f);
                if (Cf) Cf[(size_t)row * N + col] = v;
                if (Cb) Cb[(size_t)row * N + col] = f2b(v * cscale);
            }
}

// kv GEMM (1152) | Q GEMM (256) | compress GEMM (64) in one launch
__global__ __launch_bounds__(256) void gemm_stage1(
    const u16* __restrict__ kvin, const u16* __restrict__ wkvt,
    const u16* __restrict__ wqt, const u16* __restrict__ w2t,
    const float* __restrict__ convb, u16* __restrict__ kvb,
    u16* __restrict__ qb, float* __restrict__ new_cmem, u16* __restrict__ cmpb)
{
    __shared__ u16 Al[128 * 32];
    __shared__ u16 Bl[128 * 32];
    const int id = blockIdx.x;
    if (id < 1152)        // kv: M=9216 N=2048 K=1024, nx=16, nyper=9
        gemm_body(kvin, wkvt, nullptr, nullptr, kvb, 2048, 1024, 1.f,
                  0, 10, 4, 9, id, Al, Bl);
    else if (id < 1408)   // Q: nx=8, nyper=4, pre-scale C2
        gemm_body(kvin + (size_t)1280 * 1024, wqt, nullptr, nullptr, qb,
                  1024, 1024, C2, 1280, 10, 3, 4, id - 1152, Al, Bl);
    else                  // compress: K=4096, nx=8, nyper=1
        gemm_body(kvin + (size_t)256 * 1024, w2t, convb, new_cmem, cmpb,
                  1024, 4096, 1.f, 320, 8, 3, 1, id - 1408, Al, Bl);
}

__device__ __forceinline__ void transpose_v_body(
    const u16* __restrict__ src, int R, u16* __restrict__ dst,
    int bh, int j0, u16* t, int tid)
{
    const int b = bh >> 4, h = bh & 15;
    #pragma unroll
    for (int p = 0; p < 2; ++p) {
        int idx = tid + p * 256;
        int j = idx >> 3, c = idx & 7;
        uint4 v = *(const uint4*)(src + ((size_t)(b * R + j0 + j)) * 2048 + 1024 + h * 64 + c * 8);
        const u16* vv = (const u16*)&v;
        #pragma unroll
        for (int u2 = 0; u2 < 8; ++u2) t[j * 65 + c * 8 + u2] = vv[u2];
    }
    __syncthreads();
    #pragma unroll
    for (int p = 0; p < 2; ++p) {
        int idx = tid + p * 256;
        int jc = idx & 7, d = idx >> 3;
        union { u16 s[8]; uint4 u; } pk;
        #pragma unroll
        for (int u2 = 0; u2 < 8; ++u2) pk.s[u2] = t[(jc * 8 + u2) * 65 + d];
        *(uint4*)(dst + ((size_t)(bh * 64 + d)) * (size_t)R + j0 + jc * 8) = pk.u;
    }
}

// ckcv GEMM (128 blocks) | main V transpose (2304 blocks)
__global__ __launch_bounds__(256) void gemm_ckcv_tv(
    const u16* __restrict__ cmpb, const u16* __restrict__ wkvt,
    u16* __restrict__ ckcvb, const u16* __restrict__ kvb, u16* __restrict__ vt)
{
    __shared__ u16 shmem[128 * 64];   // 16 KB: gemm uses all; transpose uses 64*65
    const int id = blockIdx.x;
    if (id < 128) {       // ckcv: M=1024 N=2048 K=1024, nx=16, nyper=1
        gemm_body(cmpb, wkvt, nullptr, nullptr, ckcvb, 2048, 1024, 1.f,
                  0, 10, 4, 1, id, shmem, shmem + 4096);
    } else {
        int m = id - 128;
        transpose_v_body(kvb, 2304, vt, m / 36, (m % 36) * 64, shmem, threadIdx.x);
    }
}

// compressed V transpose (256 blocks)
__global__ __launch_bounds__(256) void transpose_cvt(
    const u16* __restrict__ ckcvb, u16* __restrict__ cvt)
{
    __shared__ u16 t[64 * 65];
    int m = blockIdx.x;
    transpose_v_body(ckcvb, 256, cvt, m / 4, (m % 4) * 64, t, threadIdx.x);
}

// out GEMM + aux finish
__global__ __launch_bounds__(256) void gemm_out(
    const u16* __restrict__ aob, const u16* __restrict__ woutt,
    const float* __restrict__ bout, float* __restrict__ logits,
    const float* __restrict__ acc, float* __restrict__ aux_out)
{
    __shared__ u16 Al[128 * 32];
    __shared__ u16 Bl[128 * 32];
    if (blockIdx.x == 0 && threadIdx.x == 0)
        aux_out[0] = acc[0] * (1.0f / 4194304.0f);
    gemm_body(aob, woutt, bout, logits, nullptr, 1024, 1024, 1.f,
              0, 10, 3, 4, blockIdx.x, Al, Bl);
}

// ---------------- fused main attention + FULL aux loss (unchanged) ----------------
__global__ __launch_bounds__(256) void attn_main_fused(
    const u16* __restrict__ qb, const u16* __restrict__ kvb,
    const u16* __restrict__ vt, const u16* __restrict__ peb,
    const u16* __restrict__ ckcv, const u16* __restrict__ cvt,
    u16* __restrict__ outb, float* __restrict__ acc)
{
    __shared__ u16 kbuf[64 * 64];
    __shared__ u16 vbuf[64 * 64];
    __shared__ u16 pering[128 * 64];
    __shared__ u16 pls[4][1024];
    __shared__ float red[4];

    const int tid = threadIdx.x;
    const int w = tid >> 6, lane = tid & 63;
    const int lr = lane & 15, lg = lane >> 4;
    const int rl = lane >> 3, cch = lane & 7;
    const int id = blockIdx.x;
    const int slot = id >> 3;
    const int bh = (id & 7) + ((slot >> 4) << 3);
    const int b = bh >> 4, h = bh & 15;
    const int i0 = (15 - (slot & 15)) * 64;   // LPT: longest first
    const int iw = i0 + 16 * w;
    const int jb0 = 960 - i0;

    const int lrh = lr >> 3, lrm = lr & 7;
    int pwidx[4], pridx[2];
    #pragma unroll
    for (int nb = 0; nb < 4; ++nb)
        pwidx[nb] = (((nb * 2 + lrh) ^ (lg * 2)) * 8) + lrm;
    #pragma unroll
    for (int ks = 0; ks < 2; ++ks)
        pridx[ks] = lr * 64 + (((ks * 4 + lg) ^ ((lr >> 2) * 2)) * 8);

    bf16x8 qf[2];
    #pragma unroll
    for (int ks = 0; ks < 2; ++ks)
        qf[ks] = *(const bf16x8*)(qb + ((size_t)(b * 1024 + iw + lr)) * 1024
                                  + h * 64 + ks * 32 + lg * 8);

    const f32x4 z = {0.f, 0.f, 0.f, 0.f};
    f32x4 od[4], od2[4];
    float lloc[4], ll2[4];
    #pragma unroll
    for (int nb = 0; nb < 4; ++nb) { od[nb] = z; od2[nb] = z; }
    #pragma unroll
    for (int jr = 0; jr < 4; ++jr) { lloc[jr] = 0.f; ll2[jr] = 0.f; }

    #pragma unroll
    for (int q = 0; q < 2; ++q) {
        int row = 16 * w + 8 * q + rl;
        gload_lds16(kvb + ((size_t)(b * 2304 + row)) * 2048 + h * 64 + ((cch ^ rl) * 8),
                    &kbuf[(16 * w + 8 * q) * 64]);
        gload_lds16(vt + ((size_t)(bh * 64 + row)) * 2304 + ((cch ^ rl) * 8),
                    &vbuf[(16 * w + 8 * q) * 64]);
    }
    #pragma unroll
    for (int q = 0; q < 4; ++q) {
        int rr = 32 * w + 8 * q;
        int a = jb0 + rr + rl;
        int srow = a > 2303 ? 2303 : a;
        gload_lds16(peb + ((size_t)(h * 2304 + srow)) * 64 + ((cch ^ rl) * 8),
                    &pering[((jb0 + rr) & 127) * 64]);
    }
    VDRAIN();
    __syncthreads();

    const int nt = ((i0 + 1343) >> 6) + 1;
    for (int t = 0; t < nt; ++t) {
        const int j0 = t * 64;
        const int jb = jb0 + j0;
        const bool more = (t + 1 < nt);

        f32x4 qk[4], qp[5];
        #pragma unroll
        for (int nb = 0; nb < 4; ++nb) qk[nb] = z;
        #pragma unroll
        for (int f = 0; f < 5; ++f) qp[f] = z;
        __builtin_amdgcn_s_setprio(1);
        #pragma unroll
        for (int ks = 0; ks < 2; ++ks) {
            #pragma unroll
            for (int nb = 0; nb < 4; ++nb) {
                int row = nb * 16 + lr;
                bf16x8 kb = *(const bf16x8*)&kbuf[row * 64 + (((4 * ks + lg) ^ (row & 7)) * 8)];
                qk[nb] = __builtin_amdgcn_mfma_f32_16x16x32_bf16(qf[ks], kb, qk[nb], 0, 0, 0);
            }
            #pragma unroll
            for (int f = 0; f < 5; ++f) {
                int rel = 48 - 16 * w + f * 16 + lr;
                int slotp = (jb + rel) & 127;
                bf16x8 pb = *(const bf16x8*)&pering[slotp * 64 + (((4 * ks + lg) ^ (slotp & 7)) * 8)];
                qp[f] = __builtin_amdgcn_mfma_f32_16x16x32_bf16(qf[ks], pb, qp[f], 0, 0, 0);
            }
        }
        __builtin_amdgcn_s_setprio(0);

        VDRAIN();
        SBAR();     // B: publishes V(t)

        if (more) {
            const int j0n = j0 + 64;
            #pragma unroll
            for (int q = 0; q < 2; ++q) {
                int row = 16 * w + 8 * q + rl;
                gload_lds16(kvb + ((size_t)(b * 2304 + j0n + row)) * 2048 + h * 64 + ((cch ^ rl) * 8),
                            &kbuf[(16 * w + 8 * q) * 64]);
            }
            const int A0 = jb + 128;
            #pragma unroll
            for (int q = 0; q < 2; ++q) {
                int rr = A0 + 16 * w + 8 * q;
                int a = rr + rl;
                int srow = a > 2303 ? 2303 : a;
                gload_lds16(peb + ((size_t)(h * 2304 + srow)) * 64 + ((cch ^ rl) * 8),
                            &pering[(rr & 127) * 64]);
            }
        }

        const bool nomask = (j0 + 63 <= iw + 1280);
        #pragma unroll
        for (int jr = 0; jr < 4; ++jr) {
            const int r = lg * 4 + jr;
            const int ia = iw + r;
            const int src = (lane & 48) | ((lr + 15 - r) & 15);
            float rot0 = __shfl(qp[0][jr], src);
            float rot1 = __shfl(qp[1][jr], src);
            float rot2 = __shfl(qp[2][jr], src);
            float rot3 = __shfl(qp[3][jr], src);
            float rot4 = __shfl(qp[4][jr], src);
            const bool hi = (lr > r);
            float s0 = qk[0][jr] + (hi ? rot1 : rot0);
            float s1 = qk[1][jr] + (hi ? rot2 : rot1);
            float s2 = qk[2][jr] + (hi ? rot3 : rot2);
            float s3 = qk[3][jr] + (hi ? rot4 : rot3);
            if (!nomask) {
                s0 = (j0 + lr      <= ia + 1280) ? s0 : -1e30f;
                s1 = (j0 + lr + 16 <= ia + 1280) ? s1 : -1e30f;
                s2 = (j0 + lr + 32 <= ia + 1280) ? s2 : -1e30f;
                s3 = (j0 + lr + 48 <= ia + 1280) ? s3 : -1e30f;
            }
            float p0 = exp2a(s0), p1 = exp2a(s1);
            float p2 = exp2a(s2), p3 = exp2a(s3);
            unsigned pkA = cvtpk(p0, p1), pkB = cvtpk(p2, p3);
            u16* pw = &pls[w][r * 64];
            pw[pwidx[0]] = (u16)pkA; pw[pwidx[1]] = (u16)(pkA >> 16);
            pw[pwidx[2]] = (u16)pkB; pw[pwidx[3]] = (u16)(pkB >> 16);
            lloc[jr] += (p0 + p1) + (p2 + p3);
        }

        __builtin_amdgcn_s_setprio(1);
        #pragma unroll
        for (int ks = 0; ks < 2; ++ks) {
            bf16x8 pa = *(const bf16x8*)&pls[w][pridx[ks]];
            #pragma unroll
            for (int nb = 0; nb < 4; ++nb) {
                int d = nb * 16 + lr;
                bf16x8 vb = *(const bf16x8*)&vbuf[d * 64 + (((4 * ks + lg) ^ (d & 7)) * 8)];
                od[nb] = __builtin_amdgcn_mfma_f32_16x16x32_bf16(pa, vb, od[nb], 0, 0, 0);
            }
        }
        __builtin_amdgcn_s_setprio(0);

        if (t >= 4 && t <= 19) {
            #pragma unroll
            for (int jr = 0; jr < 4; ++jr) {
                const int r = lg * 4 + jr;
                float p0 = exp2a(qk[0][jr]), p1 = exp2a(qk[1][jr]);
                float p2 = exp2a(qk[2][jr]), p3 = exp2a(qk[3][jr]);
                unsigned pkA = cvtpk(p0, p1), pkB = cvtpk(p2, p3);
                u16* pw = &pls[w][r * 64];
                pw[pwidx[0]] = (u16)pkA; pw[pwidx[1]] = (u16)(pkA >> 16);
                pw[pwidx[2]] = (u16)pkB; pw[pwidx[3]] = (u16)(pkB >> 16);
                ll2[jr] += (p0 + p1) + (p2 + p3);
            }
            __builtin_amdgcn_s_setprio(1);
            #pragma unroll
            for (int ks = 0; ks < 2; ++ks) {
                bf16x8 pa = *(const bf16x8*)&pls[w][pridx[ks]];
                #pragma unroll
                for (int nb = 0; nb < 4; ++nb) {
                    int d = nb * 16 + lr;
                    bf16x8 vb = *(const bf16x8*)&vbuf[d * 64 + (((4 * ks + lg) ^ (d & 7)) * 8)];
                    od2[nb] = __builtin_amdgcn_mfma_f32_16x16x32_bf16(pa, vb, od2[nb], 0, 0, 0);
                }
            }
            __builtin_amdgcn_s_setprio(0);
        }

        VDRAIN();
        SBAR();     // C: publishes kbuf=K(t+1), pering

        if (more) {
            const int j0n = j0 + 64;
            #pragma unroll
            for (int q = 0; q < 2; ++q) {
                int row = 16 * w + 8 * q + rl;
                gload_lds16(vt + ((size_t)(bh * 64 + row)) * 2304 + j0n + ((cch ^ rl) * 8),
                            &vbuf[(16 * w + 8 * q) * 64]);
            }
        }
    }

    #pragma unroll
    for (int jr = 0; jr < 4; ++jr) {
        float l = lloc[jr];
        #pragma unroll
        for (int mk = 1; mk < 16; mk <<= 1) l += __shfl_xor(l, mk);
        float inv = 1.f / l;
        int ia = iw + lg * 4 + jr;
        #pragma unroll
        for (int nb = 0; nb < 4; ++nb)
            outb[((size_t)(b * 1024 + ia)) * 1024 + h * 64 + nb * 16 + lr] =
                f2b(od[nb][jr] * inv);
    }
    #pragma unroll
    for (int jr = 0; jr < 4; ++jr) {
        float l = ll2[jr];
        #pragma unroll
        for (int mk = 1; mk < 16; mk <<= 1) l += __shfl_xor(l, mk);
        float inv = 1.f / l;
        #pragma unroll
        for (int nb = 0; nb < 4; ++nb) od2[nb][jr] *= inv;
    }

    // ---- aux phase-1: compressed KV (4 tiles) ----
    #pragma unroll
    for (int nb = 0; nb < 4; ++nb) od[nb] = z;
    #pragma unroll
    for (int jr = 0; jr < 4; ++jr) lloc[jr] = 0.f;
    const u16* kbase = ckcv + ((size_t)(b * 256)) * 2048 + h * 64;
    const u16* vbase = cvt + ((size_t)(bh * 64)) * 256;

    for (int t = 0; t < 4; ++t) {
        const int j0 = t * 64;
        __syncthreads();
        #pragma unroll
        for (int q = 0; q < 2; ++q) {
            int row = 16 * w + 8 * q + rl;
            gload_lds16(kbase + (size_t)(j0 + row) * 2048 + ((cch ^ rl) * 8),
                        &kbuf[(16 * w + 8 * q) * 64]);
            gload_lds16(vbase + (size_t)row * 256 + j0 + ((cch ^ rl) * 8),
                        &vbuf[(16 * w + 8 * q) * 64]);
        }
        VDRAIN();
        __syncthreads();

        f32x4 qk[4];
        #pragma unroll
        for (int nb = 0; nb < 4; ++nb) qk[nb] = z;
        #pragma unroll
        for (int ks = 0; ks < 2; ++ks)
            #pragma unroll
            for (int nb = 0; nb < 4; ++nb) {
                int row = nb * 16 + lr;
                bf16x8 kb = *(const bf16x8*)&kbuf[row * 64 + (((4 * ks + lg) ^ (row & 7)) * 8)];
                qk[nb] = __builtin_amdgcn_mfma_f32_16x16x32_bf16(qf[ks], kb, qk[nb], 0, 0, 0);
            }

        #pragma unroll
        for (int jr = 0; jr < 4; ++jr) {
            const int r = lg * 4 + jr;
            float p0 = exp2a(qk[0][jr]), p1 = exp2a(qk[1][jr]);
            float p2 = exp2a(qk[2][jr]), p3 = exp2a(qk[3][jr]);
            unsigned pkA = cvtpk(p0, p1), pkB = cvtpk(p2, p3);
            u16* pw = &pls[w][r * 64];
            pw[pwidx[0]] = (u16)pkA; pw[pwidx[1]] = (u16)(pkA >> 16);
            pw[pwidx[2]] = (u16)pkB; pw[pwidx[3]] = (u16)(pkB >> 16);
            lloc[jr] += (p0 + p1) + (p2 + p3);
        }

        #pragma unroll
        for (int ks = 0; ks < 2; ++ks) {
            bf16x8 pa = *(const bf16x8*)&pls[w][pridx[ks]];
            #pragma unroll
            for (int nb = 0; nb < 4; ++nb) {
                int d = nb * 16 + lr;
                bf16x8 vb = *(const bf16x8*)&vbuf[d * 64 + (((4 * ks + lg) ^ (d & 7)) * 8)];
                od[nb] = __builtin_amdgcn_mfma_f32_16x16x32_bf16(pa, vb, od[nb], 0, 0, 0);
            }
        }
    }

    float local = 0.f;
    #pragma unroll
    for (int jr = 0; jr < 4; ++jr) {
        float l = lloc[jr];
        #pragma unroll
        for (int mk = 1; mk < 16; mk <<= 1) l += __shfl_xor(l, mk);
        float inv = 1.f / l;
        #pragma unroll
        for (int nb = 0; nb < 4; ++nb) {
            float d = od2[nb][jr] - od[nb][jr] * inv;
            local += d * d;
        }
    }
    #pragma unroll
    for (int mk = 1; mk < 64; mk <<= 1) local += __shfl_xor(local, mk);
    if (lane == 0) red[w] = local;
    __syncthreads();
    if (tid == 0) atomicAdd(acc, red[0] + red[1] + red[2] + red[3]);
}

// ---------------- launch ----------------
extern "C" void kernel_launch(void* const* d_in, const int* in_sizes, int n_in,
                              void* d_out, int out_size, void* d_ws, size_t ws_size,
                              hipStream_t stream)
{
    const float* x     = (const float*)d_in[0];
    const float* mem   = (const float*)d_in[1];
    const float* cmem  = (const float*)d_in[2];
    const float* pos   = (const float*)d_in[3];
    const float* Wq    = (const float*)d_in[5];
    const float* Wkv   = (const float*)d_in[6];
    const float* Wout  = (const float*)d_in[7];
    const float* bout  = (const float*)d_in[8];
    const float* convw = (const float*)d_in[9];
    const float* convb = (const float*)d_in[10];

    float* out      = (float*)d_out;
    float* logits   = out;
    float* new_mem  = out + 4194304;
    float* new_cmem = out + 8388608;
    float* aux_out  = out + 9437184;

    char* p = (char*)d_ws;
    u16* kvb   = (u16*)p; p += (size_t)9216 * 2048 * 2;
    u16* qb    = (u16*)p; p += (size_t)4096 * 1024 * 2;
    u16* kvin  = (u16*)p; p += (size_t)9216 * 1024 * 2;   // becomes vt in L3
    u16* wkvt  = (u16*)p; p += (size_t)2048 * 1024 * 2;
    u16* wqt   = (u16*)p; p += (size_t)1024 * 1024 * 2;
    u16* woutt = (u16*)p; p += (size_t)1024 * 1024 * 2;
    u16* w2t   = (u16*)p; p += (size_t)1024 * 4096 * 2;   // becomes cvt in L4
    u16* peb   = (u16*)p; p += (size_t)16 * 2304 * 64 * 2;
    u16* xb    = (u16*)p; p += (size_t)4096 * 1024 * 2;   // spare
    u16* memb  = (u16*)p; p += (size_t)4096 * 1024 * 2;   // spare
    u16* cmpb  = (u16*)p; p += (size_t)1024 * 1024 * 2;
    u16* ckcvb = (u16*)p; p += (size_t)1024 * 2048 * 2;
    u16* aob   = (u16*)p; p += (size_t)4096 * 1024 * 2;
    float* acc = (float*)p;
    u16* vt   = kvin;
    u16* cvt  = w2t;
    (void)xb; (void)memb;

    // L1: copy | cvt | concat | transposes | w2t | zero acc (23808 blocks)
    megaprep<<<23808, 256, 0, stream>>>(pos, peb, x, mem, cmem, kvin,
                                        Wkv, wkvt, Wq, wqt, Wout, woutt,
                                        convw, w2t, new_mem, acc);

    // L2: kv | Q | compress GEMMs (1472 blocks)
    gemm_stage1<<<1472, 256, 0, stream>>>(kvin, wkvt, wqt, w2t, convb,
                                          kvb, qb, new_cmem, cmpb);

    // L3: ckcv GEMM | main V transpose (2432 blocks) — kvin dead, vt overlay OK
    gemm_ckcv_tv<<<2432, 256, 0, stream>>>(cmpb, wkvt, ckcvb, kvb, vt);

    // L4: compressed V transpose — w2t dead, cvt overlay OK
    transpose_cvt<<<256, 256, 0, stream>>>(ckcvb, cvt);

    // L5: fused attention + aux loss
    attn_main_fused<<<1024, 256, 0, stream>>>(qb, kvb, vt, peb, ckcvb, cvt, aob, acc);

    // L6: logits GEMM + aux finish
    gemm_out<<<256, 256, 0, stream>>>(aob, woutt, bout, logits, acc, aux_out);
}

// Round 17
// 345.263 us; speedup vs baseline: 1.6244x; 1.0505x over previous
//
#include <hip/hip_runtime.h>
#include <hip/hip_bf16.h>
#include <cstddef>

typedef unsigned short u16;
typedef __attribute__((ext_vector_type(8))) short bf16x8;
typedef __attribute__((ext_vector_type(4))) float f32x4;

#define C2 0.18033688011112042f   // 0.125 * log2(e)

__device__ __forceinline__ u16 f2b(float f) {
    unsigned u = __builtin_bit_cast(unsigned, f);
    unsigned r = (u + 0x7FFF + ((u >> 16) & 1)) >> 16;
    return (u16)r;
}

__device__ __forceinline__ float exp2a(float x) {
    float r; asm("v_exp_f32 %0, %1" : "=v"(r) : "v"(x)); return r;
}

__device__ __forceinline__ unsigned cvtpk(float lo, float hi) {
    unsigned r; asm("v_cvt_pk_bf16_f32 %0, %1, %2" : "=v"(r) : "v"(lo), "v"(hi));
    return r;
}

__device__ __forceinline__ void gload_lds16(const void* g, void* l) {
    __builtin_amdgcn_global_load_lds(
        (const __attribute__((address_space(1))) unsigned int*)g,
        (__attribute__((address_space(3))) unsigned int*)l, 16, 0, 0);
}

#define VDRAIN() asm volatile("s_waitcnt vmcnt(0)" ::: "memory")
#define SBAR() do { __builtin_amdgcn_sched_barrier(0); __builtin_amdgcn_s_barrier(); } while (0)

// ---------------- fused prep ----------------
__device__ __forceinline__ void transpose_body(
    const float* __restrict__ in, u16* __restrict__ out, int K, int N,
    int bx, int by, float (*t)[33], int tid)
{
    int k0 = by * 32, n0 = bx * 32;
    int tx = tid & 31, ty = tid >> 5;
    #pragma unroll
    for (int p = 0; p < 4; ++p)
        t[ty + 8 * p][tx] = in[(size_t)(k0 + ty + 8 * p) * N + n0 + tx];
    __syncthreads();
    #pragma unroll
    for (int p = 0; p < 4; ++p)
        out[(size_t)(n0 + ty + 8 * p) * K + k0 + tx] = f2b(t[tx][ty + 8 * p]);
}

// copy(new_mem=x) | cvt(pos) | concat | Wkv^T | Wq^T | Wout^T | w2t | zero(acc)
__global__ __launch_bounds__(256) void megaprep(
    const float* __restrict__ pos, u16* __restrict__ peb,
    const float* __restrict__ x, const float* __restrict__ mem,
    const float* __restrict__ cmem, u16* __restrict__ kvin,
    const float* __restrict__ Wkv, u16* __restrict__ wkvt,
    const float* __restrict__ Wq, u16* __restrict__ wqt,
    const float* __restrict__ Wout, u16* __restrict__ woutt,
    const float* __restrict__ convw, u16* __restrict__ w2t,
    float* __restrict__ new_mem, float* __restrict__ acc)
{
    __shared__ float t[32][33];
    const int bid = blockIdx.x, tid = threadIdx.x;
    if (bid == 0 && tid == 0) acc[0] = 0.f;
    if (bid < 4096) {                         // new_mem = x (fp32 copy)
        int i = bid * 256 + tid;
        ((float4*)new_mem)[i] = ((const float4*)x)[i];
    } else if (bid < 6400) {                  // cvt pos
        int i = (bid - 4096) * 256 + tid;
        float4 v = ((const float4*)pos)[i];
        union { u16 s[4]; uint2 u; } pk;
        pk.s[0] = f2b(v.x); pk.s[1] = f2b(v.y); pk.s[2] = f2b(v.z); pk.s[3] = f2b(v.w);
        ((uint2*)peb)[i] = pk.u;
    } else if (bid < 15616) {                 // concat kv_input
        int rowg = bid - 6400;
        int b = rowg / 2304, rr = rowg % 2304;
        const float* src = (rr < 256)  ? cmem + ((size_t)b * 256 + rr) * 1024
                         : (rr < 1280) ? mem  + ((size_t)b * 1024 + (rr - 256)) * 1024
                                       : x    + ((size_t)b * 1024 + (rr - 1280)) * 1024;
        float4 v = ((const float4*)src)[tid];
        union { u16 s[4]; uint2 u; } pk;
        pk.s[0] = f2b(v.x); pk.s[1] = f2b(v.y); pk.s[2] = f2b(v.z); pk.s[3] = f2b(v.w);
        ((uint2*)(kvin + (size_t)rowg * 1024))[tid] = pk.u;
    } else if (bid < 17664) {                 // Wkv^T
        int m = bid - 15616;
        transpose_body(Wkv, wkvt, 1024, 2048, m % 64, m / 64, t, tid);
    } else if (bid < 18688) {                 // Wq^T
        int m = bid - 17664;
        transpose_body(Wq, wqt, 1024, 1024, m % 32, m / 32, t, tid);
    } else if (bid < 19712) {                 // Wout^T
        int m = bid - 18688;
        transpose_body(Wout, woutt, 1024, 1024, m % 32, m / 32, t, tid);
    } else {                                  // w2t
        int m = bid - 19712;                  // 4096 blocks
        int pidx = m * 256 + tid;
        int o = pidx >> 10, i = pidx & 1023;
        float4 v = *(const float4*)(convw + ((size_t)o << 12) + 4 * i);
        size_t base = (size_t)o * 4096 + i;
        w2t[base]        = f2b(v.x);
        w2t[base + 1024] = f2b(v.y);
        w2t[base + 2048] = f2b(v.z);
        w2t[base + 3072] = f2b(v.w);
    }
}

// ---------------- bf16 MFMA GEMM body (XCD-bijective linear decode) ----------------
__device__ __forceinline__ void gemm_body(
    const u16* __restrict__ A, const u16* __restrict__ Bt,
    const float* __restrict__ bias, float* __restrict__ Cf,
    u16* __restrict__ Cb, int N, int K, float cscale,
    int apad, int ashift, int nxshift, int nyper, int id,
    u16* Al, u16* Bl)
{
    const int tid = threadIdx.x, w = tid >> 6, lane = tid & 63;
    const int lr = lane & 15, lg = lane >> 4;
    const int xcd = id & 7, s = id >> 3;
    const int bx = s & ((1 << nxshift) - 1);
    const int by = nyper * xcd + (s >> nxshift);
    const int bm0 = by * 128, bn0 = bx * 128;
    const int wr = (w >> 1) * 64, wc = (w & 1) * 64;

    f32x4 acc[4][4];
    const f32x4 z = {0.f, 0.f, 0.f, 0.f};
    #pragma unroll
    for (int mb = 0; mb < 4; ++mb)
        #pragma unroll
        for (int nb = 0; nb < 4; ++nb) acc[mb][nb] = z;

    for (int k0 = 0; k0 < K; k0 += 32) {
        __syncthreads();
        #pragma unroll
        for (int q = 0; q < 2; ++q) {
            int chunk = w * 2 + q;
            int row = bm0 + chunk * 16 + (lane >> 2);
            int arow = row + ((row >> ashift) * apad);
            int sg = (lane & 3) * 8;
            gload_lds16(A + (size_t)arow * K + k0 + sg, &Al[chunk * 512]);
            gload_lds16(Bt + (size_t)(bn0 + chunk * 16 + (lane >> 2)) * K + k0 + sg, &Bl[chunk * 512]);
        }
        __syncthreads();
        bf16x8 af[4], bf[4];
        #pragma unroll
        for (int mb = 0; mb < 4; ++mb)
            af[mb] = *(const bf16x8*)&Al[(wr + mb * 16 + lr) * 32 + lg * 8];
        #pragma unroll
        for (int nb = 0; nb < 4; ++nb)
            bf[nb] = *(const bf16x8*)&Bl[(wc + nb * 16 + lr) * 32 + lg * 8];
        #pragma unroll
        for (int mb = 0; mb < 4; ++mb)
            #pragma unroll
            for (int nb = 0; nb < 4; ++nb)
                acc[mb][nb] = __builtin_amdgcn_mfma_f32_16x16x32_bf16(
                    af[mb], bf[nb], acc[mb][nb], 0, 0, 0);
    }

    #pragma unroll
    for (int mb = 0; mb < 4; ++mb)
        #pragma unroll
        for (int nb = 0; nb < 4; ++nb)
            #pragma unroll
            for (int jr = 0; jr < 4; ++jr) {
                int row = bm0 + wr + mb * 16 + lg * 4 + jr;
                int col = bn0 + wc + nb * 16 + lr;
                float v = acc[mb][nb][jr] + (bias ? bias[col] : 0.f);
                if (Cf) Cf[(size_t)row * N + col] = v;
                if (Cb) Cb[(size_t)row * N + col] = f2b(v * cscale);
            }
}

// LPT order: compress (64, K=4096 longest) | Q (256) | kv (1152)
__global__ __launch_bounds__(256) void gemm_stage1(
    const u16* __restrict__ kvin, const u16* __restrict__ wkvt,
    const u16* __restrict__ wqt, const u16* __restrict__ w2t,
    const float* __restrict__ convb, u16* __restrict__ kvb,
    u16* __restrict__ qb, float* __restrict__ new_cmem, u16* __restrict__ cmpb)
{
    __shared__ u16 Al[128 * 32];
    __shared__ u16 Bl[128 * 32];
    const int id = blockIdx.x;
    if (id < 64)          // compress: K=4096, nx=8, nyper=1 (longest first)
        gemm_body(kvin + (size_t)256 * 1024, w2t, convb, new_cmem, cmpb,
                  1024, 4096, 1.f, 320, 8, 3, 1, id, Al, Bl);
    else if (id < 320)    // Q: nx=8, nyper=4, pre-scale C2
        gemm_body(kvin + (size_t)1280 * 1024, wqt, nullptr, nullptr, qb,
                  1024, 1024, C2, 1280, 10, 3, 4, id - 64, Al, Bl);
    else                  // kv: M=9216 N=2048 K=1024, nx=16, nyper=9
        gemm_body(kvin, wkvt, nullptr, nullptr, kvb, 2048, 1024, 1.f,
                  0, 10, 4, 9, id - 320, Al, Bl);
}

__device__ __forceinline__ void transpose_v_body(
    const u16* __restrict__ src, int R, u16* __restrict__ dst,
    int bh, int j0, u16* t, int tid)
{
    const int b = bh >> 4, h = bh & 15;
    #pragma unroll
    for (int p = 0; p < 2; ++p) {
        int idx = tid + p * 256;
        int j = idx >> 3, c = idx & 7;
        uint4 v = *(const uint4*)(src + ((size_t)(b * R + j0 + j)) * 2048 + 1024 + h * 64 + c * 8);
        const u16* vv = (const u16*)&v;
        #pragma unroll
        for (int u2 = 0; u2 < 8; ++u2) t[j * 65 + c * 8 + u2] = vv[u2];
    }
    __syncthreads();
    #pragma unroll
    for (int p = 0; p < 2; ++p) {
        int idx = tid + p * 256;
        int jc = idx & 7, d = idx >> 3;
        union { u16 s[8]; uint4 u; } pk;
        #pragma unroll
        for (int u2 = 0; u2 < 8; ++u2) pk.s[u2] = t[(jc * 8 + u2) * 65 + d];
        *(uint4*)(dst + ((size_t)(bh * 64 + d)) * (size_t)R + j0 + jc * 8) = pk.u;
    }
}

// ckcv GEMM (128 blocks) | main V transpose (2304 blocks)
__global__ __launch_bounds__(256) void gemm_ckcv_tv(
    const u16* __restrict__ cmpb, const u16* __restrict__ wkvt,
    u16* __restrict__ ckcvb, const u16* __restrict__ kvb, u16* __restrict__ vt)
{
    __shared__ u16 shmem[128 * 64];
    const int id = blockIdx.x;
    if (id < 128) {
        gemm_body(cmpb, wkvt, nullptr, nullptr, ckcvb, 2048, 1024, 1.f,
                  0, 10, 4, 1, id, shmem, shmem + 4096);
    } else {
        int m = id - 128;
        transpose_v_body(kvb, 2304, vt, m / 36, (m % 36) * 64, shmem, threadIdx.x);
    }
}

// compressed V transpose (256 blocks)
__global__ __launch_bounds__(256) void transpose_cvt(
    const u16* __restrict__ ckcvb, u16* __restrict__ cvt)
{
    __shared__ u16 t[64 * 65];
    int m = blockIdx.x;
    transpose_v_body(ckcvb, 256, cvt, m / 4, (m % 4) * 64, t, threadIdx.x);
}

// out GEMM + aux finish
__global__ __launch_bounds__(256) void gemm_out(
    const u16* __restrict__ aob, const u16* __restrict__ woutt,
    const float* __restrict__ bout, float* __restrict__ logits,
    const float* __restrict__ acc, float* __restrict__ aux_out)
{
    __shared__ u16 Al[128 * 32];
    __shared__ u16 Bl[128 * 32];
    if (blockIdx.x == 0 && threadIdx.x == 0)
        aux_out[0] = acc[0] * (1.0f / 4194304.0f);
    gemm_body(aob, woutt, bout, logits, nullptr, 1024, 1024, 1.f,
              0, 10, 3, 4, blockIdx.x, Al, Bl);
}

// ---------------- fused main attention + FULL aux loss (round-15 known-good) ----------------
__global__ __launch_bounds__(256) void attn_main_fused(
    const u16* __restrict__ qb, const u16* __restrict__ kvb,
    const u16* __restrict__ vt, const u16* __restrict__ peb,
    const u16* __restrict__ ckcv, const u16* __restrict__ cvt,
    u16* __restrict__ outb, float* __restrict__ acc)
{
    __shared__ u16 kbuf[64 * 64];
    __shared__ u16 vbuf[64 * 64];
    __shared__ u16 pering[128 * 64];
    __shared__ u16 pls[4][1024];
    __shared__ float red[4];

    const int tid = threadIdx.x;
    const int w = tid >> 6, lane = tid & 63;
    const int lr = lane & 15, lg = lane >> 4;
    const int rl = lane >> 3, cch = lane & 7;
    const int id = blockIdx.x;
    const int slot = id >> 3;
    const int bh = (id & 7) + ((slot >> 4) << 3);
    const int b = bh >> 4, h = bh & 15;
    const int i0 = (15 - (slot & 15)) * 64;   // LPT: longest first
    const int iw = i0 + 16 * w;
    const int jb0 = 960 - i0;

    const int lrh = lr >> 3, lrm = lr & 7;
    int pwidx[4], pridx[2];
    #pragma unroll
    for (int nb = 0; nb < 4; ++nb)
        pwidx[nb] = (((nb * 2 + lrh) ^ (lg * 2)) * 8) + lrm;
    #pragma unroll
    for (int ks = 0; ks < 2; ++ks)
        pridx[ks] = lr * 64 + (((ks * 4 + lg) ^ ((lr >> 2) * 2)) * 8);

    bf16x8 qf[2];
    #pragma unroll
    for (int ks = 0; ks < 2; ++ks)
        qf[ks] = *(const bf16x8*)(qb + ((size_t)(b * 1024 + iw + lr)) * 1024
                                  + h * 64 + ks * 32 + lg * 8);

    const f32x4 z = {0.f, 0.f, 0.f, 0.f};
    f32x4 od[4], od2[4];
    float lloc[4], ll2[4];
    #pragma unroll
    for (int nb = 0; nb < 4; ++nb) { od[nb] = z; od2[nb] = z; }
    #pragma unroll
    for (int jr = 0; jr < 4; ++jr) { lloc[jr] = 0.f; ll2[jr] = 0.f; }

    #pragma unroll
    for (int q = 0; q < 2; ++q) {
        int row = 16 * w + 8 * q + rl;
        gload_lds16(kvb + ((size_t)(b * 2304 + row)) * 2048 + h * 64 + ((cch ^ rl) * 8),
                    &kbuf[(16 * w + 8 * q) * 64]);
        gload_lds16(vt + ((size_t)(bh * 64 + row)) * 2304 + ((cch ^ rl) * 8),
                    &vbuf[(16 * w + 8 * q) * 64]);
    }
    #pragma unroll
    for (int q = 0; q < 4; ++q) {
        int rr = 32 * w + 8 * q;
        int a = jb0 + rr + rl;
        int srow = a > 2303 ? 2303 : a;
        gload_lds16(peb + ((size_t)(h * 2304 + srow)) * 64 + ((cch ^ rl) * 8),
                    &pering[((jb0 + rr) & 127) * 64]);
    }
    VDRAIN();
    __syncthreads();

    const int nt = ((i0 + 1343) >> 6) + 1;
    for (int t = 0; t < nt; ++t) {
        const int j0 = t * 64;
        const int jb = jb0 + j0;
        const bool more = (t + 1 < nt);

        f32x4 qk[4], qp[5];
        #pragma unroll
        for (int nb = 0; nb < 4; ++nb) qk[nb] = z;
        #pragma unroll
        for (int f = 0; f < 5; ++f) qp[f] = z;
        __builtin_amdgcn_s_setprio(1);
        #pragma unroll
        for (int ks = 0; ks < 2; ++ks) {
            #pragma unroll
            for (int nb = 0; nb < 4; ++nb) {
                int row = nb * 16 + lr;
                bf16x8 kb = *(const bf16x8*)&kbuf[row * 64 + (((4 * ks + lg) ^ (row & 7)) * 8)];
                qk[nb] = __builtin_amdgcn_mfma_f32_16x16x32_bf16(qf[ks], kb, qk[nb], 0, 0, 0);
            }
            #pragma unroll
            for (int f = 0; f < 5; ++f) {
                int rel = 48 - 16 * w + f * 16 + lr;
                int slotp = (jb + rel) & 127;
                bf16x8 pb = *(const bf16x8*)&pering[slotp * 64 + (((4 * ks + lg) ^ (slotp & 7)) * 8)];
                qp[f] = __builtin_amdgcn_mfma_f32_16x16x32_bf16(qf[ks], pb, qp[f], 0, 0, 0);
            }
        }
        __builtin_amdgcn_s_setprio(0);

        VDRAIN();
        SBAR();     // B: publishes V(t)

        if (more) {
            const int j0n = j0 + 64;
            #pragma unroll
            for (int q = 0; q < 2; ++q) {
                int row = 16 * w + 8 * q + rl;
                gload_lds16(kvb + ((size_t)(b * 2304 + j0n + row)) * 2048 + h * 64 + ((cch ^ rl) * 8),
                            &kbuf[(16 * w + 8 * q) * 64]);
            }
            const int A0 = jb + 128;
            #pragma unroll
            for (int q = 0; q < 2; ++q) {
                int rr = A0 + 16 * w + 8 * q;
                int a = rr + rl;
                int srow = a > 2303 ? 2303 : a;
                gload_lds16(peb + ((size_t)(h * 2304 + srow)) * 64 + ((cch ^ rl) * 8),
                            &pering[(rr & 127) * 64]);
            }
        }

        const bool nomask = (j0 + 63 <= iw + 1280);
        #pragma unroll
        for (int jr = 0; jr < 4; ++jr) {
            const int r = lg * 4 + jr;
            const int ia = iw + r;
            const int src = (lane & 48) | ((lr + 15 - r) & 15);
            float rot0 = __shfl(qp[0][jr], src);
            float rot1 = __shfl(qp[1][jr], src);
            float rot2 = __shfl(qp[2][jr], src);
            float rot3 = __shfl(qp[3][jr], src);
            float rot4 = __shfl(qp[4][jr], src);
            const bool hi = (lr > r);
            float s0 = qk[0][jr] + (hi ? rot1 : rot0);
            float s1 = qk[1][jr] + (hi ? rot2 : rot1);
            float s2 = qk[2][jr] + (hi ? rot3 : rot2);
            float s3 = qk[3][jr] + (hi ? rot4 : rot3);
            if (!nomask) {
                s0 = (j0 + lr      <= ia + 1280) ? s0 : -1e30f;
                s1 = (j0 + lr + 16 <= ia + 1280) ? s1 : -1e30f;
                s2 = (j0 + lr + 32 <= ia + 1280) ? s2 : -1e30f;
                s3 = (j0 + lr + 48 <= ia + 1280) ? s3 : -1e30f;
            }
            float p0 = exp2a(s0), p1 = exp2a(s1);
            float p2 = exp2a(s2), p3 = exp2a(s3);
            unsigned pkA = cvtpk(p0, p1), pkB = cvtpk(p2, p3);
            u16* pw = &pls[w][r * 64];
            pw[pwidx[0]] = (u16)pkA; pw[pwidx[1]] = (u16)(pkA >> 16);
            pw[pwidx[2]] = (u16)pkB; pw[pwidx[3]] = (u16)(pkB >> 16);
            lloc[jr] += (p0 + p1) + (p2 + p3);
        }

        __builtin_amdgcn_s_setprio(1);
        #pragma unroll
        for (int ks = 0; ks < 2; ++ks) {
            bf16x8 pa = *(const bf16x8*)&pls[w][pridx[ks]];
            #pragma unroll
            for (int nb = 0; nb < 4; ++nb) {
                int d = nb * 16 + lr;
                bf16x8 vb = *(const bf16x8*)&vbuf[d * 64 + (((4 * ks + lg) ^ (d & 7)) * 8)];
                od[nb] = __builtin_amdgcn_mfma_f32_16x16x32_bf16(pa, vb, od[nb], 0, 0, 0);
            }
        }
        __builtin_amdgcn_s_setprio(0);

        if (t >= 4 && t <= 19) {
            #pragma unroll
            for (int jr = 0; jr < 4; ++jr) {
                const int r = lg * 4 + jr;
                float p0 = exp2a(qk[0][jr]), p1 = exp2a(qk[1][jr]);
                float p2 = exp2a(qk[2][jr]), p3 = exp2a(qk[3][jr]);
                unsigned pkA = cvtpk(p0, p1), pkB = cvtpk(p2, p3);
                u16* pw = &pls[w][r * 64];
                pw[pwidx[0]] = (u16)pkA; pw[pwidx[1]] = (u16)(pkA >> 16);
                pw[pwidx[2]] = (u16)pkB; pw[pwidx[3]] = (u16)(pkB >> 16);
                ll2[jr] += (p0 + p1) + (p2 + p3);
            }
            __builtin_amdgcn_s_setprio(1);
            #pragma unroll
            for (int ks = 0; ks < 2; ++ks) {
                bf16x8 pa = *(const bf16x8*)&pls[w][pridx[ks]];
                #pragma unroll
                for (int nb = 0; nb < 4; ++nb) {
                    int d = nb * 16 + lr;
                    bf16x8 vb = *(const bf16x8*)&vbuf[d * 64 + (((4 * ks + lg) ^ (d & 7)) * 8)];
                    od2[nb] = __builtin_amdgcn_mfma_f32_16x16x32_bf16(pa, vb, od2[nb], 0, 0, 0);
                }
            }
            __builtin_amdgcn_s_setprio(0);
        }

        VDRAIN();
        SBAR();     // C: publishes kbuf=K(t+1), pering

        if (more) {
            const int j0n = j0 + 64;
            #pragma unroll
            for (int q = 0; q < 2; ++q) {
                int row = 16 * w + 8 * q + rl;
                gload_lds16(vt + ((size_t)(bh * 64 + row)) * 2304 + j0n + ((cch ^ rl) * 8),
                            &vbuf[(16 * w + 8 * q) * 64]);
            }
        }
    }

    #pragma unroll
    for (int jr = 0; jr < 4; ++jr) {
        float l = lloc[jr];
        #pragma unroll
        for (int mk = 1; mk < 16; mk <<= 1) l += __shfl_xor(l, mk);
        float inv = 1.f / l;
        int ia = iw + lg * 4 + jr;
        #pragma unroll
        for (int nb = 0; nb < 4; ++nb)
            outb[((size_t)(b * 1024 + ia)) * 1024 + h * 64 + nb * 16 + lr] =
                f2b(od[nb][jr] * inv);
    }
    #pragma unroll
    for (int jr = 0; jr < 4; ++jr) {
        float l = ll2[jr];
        #pragma unroll
        for (int mk = 1; mk < 16; mk <<= 1) l += __shfl_xor(l, mk);
        float inv = 1.f / l;
        #pragma unroll
        for (int nb = 0; nb < 4; ++nb) od2[nb][jr] *= inv;
    }

    // ---- aux phase-1: compressed KV (4 tiles) ----
    #pragma unroll
    for (int nb = 0; nb < 4; ++nb) od[nb] = z;
    #pragma unroll
    for (int jr = 0; jr < 4; ++jr) lloc[jr] = 0.f;
    const u16* kbase = ckcv + ((size_t)(b * 256)) * 2048 + h * 64;
    const u16* vbase = cvt + ((size_t)(bh * 64)) * 256;

    for (int t = 0; t < 4; ++t) {
        const int j0 = t * 64;
        __syncthreads();
        #pragma unroll
        for (int q = 0; q < 2; ++q) {
            int row = 16 * w + 8 * q + rl;
            gload_lds16(kbase + (size_t)(j0 + row) * 2048 + ((cch ^ rl) * 8),
                        &kbuf[(16 * w + 8 * q) * 64]);
            gload_lds16(vbase + (size_t)row * 256 + j0 + ((cch ^ rl) * 8),
                        &vbuf[(16 * w + 8 * q) * 64]);
        }
        VDRAIN();
        __syncthreads();

        f32x4 qk[4];
        #pragma unroll
        for (int nb = 0; nb < 4; ++nb) qk[nb] = z;
        #pragma unroll
        for (int ks = 0; ks < 2; ++ks)
            #pragma unroll
            for (int nb = 0; nb < 4; ++nb) {
                int row = nb * 16 + lr;
                bf16x8 kb = *(const bf16x8*)&kbuf[row * 64 + (((4 * ks + lg) ^ (row & 7)) * 8)];
                qk[nb] = __builtin_amdgcn_mfma_f32_16x16x32_bf16(qf[ks], kb, qk[nb], 0, 0, 0);
            }

        #pragma unroll
        for (int jr = 0; jr < 4; ++jr) {
            const int r = lg * 4 + jr;
            float p0 = exp2a(qk[0][jr]), p1 = exp2a(qk[1][jr]);
            float p2 = exp2a(qk[2][jr]), p3 = exp2a(qk[3][jr]);
            unsigned pkA = cvtpk(p0, p1), pkB = cvtpk(p2, p3);
            u16* pw = &pls[w][r * 64];
            pw[pwidx[0]] = (u16)pkA; pw[pwidx[1]] = (u16)(pkA >> 16);
            pw[pwidx[2]] = (u16)pkB; pw[pwidx[3]] = (u16)(pkB >> 16);
            lloc[jr] += (p0 + p1) + (p2 + p3);
        }

        #pragma unroll
        for (int ks = 0; ks < 2; ++ks) {
            bf16x8 pa = *(const bf16x8*)&pls[w][pridx[ks]];
            #pragma unroll
            for (int nb = 0; nb < 4; ++nb) {
                int d = nb * 16 + lr;
                bf16x8 vb = *(const bf16x8*)&vbuf[d * 64 + (((4 * ks + lg) ^ (d & 7)) * 8)];
                od[nb] = __builtin_amdgcn_mfma_f32_16x16x32_bf16(pa, vb, od[nb], 0, 0, 0);
            }
        }
    }

    float local = 0.f;
    #pragma unroll
    for (int jr = 0; jr < 4; ++jr) {
        float l = lloc[jr];
        #pragma unroll
        for (int mk = 1; mk < 16; mk <<= 1) l += __shfl_xor(l, mk);
        float inv = 1.f / l;
        #pragma unroll
        for (int nb = 0; nb < 4; ++nb) {
            float d = od2[nb][jr] - od[nb][jr] * inv;
            local += d * d;
        }
    }
    #pragma unroll
    for (int mk = 1; mk < 64; mk <<= 1) local += __shfl_xor(local, mk);
    if (lane == 0) red[w] = local;
    __syncthreads();
    if (tid == 0) atomicAdd(acc, red[0] + red[1] + red[2] + red[3]);
}

// ---------------- launch ----------------
extern "C" void kernel_launch(void* const* d_in, const int* in_sizes, int n_in,
                              void* d_out, int out_size, void* d_ws, size_t ws_size,
                              hipStream_t stream)
{
    const float* x     = (const float*)d_in[0];
    const float* mem   = (const float*)d_in[1];
    const float* cmem  = (const float*)d_in[2];
    const float* pos   = (const float*)d_in[3];
    const float* Wq    = (const float*)d_in[5];
    const float* Wkv   = (const float*)d_in[6];
    const float* Wout  = (const float*)d_in[7];
    const float* bout  = (const float*)d_in[8];
    const float* convw = (const float*)d_in[9];
    const float* convb = (const float*)d_in[10];

    float* out      = (float*)d_out;
    float* logits   = out;
    float* new_mem  = out + 4194304;
    float* new_cmem = out + 8388608;
    float* aux_out  = out + 9437184;

    char* p = (char*)d_ws;
    u16* kvb   = (u16*)p; p += (size_t)9216 * 2048 * 2;
    u16* qb    = (u16*)p; p += (size_t)4096 * 1024 * 2;
    u16* kvin  = (u16*)p; p += (size_t)9216 * 1024 * 2;   // becomes vt in L3
    u16* wkvt  = (u16*)p; p += (size_t)2048 * 1024 * 2;
    u16* wqt   = (u16*)p; p += (size_t)1024 * 1024 * 2;
    u16* woutt = (u16*)p; p += (size_t)1024 * 1024 * 2;
    u16* w2t   = (u16*)p; p += (size_t)1024 * 4096 * 2;   // becomes cvt in L4
    u16* peb   = (u16*)p; p += (size_t)16 * 2304 * 64 * 2;
    u16* xb    = (u16*)p; p += (size_t)4096 * 1024 * 2;   // spare
    u16* memb  = (u16*)p; p += (size_t)4096 * 1024 * 2;   // spare
    u16* cmpb  = (u16*)p; p += (size_t)1024 * 1024 * 2;
    u16* ckcvb = (u16*)p; p += (size_t)1024 * 2048 * 2;
    u16* aob   = (u16*)p; p += (size_t)4096 * 1024 * 2;
    float* acc = (float*)p;
    u16* vt   = kvin;
    u16* cvt  = w2t;
    (void)xb; (void)memb;

    // L1: copy | cvt | concat | transposes | w2t | zero acc (23808 blocks)
    megaprep<<<23808, 256, 0, stream>>>(pos, peb, x, mem, cmem, kvin,
                                        Wkv, wkvt, Wq, wqt, Wout, woutt,
                                        convw, w2t, new_mem, acc);

    // L2: compress | Q | kv GEMMs, LPT-ordered (1472 blocks)
    gemm_stage1<<<1472, 256, 0, stream>>>(kvin, wkvt, wqt, w2t, convb,
                                          kvb, qb, new_cmem, cmpb);

    // L3: ckcv GEMM | main V transpose (2432 blocks)
    gemm_ckcv_tv<<<2432, 256, 0, stream>>>(cmpb, wkvt, ckcvb, kvb, vt);

    // L4: compressed V transpose
    transpose_cvt<<<256, 256, 0, stream>>>(ckcvb, cvt);

    // L5: fused attention + aux loss
    attn_main_fused<<<1024, 256, 0, stream>>>(qb, kvb, vt, peb, ckcvb, cvt, aob, acc);

    // L6: logits GEMM + aux finish
    gemm_out<<<256, 256, 0, stream>>>(aob, woutt, bout, logits, acc, aux_out);
}

// Round 18
// 342.285 us; speedup vs baseline: 1.6385x; 1.0087x over previous
//
#include <hip/hip_runtime.h>
#include <hip/hip_bf16.h>
#include <cstddef>

typedef unsigned short u16;
typedef __attribute__((ext_vector_type(8))) short bf16x8;
typedef __attribute__((ext_vector_type(4))) float f32x4;

#define C2 0.18033688011112042f   // 0.125 * log2(e)

__device__ __forceinline__ u16 f2b(float f) {
    unsigned u = __builtin_bit_cast(unsigned, f);
    unsigned r = (u + 0x7FFF + ((u >> 16) & 1)) >> 16;
    return (u16)r;
}

__device__ __forceinline__ float exp2a(float x) {
    float r; asm("v_exp_f32 %0, %1" : "=v"(r) : "v"(x)); return r;
}

__device__ __forceinline__ unsigned cvtpk(float lo, float hi) {
    unsigned r; asm("v_cvt_pk_bf16_f32 %0, %1, %2" : "=v"(r) : "v"(lo), "v"(hi));
    return r;
}

__device__ __forceinline__ void gload_lds16(const void* g, void* l) {
    __builtin_amdgcn_global_load_lds(
        (const __attribute__((address_space(1))) unsigned int*)g,
        (__attribute__((address_space(3))) unsigned int*)l, 16, 0, 0);
}

#define VDRAIN() asm volatile("s_waitcnt vmcnt(0)" ::: "memory")
#define SBAR() do { __builtin_amdgcn_sched_barrier(0); __builtin_amdgcn_s_barrier(); } while (0)

// ---------------- fused prep ----------------
__device__ __forceinline__ void transpose_body(
    const float* __restrict__ in, u16* __restrict__ out, int K, int N,
    int bx, int by, float (*t)[33], int tid)
{
    int k0 = by * 32, n0 = bx * 32;
    int tx = tid & 31, ty = tid >> 5;
    #pragma unroll
    for (int p = 0; p < 4; ++p)
        t[ty + 8 * p][tx] = in[(size_t)(k0 + ty + 8 * p) * N + n0 + tx];
    __syncthreads();
    #pragma unroll
    for (int p = 0; p < 4; ++p)
        out[(size_t)(n0 + ty + 8 * p) * K + k0 + tx] = f2b(t[tx][ty + 8 * p]);
}

// copy(new_mem=x) | cvt(pos) | concat | Wkv^T | Wq^T | Wout^T | w2t | zero(acc)
__global__ __launch_bounds__(256) void megaprep(
    const float* __restrict__ pos, u16* __restrict__ peb,
    const float* __restrict__ x, const float* __restrict__ mem,
    const float* __restrict__ cmem, u16* __restrict__ kvin,
    const float* __restrict__ Wkv, u16* __restrict__ wkvt,
    const float* __restrict__ Wq, u16* __restrict__ wqt,
    const float* __restrict__ Wout, u16* __restrict__ woutt,
    const float* __restrict__ convw, u16* __restrict__ w2t,
    float* __restrict__ new_mem, float* __restrict__ acc)
{
    __shared__ float t[32][33];
    const int bid = blockIdx.x, tid = threadIdx.x;
    if (bid == 0 && tid == 0) acc[0] = 0.f;
    if (bid < 4096) {                         // new_mem = x (fp32 copy)
        int i = bid * 256 + tid;
        ((float4*)new_mem)[i] = ((const float4*)x)[i];
    } else if (bid < 6400) {                  // cvt pos
        int i = (bid - 4096) * 256 + tid;
        float4 v = ((const float4*)pos)[i];
        union { u16 s[4]; uint2 u; } pk;
        pk.s[0] = f2b(v.x); pk.s[1] = f2b(v.y); pk.s[2] = f2b(v.z); pk.s[3] = f2b(v.w);
        ((uint2*)peb)[i] = pk.u;
    } else if (bid < 15616) {                 // concat kv_input
        int rowg = bid - 6400;
        int b = rowg / 2304, rr = rowg % 2304;
        const float* src = (rr < 256)  ? cmem + ((size_t)b * 256 + rr) * 1024
                         : (rr < 1280) ? mem  + ((size_t)b * 1024 + (rr - 256)) * 1024
                                       : x    + ((size_t)b * 1024 + (rr - 1280)) * 1024;
        float4 v = ((const float4*)src)[tid];
        union { u16 s[4]; uint2 u; } pk;
        pk.s[0] = f2b(v.x); pk.s[1] = f2b(v.y); pk.s[2] = f2b(v.z); pk.s[3] = f2b(v.w);
        ((uint2*)(kvin + (size_t)rowg * 1024))[tid] = pk.u;
    } else if (bid < 17664) {                 // Wkv^T
        int m = bid - 15616;
        transpose_body(Wkv, wkvt, 1024, 2048, m % 64, m / 64, t, tid);
    } else if (bid < 18688) {                 // Wq^T
        int m = bid - 17664;
        transpose_body(Wq, wqt, 1024, 1024, m % 32, m / 32, t, tid);
    } else if (bid < 19712) {                 // Wout^T
        int m = bid - 18688;
        transpose_body(Wout, woutt, 1024, 1024, m % 32, m / 32, t, tid);
    } else {                                  // w2t
        int m = bid - 19712;                  // 4096 blocks
        int pidx = m * 256 + tid;
        int o = pidx >> 10, i = pidx & 1023;
        float4 v = *(const float4*)(convw + ((size_t)o << 12) + 4 * i);
        size_t base = (size_t)o * 4096 + i;
        w2t[base]        = f2b(v.x);
        w2t[base + 1024] = f2b(v.y);
        w2t[base + 2048] = f2b(v.z);
        w2t[base + 3072] = f2b(v.w);
    }
}

// ---------------- bf16 MFMA GEMM body (XCD-bijective linear decode) ----------------
__device__ __forceinline__ void gemm_body(
    const u16* __restrict__ A, const u16* __restrict__ Bt,
    const float* __restrict__ bias, float* __restrict__ Cf,
    u16* __restrict__ Cb, int N, int K, float cscale,
    int apad, int ashift, int nxshift, int nyper, int id,
    u16* Al, u16* Bl)
{
    const int tid = threadIdx.x, w = tid >> 6, lane = tid & 63;
    const int lr = lane & 15, lg = lane >> 4;
    const int xcd = id & 7, s = id >> 3;
    const int bx = s & ((1 << nxshift) - 1);
    const int by = nyper * xcd + (s >> nxshift);
    const int bm0 = by * 128, bn0 = bx * 128;
    const int wr = (w >> 1) * 64, wc = (w & 1) * 64;

    f32x4 acc[4][4];
    const f32x4 z = {0.f, 0.f, 0.f, 0.f};
    #pragma unroll
    for (int mb = 0; mb < 4; ++mb)
        #pragma unroll
        for (int nb = 0; nb < 4; ++nb) acc[mb][nb] = z;

    for (int k0 = 0; k0 < K; k0 += 32) {
        __syncthreads();
        #pragma unroll
        for (int q = 0; q < 2; ++q) {
            int chunk = w * 2 + q;
            int row = bm0 + chunk * 16 + (lane >> 2);
            int arow = row + ((row >> ashift) * apad);
            int sg = (lane & 3) * 8;
            gload_lds16(A + (size_t)arow * K + k0 + sg, &Al[chunk * 512]);
            gload_lds16(Bt + (size_t)(bn0 + chunk * 16 + (lane >> 2)) * K + k0 + sg, &Bl[chunk * 512]);
        }
        __syncthreads();
        bf16x8 af[4], bf[4];
        #pragma unroll
        for (int mb = 0; mb < 4; ++mb)
            af[mb] = *(const bf16x8*)&Al[(wr + mb * 16 + lr) * 32 + lg * 8];
        #pragma unroll
        for (int nb = 0; nb < 4; ++nb)
            bf[nb] = *(const bf16x8*)&Bl[(wc + nb * 16 + lr) * 32 + lg * 8];
        #pragma unroll
        for (int mb = 0; mb < 4; ++mb)
            #pragma unroll
            for (int nb = 0; nb < 4; ++nb)
                acc[mb][nb] = __builtin_amdgcn_mfma_f32_16x16x32_bf16(
                    af[mb], bf[nb], acc[mb][nb], 0, 0, 0);
    }

    #pragma unroll
    for (int mb = 0; mb < 4; ++mb)
        #pragma unroll
        for (int nb = 0; nb < 4; ++nb)
            #pragma unroll
            for (int jr = 0; jr < 4; ++jr) {
                int row = bm0 + wr + mb * 16 + lg * 4 + jr;
                int col = bn0 + wc + nb * 16 + lr;
                float v = acc[mb][nb][jr] + (bias ? bias[col] : 0.f);
                if (Cf) Cf[(size_t)row * N + col] = v;
                if (Cb) Cb[(size_t)row * N + col] = f2b(v * cscale);
            }
}

// LPT order: compress (64, K=4096 longest) | Q (256) | kv (1152)
__global__ __launch_bounds__(256) void gemm_stage1(
    const u16* __restrict__ kvin, const u16* __restrict__ wkvt,
    const u16* __restrict__ wqt, const u16* __restrict__ w2t,
    const float* __restrict__ convb, u16* __restrict__ kvb,
    u16* __restrict__ qb, float* __restrict__ new_cmem, u16* __restrict__ cmpb)
{
    __shared__ u16 Al[128 * 32];
    __shared__ u16 Bl[128 * 32];
    const int id = blockIdx.x;
    if (id < 64)
        gemm_body(kvin + (size_t)256 * 1024, w2t, convb, new_cmem, cmpb,
                  1024, 4096, 1.f, 320, 8, 3, 1, id, Al, Bl);
    else if (id < 320)
        gemm_body(kvin + (size_t)1280 * 1024, wqt, nullptr, nullptr, qb,
                  1024, 1024, C2, 1280, 10, 3, 4, id - 64, Al, Bl);
    else
        gemm_body(kvin, wkvt, nullptr, nullptr, kvb, 2048, 1024, 1.f,
                  0, 10, 4, 9, id - 320, Al, Bl);
}

__device__ __forceinline__ void transpose_v_body(
    const u16* __restrict__ src, int R, u16* __restrict__ dst,
    int bh, int j0, u16* t, int tid)
{
    const int b = bh >> 4, h = bh & 15;
    #pragma unroll
    for (int p = 0; p < 2; ++p) {
        int idx = tid + p * 256;
        int j = idx >> 3, c = idx & 7;
        uint4 v = *(const uint4*)(src + ((size_t)(b * R + j0 + j)) * 2048 + 1024 + h * 64 + c * 8);
        const u16* vv = (const u16*)&v;
        #pragma unroll
        for (int u2 = 0; u2 < 8; ++u2) t[j * 65 + c * 8 + u2] = vv[u2];
    }
    __syncthreads();
    #pragma unroll
    for (int p = 0; p < 2; ++p) {
        int idx = tid + p * 256;
        int jc = idx & 7, d = idx >> 3;
        union { u16 s[8]; uint4 u; } pk;
        #pragma unroll
        for (int u2 = 0; u2 < 8; ++u2) pk.s[u2] = t[(jc * 8 + u2) * 65 + d];
        *(uint4*)(dst + ((size_t)(bh * 64 + d)) * (size_t)R + j0 + jc * 8) = pk.u;
    }
}

// ckcv GEMM (128 blocks) | main V transpose (2304 blocks)
__global__ __launch_bounds__(256) void gemm_ckcv_tv(
    const u16* __restrict__ cmpb, const u16* __restrict__ wkvt,
    u16* __restrict__ ckcvb, const u16* __restrict__ kvb, u16* __restrict__ vt)
{
    __shared__ u16 shmem[128 * 64];
    const int id = blockIdx.x;
    if (id < 128) {
        gemm_body(cmpb, wkvt, nullptr, nullptr, ckcvb, 2048, 1024, 1.f,
                  0, 10, 4, 1, id, shmem, shmem + 4096);
    } else {
        int m = id - 128;
        transpose_v_body(kvb, 2304, vt, m / 36, (m % 36) * 64, shmem, threadIdx.x);
    }
}

// compressed V transpose (256 blocks)
__global__ __launch_bounds__(256) void transpose_cvt(
    const u16* __restrict__ ckcvb, u16* __restrict__ cvt)
{
    __shared__ u16 t[64 * 65];
    int m = blockIdx.x;
    transpose_v_body(ckcvb, 256, cvt, m / 4, (m % 4) * 64, t, threadIdx.x);
}

// out GEMM + aux finish
__global__ __launch_bounds__(256) void gemm_out(
    const u16* __restrict__ aob, const u16* __restrict__ woutt,
    const float* __restrict__ bout, float* __restrict__ logits,
    const float* __restrict__ acc, float* __restrict__ aux_out)
{
    __shared__ u16 Al[128 * 32];
    __shared__ u16 Bl[128 * 32];
    if (blockIdx.x == 0 && threadIdx.x == 0)
        aux_out[0] = acc[0] * (1.0f / 4194304.0f);
    gemm_body(aob, woutt, bout, logits, nullptr, 1024, 1024, 1.f,
              0, 10, 3, 4, blockIdx.x, Al, Bl);
}

// ---------------- fused main attention + FULL aux loss ----------------
// V double-buffered: V(t+1) staged with K(t+1)/PE(t+1) right after barrier B
// into vbuf[vcur^1] (PV reads vbuf[vcur]) -> B needs NO vm drain; the single
// remaining drain (before C) has the softmax+PV+aux phase as cover.
__global__ __launch_bounds__(256) void attn_main_fused(
    const u16* __restrict__ qb, const u16* __restrict__ kvb,
    const u16* __restrict__ vt, const u16* __restrict__ peb,
    const u16* __restrict__ ckcv, const u16* __restrict__ cvt,
    u16* __restrict__ outb, float* __restrict__ acc)
{
    __shared__ u16 kbuf[64 * 64];
    __shared__ u16 vbuf[2][64 * 64];
    __shared__ u16 pering[128 * 64];
    __shared__ u16 pls[4][1024];
    __shared__ float red[4];

    const int tid = threadIdx.x;
    const int w = tid >> 6, lane = tid & 63;
    const int lr = lane & 15, lg = lane >> 4;
    const int rl = lane >> 3, cch = lane & 7;
    const int id = blockIdx.x;
    const int slot = id >> 3;
    const int bh = (id & 7) + ((slot >> 4) << 3);
    const int b = bh >> 4, h = bh & 15;
    const int i0 = (15 - (slot & 15)) * 64;   // LPT: longest first
    const int iw = i0 + 16 * w;
    const int jb0 = 960 - i0;

    const int lrh = lr >> 3, lrm = lr & 7;
    int pwidx[4], pridx[2];
    #pragma unroll
    for (int nb = 0; nb < 4; ++nb)
        pwidx[nb] = (((nb * 2 + lrh) ^ (lg * 2)) * 8) + lrm;
    #pragma unroll
    for (int ks = 0; ks < 2; ++ks)
        pridx[ks] = lr * 64 + (((ks * 4 + lg) ^ ((lr >> 2) * 2)) * 8);

    bf16x8 qf[2];
    #pragma unroll
    for (int ks = 0; ks < 2; ++ks)
        qf[ks] = *(const bf16x8*)(qb + ((size_t)(b * 1024 + iw + lr)) * 1024
                                  + h * 64 + ks * 32 + lg * 8);

    const f32x4 z = {0.f, 0.f, 0.f, 0.f};
    f32x4 od[4], od2[4];
    float lloc[4], ll2[4];
    #pragma unroll
    for (int nb = 0; nb < 4; ++nb) { od[nb] = z; od2[nb] = z; }
    #pragma unroll
    for (int jr = 0; jr < 4; ++jr) { lloc[jr] = 0.f; ll2[jr] = 0.f; }

    // ---- prologue: K(0), V(0)->vbuf[0], full 128-row PE band ----
    #pragma unroll
    for (int q = 0; q < 2; ++q) {
        int row = 16 * w + 8 * q + rl;
        gload_lds16(kvb + ((size_t)(b * 2304 + row)) * 2048 + h * 64 + ((cch ^ rl) * 8),
                    &kbuf[(16 * w + 8 * q) * 64]);
        gload_lds16(vt + ((size_t)(bh * 64 + row)) * 2304 + ((cch ^ rl) * 8),
                    &vbuf[0][(16 * w + 8 * q) * 64]);
    }
    #pragma unroll
    for (int q = 0; q < 4; ++q) {
        int rr = 32 * w + 8 * q;
        int a = jb0 + rr + rl;
        int srow = a > 2303 ? 2303 : a;
        gload_lds16(peb + ((size_t)(h * 2304 + srow)) * 64 + ((cch ^ rl) * 8),
                    &pering[((jb0 + rr) & 127) * 64]);
    }
    VDRAIN();
    __syncthreads();

    int vcur = 0;
    const int nt = ((i0 + 1343) >> 6) + 1;
    for (int t = 0; t < nt; ++t) {
        const int j0 = t * 64;
        const int jb = jb0 + j0;
        const bool more = (t + 1 < nt);

        f32x4 qk[4], qp[5];
        #pragma unroll
        for (int nb = 0; nb < 4; ++nb) qk[nb] = z;
        #pragma unroll
        for (int f = 0; f < 5; ++f) qp[f] = z;
        __builtin_amdgcn_s_setprio(1);
        #pragma unroll
        for (int ks = 0; ks < 2; ++ks) {
            #pragma unroll
            for (int nb = 0; nb < 4; ++nb) {
                int row = nb * 16 + lr;
                bf16x8 kb = *(const bf16x8*)&kbuf[row * 64 + (((4 * ks + lg) ^ (row & 7)) * 8)];
                qk[nb] = __builtin_amdgcn_mfma_f32_16x16x32_bf16(qf[ks], kb, qk[nb], 0, 0, 0);
            }
            #pragma unroll
            for (int f = 0; f < 5; ++f) {
                int rel = 48 - 16 * w + f * 16 + lr;
                int slotp = (jb + rel) & 127;
                bf16x8 pb = *(const bf16x8*)&pering[slotp * 64 + (((4 * ks + lg) ^ (slotp & 7)) * 8)];
                qp[f] = __builtin_amdgcn_mfma_f32_16x16x32_bf16(qf[ks], pb, qp[f], 0, 0, 0);
            }
        }
        __builtin_amdgcn_s_setprio(0);

        SBAR();     // B: certifies kbuf/pering reads of tile t (no vm drain needed)

        if (more) { // stage K(t+1), PE(t+1), V(t+1)->vbuf[vcur^1]
            const int j0n = j0 + 64;
            #pragma unroll
            for (int q = 0; q < 2; ++q) {
                int row = 16 * w + 8 * q + rl;
                gload_lds16(kvb + ((size_t)(b * 2304 + j0n + row)) * 2048 + h * 64 + ((cch ^ rl) * 8),
                            &kbuf[(16 * w + 8 * q) * 64]);
                gload_lds16(vt + ((size_t)(bh * 64 + row)) * 2304 + j0n + ((cch ^ rl) * 8),
                            &vbuf[vcur ^ 1][(16 * w + 8 * q) * 64]);
            }
            const int A0 = jb + 128;
            #pragma unroll
            for (int q = 0; q < 2; ++q) {
                int rr = A0 + 16 * w + 8 * q;
                int a = rr + rl;
                int srow = a > 2303 ? 2303 : a;
                gload_lds16(peb + ((size_t)(h * 2304 + srow)) * 64 + ((cch ^ rl) * 8),
                            &pering[(rr & 127) * 64]);
            }
        }

        const bool nomask = (j0 + 63 <= iw + 1280);
        #pragma unroll
        for (int jr = 0; jr < 4; ++jr) {
            const int r = lg * 4 + jr;
            const int ia = iw + r;
            const int src = (lane & 48) | ((lr + 15 - r) & 15);
            float rot0 = __shfl(qp[0][jr], src);
            float rot1 = __shfl(qp[1][jr], src);
            float rot2 = __shfl(qp[2][jr], src);
            float rot3 = __shfl(qp[3][jr], src);
            float rot4 = __shfl(qp[4][jr], src);
            const bool hi = (lr > r);
            float s0 = qk[0][jr] + (hi ? rot1 : rot0);
            float s1 = qk[1][jr] + (hi ? rot2 : rot1);
            float s2 = qk[2][jr] + (hi ? rot3 : rot2);
            float s3 = qk[3][jr] + (hi ? rot4 : rot3);
            if (!nomask) {
                s0 = (j0 + lr      <= ia + 1280) ? s0 : -1e30f;
                s1 = (j0 + lr + 16 <= ia + 1280) ? s1 : -1e30f;
                s2 = (j0 + lr + 32 <= ia + 1280) ? s2 : -1e30f;
                s3 = (j0 + lr + 48 <= ia + 1280) ? s3 : -1e30f;
            }
            float p0 = exp2a(s0), p1 = exp2a(s1);
            float p2 = exp2a(s2), p3 = exp2a(s3);
            unsigned pkA = cvtpk(p0, p1), pkB = cvtpk(p2, p3);
            u16* pw = &pls[w][r * 64];
            pw[pwidx[0]] = (u16)pkA; pw[pwidx[1]] = (u16)(pkA >> 16);
            pw[pwidx[2]] = (u16)pkB; pw[pwidx[3]] = (u16)(pkB >> 16);
            lloc[jr] += (p0 + p1) + (p2 + p3);
        }

        __builtin_amdgcn_s_setprio(1);
        #pragma unroll
        for (int ks = 0; ks < 2; ++ks) {
            bf16x8 pa = *(const bf16x8*)&pls[w][pridx[ks]];
            #pragma unroll
            for (int nb = 0; nb < 4; ++nb) {
                int d = nb * 16 + lr;
                bf16x8 vb = *(const bf16x8*)&vbuf[vcur][d * 64 + (((4 * ks + lg) ^ (d & 7)) * 8)];
                od[nb] = __builtin_amdgcn_mfma_f32_16x16x32_bf16(pa, vb, od[nb], 0, 0, 0);
            }
        }
        __builtin_amdgcn_s_setprio(0);

        if (t >= 4 && t <= 19) {
            #pragma unroll
            for (int jr = 0; jr < 4; ++jr) {
                const int r = lg * 4 + jr;
                float p0 = exp2a(qk[0][jr]), p1 = exp2a(qk[1][jr]);
                float p2 = exp2a(qk[2][jr]), p3 = exp2a(qk[3][jr]);
                unsigned pkA = cvtpk(p0, p1), pkB = cvtpk(p2, p3);
                u16* pw = &pls[w][r * 64];
                pw[pwidx[0]] = (u16)pkA; pw[pwidx[1]] = (u16)(pkA >> 16);
                pw[pwidx[2]] = (u16)pkB; pw[pwidx[3]] = (u16)(pkB >> 16);
                ll2[jr] += (p0 + p1) + (p2 + p3);
            }
            __builtin_amdgcn_s_setprio(1);
            #pragma unroll
            for (int ks = 0; ks < 2; ++ks) {
                bf16x8 pa = *(const bf16x8*)&pls[w][pridx[ks]];
                #pragma unroll
                for (int nb = 0; nb < 4; ++nb) {
                    int d = nb * 16 + lr;
                    bf16x8 vb = *(const bf16x8*)&vbuf[vcur][d * 64 + (((4 * ks + lg) ^ (d & 7)) * 8)];
                    od2[nb] = __builtin_amdgcn_mfma_f32_16x16x32_bf16(pa, vb, od2[nb], 0, 0, 0);
                }
            }
            __builtin_amdgcn_s_setprio(0);
        }

        VDRAIN();   // retire own K/PE/V(t+1) loads
        SBAR();     // C: publishes kbuf=K(t+1), pering, vbuf[vcur^1]=V(t+1)
        vcur ^= 1;
    }

    #pragma unroll
    for (int jr = 0; jr < 4; ++jr) {
        float l = lloc[jr];
        #pragma unroll
        for (int mk = 1; mk < 16; mk <<= 1) l += __shfl_xor(l, mk);
        float inv = 1.f / l;
        int ia = iw + lg * 4 + jr;
        #pragma unroll
        for (int nb = 0; nb < 4; ++nb)
            outb[((size_t)(b * 1024 + ia)) * 1024 + h * 64 + nb * 16 + lr] =
                f2b(od[nb][jr] * inv);
    }
    #pragma unroll
    for (int jr = 0; jr < 4; ++jr) {
        float l = ll2[jr];
        #pragma unroll
        for (int mk = 1; mk < 16; mk <<= 1) l += __shfl_xor(l, mk);
        float inv = 1.f / l;
        #pragma unroll
        for (int nb = 0; nb < 4; ++nb) od2[nb][jr] *= inv;
    }

    // ---- aux phase-1: compressed KV (4 tiles), vbuf[0] ----
    #pragma unroll
    for (int nb = 0; nb < 4; ++nb) od[nb] = z;
    #pragma unroll
    for (int jr = 0; jr < 4; ++jr) lloc[jr] = 0.f;
    const u16* kbase = ckcv + ((size_t)(b * 256)) * 2048 + h * 64;
    const u16* vbase = cvt + ((size_t)(bh * 64)) * 256;

    for (int t = 0; t < 4; ++t) {
        const int j0 = t * 64;
        __syncthreads();
        #pragma unroll
        for (int q = 0; q < 2; ++q) {
            int row = 16 * w + 8 * q + rl;
            gload_lds16(kbase + (size_t)(j0 + row) * 2048 + ((cch ^ rl) * 8),
                        &kbuf[(16 * w + 8 * q) * 64]);
            gload_lds16(vbase + (size_t)row * 256 + j0 + ((cch ^ rl) * 8),
                        &vbuf[0][(16 * w + 8 * q) * 64]);
        }
        VDRAIN();
        __syncthreads();

        f32x4 qk[4];
        #pragma unroll
        for (int nb = 0; nb < 4; ++nb) qk[nb] = z;
        #pragma unroll
        for (int ks = 0; ks < 2; ++ks)
            #pragma unroll
            for (int nb = 0; nb < 4; ++nb) {
                int row = nb * 16 + lr;
                bf16x8 kb = *(const bf16x8*)&kbuf[row * 64 + (((4 * ks + lg) ^ (row & 7)) * 8)];
                qk[nb] = __builtin_amdgcn_mfma_f32_16x16x32_bf16(qf[ks], kb, qk[nb], 0, 0, 0);
            }

        #pragma unroll
        for (int jr = 0; jr < 4; ++jr) {
            const int r = lg * 4 + jr;
            float p0 = exp2a(qk[0][jr]), p1 = exp2a(qk[1][jr]);
            float p2 = exp2a(qk[2][jr]), p3 = exp2a(qk[3][jr]);
            unsigned pkA = cvtpk(p0, p1), pkB = cvtpk(p2, p3);
            u16* pw = &pls[w][r * 64];
            pw[pwidx[0]] = (u16)pkA; pw[pwidx[1]] = (u16)(pkA >> 16);
            pw[pwidx[2]] = (u16)pkB; pw[pwidx[3]] = (u16)(pkB >> 16);
            lloc[jr] += (p0 + p1) + (p2 + p3);
        }

        #pragma unroll
        for (int ks = 0; ks < 2; ++ks) {
            bf16x8 pa = *(const bf16x8*)&pls[w][pridx[ks]];
            #pragma unroll
            for (int nb = 0; nb < 4; ++nb) {
                int d = nb * 16 + lr;
                bf16x8 vb = *(const bf16x8*)&vbuf[0][d * 64 + (((4 * ks + lg) ^ (d & 7)) * 8)];
                od[nb] = __builtin_amdgcn_mfma_f32_16x16x32_bf16(pa, vb, od[nb], 0, 0, 0);
            }
        }
    }

    float local = 0.f;
    #pragma unroll
    for (int jr = 0; jr < 4; ++jr) {
        float l = lloc[jr];
        #pragma unroll
        for (int mk = 1; mk < 16; mk <<= 1) l += __shfl_xor(l, mk);
        float inv = 1.f / l;
        #pragma unroll
        for (int nb = 0; nb < 4; ++nb) {
            float d = od2[nb][jr] - od[nb][jr] * inv;
            local += d * d;
        }
    }
    #pragma unroll
    for (int mk = 1; mk < 64; mk <<= 1) local += __shfl_xor(local, mk);
    if (lane == 0) red[w] = local;
    __syncthreads();
    if (tid == 0) atomicAdd(acc, red[0] + red[1] + red[2] + red[3]);
}

// ---------------- launch ----------------
extern "C" void kernel_launch(void* const* d_in, const int* in_sizes, int n_in,
                              void* d_out, int out_size, void* d_ws, size_t ws_size,
                              hipStream_t stream)
{
    const float* x     = (const float*)d_in[0];
    const float* mem   = (const float*)d_in[1];
    const float* cmem  = (const float*)d_in[2];
    const float* pos   = (const float*)d_in[3];
    const float* Wq    = (const float*)d_in[5];
    const float* Wkv   = (const float*)d_in[6];
    const float* Wout  = (const float*)d_in[7];
    const float* bout  = (const float*)d_in[8];
    const float* convw = (const float*)d_in[9];
    const float* convb = (const float*)d_in[10];

    float* out      = (float*)d_out;
    float* logits   = out;
    float* new_mem  = out + 4194304;
    float* new_cmem = out + 8388608;
    float* aux_out  = out + 9437184;

    char* p = (char*)d_ws;
    u16* kvb   = (u16*)p; p += (size_t)9216 * 2048 * 2;
    u16* qb    = (u16*)p; p += (size_t)4096 * 1024 * 2;
    u16* kvin  = (u16*)p; p += (size_t)9216 * 1024 * 2;   // becomes vt in L3
    u16* wkvt  = (u16*)p; p += (size_t)2048 * 1024 * 2;
    u16* wqt   = (u16*)p; p += (size_t)1024 * 1024 * 2;
    u16* woutt = (u16*)p; p += (size_t)1024 * 1024 * 2;
    u16* w2t   = (u16*)p; p += (size_t)1024 * 4096 * 2;   // becomes cvt in L4
    u16* peb   = (u16*)p; p += (size_t)16 * 2304 * 64 * 2;
    u16* xb    = (u16*)p; p += (size_t)4096 * 1024 * 2;   // spare
    u16* memb  = (u16*)p; p += (size_t)4096 * 1024 * 2;   // spare
    u16* cmpb  = (u16*)p; p += (size_t)1024 * 1024 * 2;
    u16* ckcvb = (u16*)p; p += (size_t)1024 * 2048 * 2;
    u16* aob   = (u16*)p; p += (size_t)4096 * 1024 * 2;
    float* acc = (float*)p;
    u16* vt   = kvin;
    u16* cvt  = w2t;
    (void)xb; (void)memb;

    // L1: copy | cvt | concat | transposes | w2t | zero acc (23808 blocks)
    megaprep<<<23808, 256, 0, stream>>>(pos, peb, x, mem, cmem, kvin,
                                        Wkv, wkvt, Wq, wqt, Wout, woutt,
                                        convw, w2t, new_mem, acc);

    // L2: compress | Q | kv GEMMs, LPT-ordered (1472 blocks)
    gemm_stage1<<<1472, 256, 0, stream>>>(kvin, wkvt, wqt, w2t, convb,
                                          kvb, qb, new_cmem, cmpb);

    // L3: ckcv GEMM | main V transpose (2432 blocks)
    gemm_ckcv_tv<<<2432, 256, 0, stream>>>(cmpb, wkvt, ckcvb, kvb, vt);

    // L4: compressed V transpose
    transpose_cvt<<<256, 256, 0, stream>>>(ckcvb, cvt);

    // L5: fused attention + aux loss
    attn_main_fused<<<1024, 256, 0, stream>>>(qb, kvb, vt, peb, ckcvb, cvt, aob, acc);

    // L6: logits GEMM + aux finish
    gemm_out<<<256, 256, 0, stream>>>(aob, woutt, bout, logits, acc, aux_out);
}